// Round 1
// baseline (760.494 us; speedup 1.0000x reference)
//
#include <hip/hip_runtime.h>
#include <hip/hip_bf16.h>
#include <math.h>

typedef __bf16 bf16;
typedef __attribute__((ext_vector_type(8))) __bf16 bf16x8;
typedef __attribute__((ext_vector_type(4))) float f32x4;

#define NTOK 4096
#define DIM  320
#define HEADS 8
#define DHEAD 40
#define NCTX 77
#define CTXD 768
#define IFF  1280

__device__ __forceinline__ bf16x8 bzero8() {
    bf16x8 v;
#pragma unroll
    for (int e = 0; e < 8; ++e) v[e] = (bf16)0.0f;
    return v;
}

// ---------------- transpose + convert fp32 W[K][N] -> bf16 Wt[N][K] ----------
__global__ __launch_bounds__(256)
void transpose_to_bf16(const float* __restrict__ W, bf16* __restrict__ Wt, int K, int N) {
    __shared__ float tile[32][33];
    int n0 = blockIdx.x * 32, k0 = blockIdx.y * 32;
    int tx = threadIdx.x, ty = threadIdx.y;  // (32,8)
#pragma unroll
    for (int i = 0; i < 4; ++i)
        tile[ty + i * 8][tx] = W[(size_t)(k0 + ty + i * 8) * N + n0 + tx];
    __syncthreads();
#pragma unroll
    for (int i = 0; i < 4; ++i)
        Wt[(size_t)(n0 + ty + i * 8) * K + k0 + tx] = (bf16)tile[tx][ty + i * 8];
}

// ---------------- fp32 -> bf16 elementwise ----------------
__global__ void f32_to_bf16(const float* __restrict__ X, bf16* __restrict__ Y, int n) {
    int i = blockIdx.x * 256 + threadIdx.x;
    if (i < n) Y[i] = (bf16)X[i];
}

// ---------------- LayerNorm: fp32 in -> bf16 out, N=320 ----------------
__global__ __launch_bounds__(256)
void layernorm_kernel(const float* __restrict__ X, const float* __restrict__ g,
                      const float* __restrict__ b, bf16* __restrict__ Y) {
    int w = threadIdx.x >> 6, lane = threadIdx.x & 63;
    int row = blockIdx.x * 4 + w;
    const float* xr = X + (size_t)row * DIM;
    float v[5];
    float sum = 0.f;
#pragma unroll
    for (int c = 0; c < 5; ++c) { v[c] = xr[c * 64 + lane]; sum += v[c]; }
#pragma unroll
    for (int off = 1; off < 64; off <<= 1) sum += __shfl_xor(sum, off);
    float mu = sum * (1.f / 320.f);
    float vs = 0.f;
#pragma unroll
    for (int c = 0; c < 5; ++c) { float d = v[c] - mu; vs += d * d; }
#pragma unroll
    for (int off = 1; off < 64; off <<= 1) vs += __shfl_xor(vs, off);
    float rs = rsqrtf(vs * (1.f / 320.f) + 1e-5f);
    bf16* yr = Y + (size_t)row * DIM;
#pragma unroll
    for (int c = 0; c < 5; ++c)
        yr[c * 64 + lane] = (bf16)((v[c] - mu) * rs * g[c * 64 + lane] + b[c * 64 + lane]);
}

// ---------------- generic bf16 MFMA GEMM ----------------
// C[M][N] = A[M][K] @ B  with Bt = B^T row-major [N][K].
// EPI 0: Ybf = bf16(acc); 1: Ybf = bf16(acc+bias); 2: Yf = acc + bias + res (fp32)
// BM=128 BN=64 BK=64, 256 threads (4 waves, 2x2), XOR-swizzled LDS.
template <int EPI>
__global__ __launch_bounds__(256)
void gemm_bf16(const bf16* __restrict__ A, const bf16* __restrict__ Bt,
               int M, int N, int K,
               bf16* __restrict__ Ybf, float* Yf,
               const float* __restrict__ bias, const float* res) {
    __shared__ char smem[24 * 1024];  // A:16KB  B:8KB
    const int t = threadIdx.x;
    const int lane = t & 63;
    const int w = t >> 6;
    const int wr = w >> 1, wc = w & 1;
    const int m0 = blockIdx.x * 128;
    const int n0 = blockIdx.y * 64;

    f32x4 acc[4][2];
#pragma unroll
    for (int mi = 0; mi < 4; ++mi)
#pragma unroll
        for (int ni = 0; ni < 2; ++ni)
#pragma unroll
            for (int r = 0; r < 4; ++r) acc[mi][ni][r] = 0.f;

    for (int k0 = 0; k0 < K; k0 += 64) {
        // stage A tile [128][64] (rows padded with zeros past M)
#pragma unroll
        for (int i = 0; i < 4; ++i) {
            int c = t + i * 256;
            int row = c >> 3, seg = c & 7;
            int gr = m0 + row;
            bf16x8 v = bzero8();
            if (gr < M) v = *(const bf16x8*)(A + (size_t)gr * K + k0 + seg * 8);
            *(bf16x8*)(smem + row * 128 + ((seg * 16) ^ ((row & 7) << 4))) = v;
        }
        // stage Bt tile [64][64]
#pragma unroll
        for (int i = 0; i < 2; ++i) {
            int c = t + i * 256;
            int row = c >> 3, seg = c & 7;
            bf16x8 v = *(const bf16x8*)(Bt + (size_t)(n0 + row) * K + k0 + seg * 8);
            *(bf16x8*)(smem + 16 * 1024 + row * 128 + ((seg * 16) ^ ((row & 7) << 4))) = v;
        }
        __syncthreads();

        bf16x8 a[4][2], bfr[2][2];
#pragma unroll
        for (int mi = 0; mi < 4; ++mi)
#pragma unroll
            for (int kh = 0; kh < 2; ++kh) {
                int row = wr * 64 + mi * 16 + (lane & 15);
                a[mi][kh] = *(const bf16x8*)(smem + row * 128 +
                             ((kh * 64 + (lane >> 4) * 16) ^ ((row & 7) << 4)));
            }
#pragma unroll
        for (int ni = 0; ni < 2; ++ni)
#pragma unroll
            for (int kh = 0; kh < 2; ++kh) {
                int row = wc * 32 + ni * 16 + (lane & 15);
                bfr[ni][kh] = *(const bf16x8*)(smem + 16 * 1024 + row * 128 +
                               ((kh * 64 + (lane >> 4) * 16) ^ ((row & 7) << 4)));
            }
#pragma unroll
        for (int mi = 0; mi < 4; ++mi)
#pragma unroll
            for (int ni = 0; ni < 2; ++ni) {
                acc[mi][ni] = __builtin_amdgcn_mfma_f32_16x16x32_bf16(a[mi][0], bfr[ni][0], acc[mi][ni], 0, 0, 0);
                acc[mi][ni] = __builtin_amdgcn_mfma_f32_16x16x32_bf16(a[mi][1], bfr[ni][1], acc[mi][ni], 0, 0, 0);
            }
        __syncthreads();
    }

#pragma unroll
    for (int mi = 0; mi < 4; ++mi)
#pragma unroll
        for (int ni = 0; ni < 2; ++ni)
#pragma unroll
            for (int r = 0; r < 4; ++r) {
                int row = m0 + wr * 64 + mi * 16 + (lane >> 4) * 4 + r;
                int col = n0 + wc * 32 + ni * 16 + (lane & 15);
                if (row < M) {
                    float v = acc[mi][ni][r];
                    if (EPI == 0) {
                        Ybf[(size_t)row * N + col] = (bf16)v;
                    } else if (EPI == 1) {
                        Ybf[(size_t)row * N + col] = (bf16)(v + bias[col]);
                    } else {
                        Yf[(size_t)row * N + col] = v + bias[col] + res[(size_t)row * N + col];
                    }
                }
            }
}

// ---------------- flash self-attention ----------------
// Q,K,V bf16 [4096][320] (col = h*40+d), O bf16 [4096][320].
// grid (64, 8): 64 q-rows per block (4 waves x 16 rows), head = blockIdx.y.
// KV tiles of 64. dhead 40 padded to 64. scale*log2e folded into Q (exp2 softmax).
__global__ __launch_bounds__(256)
void flash_self_attn(const bf16* __restrict__ Qg, const bf16* __restrict__ Kg,
                     const bf16* __restrict__ Vg, bf16* __restrict__ O) {
    __shared__ char smem[30 * 1024];
    // layout: Kt [64][64] @0 (8KB) | Vt [48][64] @8KB (6KB) | Qs 4x[16][64] @14KB | Ps 4x[16][64] @22KB
    const int t = threadIdx.x;
    const int lane = t & 63;
    const int w = t >> 6;
    const int h = blockIdx.y;
    const int qb = blockIdx.x * 64 + w * 16;
    char* Qs = smem + 14 * 1024 + w * 2048;
    char* Ps = smem + 22 * 1024 + w * 2048;

    const float qscale = 0.15811388300841897f * 1.4426950408889634f;  // 40^-0.5 * log2(e)

    // stage this wave's Q rows (scaled), pad d 40..63 with zero
#pragma unroll
    for (int i = 0; i < 2; ++i) {
        int c = lane + i * 64;
        int row = c >> 3, seg = c & 7;
        bf16x8 v = bzero8();
        if (seg < 5) {
            bf16x8 raw = *(const bf16x8*)(Qg + (size_t)(qb + row) * DIM + h * DHEAD + seg * 8);
#pragma unroll
            for (int e = 0; e < 8; ++e) v[e] = (bf16)((float)raw[e] * qscale);
        }
        *(bf16x8*)(Qs + row * 128 + ((seg * 16) ^ ((row & 7) << 4))) = v;
    }
    // Q fragments (wave-local LDS, in-order: safe without barrier)
    bf16x8 qf[2];
#pragma unroll
    for (int kh = 0; kh < 2; ++kh) {
        int row = lane & 15;
        qf[kh] = *(const bf16x8*)(Qs + row * 128 + ((kh * 64 + (lane >> 4) * 16) ^ ((row & 7) << 4)));
    }

    f32x4 accO[3];
#pragma unroll
    for (int dt = 0; dt < 3; ++dt)
#pragma unroll
        for (int r = 0; r < 4; ++r) accO[dt][r] = 0.f;
    float m_run[4], l_run[4];
#pragma unroll
    for (int r = 0; r < 4; ++r) { m_run[r] = -1e30f; l_run[r] = 0.f; }

    for (int j0 = 0; j0 < NTOK; j0 += 64) {
        // stage K tile [64 kv][64 d-padded]
#pragma unroll
        for (int i = 0; i < 2; ++i) {
            int c = t + i * 256;
            int row = c >> 3, seg = c & 7;
            bf16x8 v = bzero8();
            if (seg < 5) v = *(const bf16x8*)(Kg + (size_t)(j0 + row) * DIM + h * DHEAD + seg * 8);
            *(bf16x8*)(smem + row * 128 + ((seg * 16) ^ ((row & 7) << 4))) = v;
        }
        // stage V transposed: Vt[d][j]  (rows d=40..47 left unread -> unused out cols)
#pragma unroll
        for (int i = 0; i < 2; ++i) {
            int c = t + i * 256;
            int j = c >> 3, seg = c & 7;
            if (seg < 5) {
                bf16x8 v = *(const bf16x8*)(Vg + (size_t)(j0 + j) * DIM + h * DHEAD + seg * 8);
#pragma unroll
                for (int e = 0; e < 8; ++e) {
                    int d = seg * 8 + e;
                    *(bf16*)(smem + 8 * 1024 + d * 128 + ((j * 2) ^ ((d & 7) << 4))) = v[e];
                }
            }
        }
        __syncthreads();

        // QK^T: s[jt] = 16x16 tile, cols j = jt*16+(lane&15), rows q = (lane>>4)*4+r
        f32x4 s[4];
#pragma unroll
        for (int jt = 0; jt < 4; ++jt) {
            int row = jt * 16 + (lane & 15);
            bf16x8 kb0 = *(const bf16x8*)(smem + row * 128 + (((lane >> 4) * 16) ^ ((row & 7) << 4)));
            bf16x8 kb1 = *(const bf16x8*)(smem + row * 128 + ((64 + (lane >> 4) * 16) ^ ((row & 7) << 4)));
            f32x4 z;
#pragma unroll
            for (int r = 0; r < 4; ++r) z[r] = 0.f;
            z = __builtin_amdgcn_mfma_f32_16x16x32_bf16(qf[0], kb0, z, 0, 0, 0);
            z = __builtin_amdgcn_mfma_f32_16x16x32_bf16(qf[1], kb1, z, 0, 0, 0);
            s[jt] = z;
        }

        // online softmax (log2 domain), per accumulator row r
        float p[4][4];
#pragma unroll
        for (int r = 0; r < 4; ++r) {
            float mrow = fmaxf(fmaxf(s[0][r], s[1][r]), fmaxf(s[2][r], s[3][r]));
#pragma unroll
            for (int off = 1; off < 16; off <<= 1)
                mrow = fmaxf(mrow, __shfl_xor(mrow, off, 16));
            float mnew = fmaxf(m_run[r], mrow);
            float f = exp2f(m_run[r] - mnew);
            m_run[r] = mnew;
            float psum = 0.f;
#pragma unroll
            for (int jt = 0; jt < 4; ++jt) {
                float pv = exp2f(s[jt][r] - mnew);
                p[jt][r] = pv;
                psum += pv;
            }
#pragma unroll
            for (int off = 1; off < 16; off <<= 1)
                psum += __shfl_xor(psum, off, 16);
            l_run[r] = l_run[r] * f + psum;
#pragma unroll
            for (int dt = 0; dt < 3; ++dt) accO[dt][r] *= f;
        }

        // write P tile (bf16) to wave-local LDS
#pragma unroll
        for (int jt = 0; jt < 4; ++jt)
#pragma unroll
            for (int r = 0; r < 4; ++r) {
                int row = (lane >> 4) * 4 + r;
                *(bf16*)(Ps + row * 128 + ((jt * 32 + (lane & 15) * 2) ^ ((row & 7) << 4))) = (bf16)p[jt][r];
            }

        // PV: A = P [16 q][64 j], B = Vt (col=d, k=j)
        bf16x8 pa[2];
#pragma unroll
        for (int kh = 0; kh < 2; ++kh) {
            int row = lane & 15;
            pa[kh] = *(const bf16x8*)(Ps + row * 128 + ((kh * 64 + (lane >> 4) * 16) ^ ((row & 7) << 4)));
        }
#pragma unroll
        for (int dt = 0; dt < 3; ++dt) {
            int row = dt * 16 + (lane & 15);
            bf16x8 vb0 = *(const bf16x8*)(smem + 8 * 1024 + row * 128 + (((lane >> 4) * 16) ^ ((row & 7) << 4)));
            bf16x8 vb1 = *(const bf16x8*)(smem + 8 * 1024 + row * 128 + ((64 + (lane >> 4) * 16) ^ ((row & 7) << 4)));
            accO[dt] = __builtin_amdgcn_mfma_f32_16x16x32_bf16(pa[0], vb0, accO[dt], 0, 0, 0);
            accO[dt] = __builtin_amdgcn_mfma_f32_16x16x32_bf16(pa[1], vb1, accO[dt], 0, 0, 0);
        }
        __syncthreads();
    }

#pragma unroll
    for (int dt = 0; dt < 3; ++dt)
#pragma unroll
        for (int r = 0; r < 4; ++r) {
            int col = dt * 16 + (lane & 15);
            if (col < DHEAD) {
                int row = qb + (lane >> 4) * 4 + r;
                O[(size_t)row * DIM + h * DHEAD + col] = (bf16)(accO[dt][r] / l_run[r]);
            }
        }
}

// ---------------- cross-attention (77 kv tokens, VALU) ----------------
__global__ __launch_bounds__(256)
void cross_attn(const bf16* __restrict__ Q2, const bf16* __restrict__ K2,
                const bf16* __restrict__ V2, bf16* __restrict__ O) {
    __shared__ __align__(16) float Ksm[NCTX * DHEAD];
    __shared__ __align__(16) float Vsm[NCTX * DHEAD];
    const int t = threadIdx.x;
    const int h = blockIdx.y;
    for (int idx = t; idx < NCTX * DHEAD; idx += 256) {
        int j = idx / DHEAD, d = idx % DHEAD;
        Ksm[idx] = (float)K2[(size_t)j * DIM + h * DHEAD + d];
        Vsm[idx] = (float)V2[(size_t)j * DIM + h * DHEAD + d];
    }
    __syncthreads();
    const int i = blockIdx.x * 256 + t;
    const float qscale = 0.15811388300841897f * 1.4426950408889634f;
    float q[DHEAD];
#pragma unroll
    for (int c = 0; c < 5; ++c) {
        bf16x8 v = *(const bf16x8*)(Q2 + (size_t)i * DIM + h * DHEAD + c * 8);
#pragma unroll
        for (int e = 0; e < 8; ++e) q[c * 8 + e] = (float)v[e] * qscale;
    }
    float s[NCTX];
    float m = -1e30f;
    const float4* K4 = reinterpret_cast<const float4*>(Ksm);
    const float4* V4 = reinterpret_cast<const float4*>(Vsm);
#pragma unroll
    for (int j = 0; j < NCTX; ++j) {
        float acc = 0.f;
#pragma unroll
        for (int d4 = 0; d4 < 10; ++d4) {
            float4 kv = K4[j * 10 + d4];
            acc += q[d4 * 4 + 0] * kv.x + q[d4 * 4 + 1] * kv.y + q[d4 * 4 + 2] * kv.z + q[d4 * 4 + 3] * kv.w;
        }
        s[j] = acc;
        m = fmaxf(m, acc);
    }
    float l = 0.f;
    float out[DHEAD];
#pragma unroll
    for (int d = 0; d < DHEAD; ++d) out[d] = 0.f;
#pragma unroll
    for (int j = 0; j < NCTX; ++j) {
        float p = exp2f(s[j] - m);
        l += p;
#pragma unroll
        for (int d4 = 0; d4 < 10; ++d4) {
            float4 vv = V4[j * 10 + d4];
            out[d4 * 4 + 0] += p * vv.x; out[d4 * 4 + 1] += p * vv.y;
            out[d4 * 4 + 2] += p * vv.z; out[d4 * 4 + 3] += p * vv.w;
        }
    }
    float inv = 1.f / l;
#pragma unroll
    for (int c = 0; c < 5; ++c) {
        bf16x8 o;
#pragma unroll
        for (int e = 0; e < 8; ++e) o[e] = (bf16)(out[c * 8 + e] * inv);
        *(bf16x8*)(O + (size_t)i * DIM + h * DHEAD + c * 8) = o;
    }
}

// ---------------- GEGLU: H [4096][2560] -> G [4096][1280] ----------------
__global__ __launch_bounds__(256)
void geglu_kernel(const bf16* __restrict__ H, bf16* __restrict__ G) {
    size_t idx = (size_t)blockIdx.x * 256 + threadIdx.x;  // one 8-elem chunk
    size_t r = idx / 160;
    size_t c8 = idx % 160;
    bf16x8 val = *(const bf16x8*)(H + r * 2560 + c8 * 8);
    bf16x8 gate = *(const bf16x8*)(H + r * 2560 + 1280 + c8 * 8);
    bf16x8 o;
#pragma unroll
    for (int e = 0; e < 8; ++e) {
        float g = (float)gate[e];
        float gl = 0.5f * g * (1.f + erff(g * 0.70710678118654752f));
        o[e] = (bf16)((float)val[e] * gl);
    }
    *(bf16x8*)(G + r * 1280 + c8 * 8) = o;
}

// ---------------- launch ----------------
extern "C" void kernel_launch(void* const* d_in, const int* in_sizes, int n_in,
                              void* d_out, int out_size, void* d_ws, size_t ws_size,
                              hipStream_t stream) {
    const float* x     = (const float*)d_in[0];
    const float* ctx   = (const float*)d_in[1];
    const float* n1_g  = (const float*)d_in[2];
    const float* n1_b  = (const float*)d_in[3];
    const float* a1_wq = (const float*)d_in[4];
    const float* a1_wk = (const float*)d_in[5];
    const float* a1_wv = (const float*)d_in[6];
    const float* a1_wo = (const float*)d_in[7];
    const float* a1_bo = (const float*)d_in[8];
    const float* n2_g  = (const float*)d_in[9];
    const float* n2_b  = (const float*)d_in[10];
    const float* a2_wq = (const float*)d_in[11];
    const float* a2_wk = (const float*)d_in[12];
    const float* a2_wv = (const float*)d_in[13];
    const float* a2_wo = (const float*)d_in[14];
    const float* a2_bo = (const float*)d_in[15];
    const float* n3_g  = (const float*)d_in[16];
    const float* n3_b  = (const float*)d_in[17];
    const float* ff_w1 = (const float*)d_in[18];
    const float* ff_b1 = (const float*)d_in[19];
    const float* ff_w2 = (const float*)d_in[20];
    const float* ff_b2 = (const float*)d_in[21];

    char* ws = (char*)d_ws;
    size_t off = 0;
    auto alloc = [&](size_t bytes) -> char* {
        char* p = ws + off;
        off += (bytes + 255) & ~(size_t)255;
        return p;
    };
    bf16* lnbuf = (bf16*)alloc((size_t)NTOK * DIM * 2);
    bf16* qbuf  = (bf16*)alloc((size_t)NTOK * DIM * 2);
    bf16* kbuf  = (bf16*)alloc((size_t)NTOK * DIM * 2);
    bf16* vbuf  = (bf16*)alloc((size_t)NTOK * DIM * 2);
    bf16* abuf  = (bf16*)alloc((size_t)NTOK * DIM * 2);
    bf16* hbuf  = (bf16*)alloc((size_t)NTOK * 2 * IFF * 2);
    bf16* gbuf  = (bf16*)alloc((size_t)NTOK * IFF * 2);
    bf16* ctxb  = (bf16*)alloc((size_t)NCTX * CTXD * 2);
    bf16* k2buf = (bf16*)alloc((size_t)NCTX * DIM * 2);
    bf16* v2buf = (bf16*)alloc((size_t)NCTX * DIM * 2);
    bf16* wqT   = (bf16*)alloc((size_t)DIM * DIM * 2);
    bf16* wkT   = (bf16*)alloc((size_t)DIM * DIM * 2);
    bf16* wvT   = (bf16*)alloc((size_t)DIM * DIM * 2);
    bf16* woT   = (bf16*)alloc((size_t)DIM * DIM * 2);
    bf16* q2T   = (bf16*)alloc((size_t)DIM * DIM * 2);
    bf16* k2T   = (bf16*)alloc((size_t)CTXD * DIM * 2);
    bf16* v2T   = (bf16*)alloc((size_t)CTXD * DIM * 2);
    bf16* o2T   = (bf16*)alloc((size_t)DIM * DIM * 2);
    bf16* w1T   = (bf16*)alloc((size_t)DIM * 2 * IFF * 2);
    bf16* w2T   = (bf16*)alloc((size_t)IFF * DIM * 2);
    float* out  = (float*)d_out;

    dim3 tb(32, 8);
    transpose_to_bf16<<<dim3(10, 10), tb, 0, stream>>>(a1_wq, wqT, 320, 320);
    transpose_to_bf16<<<dim3(10, 10), tb, 0, stream>>>(a1_wk, wkT, 320, 320);
    transpose_to_bf16<<<dim3(10, 10), tb, 0, stream>>>(a1_wv, wvT, 320, 320);
    transpose_to_bf16<<<dim3(10, 10), tb, 0, stream>>>(a1_wo, woT, 320, 320);
    transpose_to_bf16<<<dim3(10, 10), tb, 0, stream>>>(a2_wq, q2T, 320, 320);
    transpose_to_bf16<<<dim3(10, 24), tb, 0, stream>>>(a2_wk, k2T, 768, 320);
    transpose_to_bf16<<<dim3(10, 24), tb, 0, stream>>>(a2_wv, v2T, 768, 320);
    transpose_to_bf16<<<dim3(10, 10), tb, 0, stream>>>(a2_wo, o2T, 320, 320);
    transpose_to_bf16<<<dim3(80, 10), tb, 0, stream>>>(ff_w1, w1T, 320, 2560);
    transpose_to_bf16<<<dim3(10, 40), tb, 0, stream>>>(ff_w2, w2T, 1280, 320);
    f32_to_bf16<<<231, 256, 0, stream>>>(ctx, ctxb, NCTX * CTXD);

    // ---- self-attention ----
    layernorm_kernel<<<1024, 256, 0, stream>>>(x, n1_g, n1_b, lnbuf);
    gemm_bf16<0><<<dim3(32, 5), 256, 0, stream>>>(lnbuf, wqT, NTOK, DIM, DIM, qbuf, nullptr, nullptr, nullptr);
    gemm_bf16<0><<<dim3(32, 5), 256, 0, stream>>>(lnbuf, wkT, NTOK, DIM, DIM, kbuf, nullptr, nullptr, nullptr);
    gemm_bf16<0><<<dim3(32, 5), 256, 0, stream>>>(lnbuf, wvT, NTOK, DIM, DIM, vbuf, nullptr, nullptr, nullptr);
    flash_self_attn<<<dim3(64, 8), 256, 0, stream>>>(qbuf, kbuf, vbuf, abuf);
    gemm_bf16<2><<<dim3(32, 5), 256, 0, stream>>>(abuf, woT, NTOK, DIM, DIM, nullptr, out, a1_bo, x);

    // ---- cross-attention ----
    layernorm_kernel<<<1024, 256, 0, stream>>>(out, n2_g, n2_b, lnbuf);
    gemm_bf16<0><<<dim3(32, 5), 256, 0, stream>>>(lnbuf, q2T, NTOK, DIM, DIM, qbuf, nullptr, nullptr, nullptr);
    gemm_bf16<0><<<dim3(1, 5), 256, 0, stream>>>(ctxb, k2T, NCTX, DIM, CTXD, k2buf, nullptr, nullptr, nullptr);
    gemm_bf16<0><<<dim3(1, 5), 256, 0, stream>>>(ctxb, v2T, NCTX, DIM, CTXD, v2buf, nullptr, nullptr, nullptr);
    cross_attn<<<dim3(16, 8), 256, 0, stream>>>(qbuf, k2buf, v2buf, abuf);
    gemm_bf16<2><<<dim3(32, 5), 256, 0, stream>>>(abuf, o2T, NTOK, DIM, DIM, nullptr, out, a2_bo, out);

    // ---- GEGLU FF ----
    layernorm_kernel<<<1024, 256, 0, stream>>>(out, n3_g, n3_b, lnbuf);
    gemm_bf16<1><<<dim3(32, 40), 256, 0, stream>>>(lnbuf, w1T, NTOK, 2 * IFF, DIM, hbuf, nullptr, ff_b1, nullptr);
    geglu_kernel<<<2560, 256, 0, stream>>>(hbuf, gbuf);
    gemm_bf16<2><<<dim3(32, 5), 256, 0, stream>>>(gbuf, w2T, NTOK, DIM, IFF, nullptr, out, ff_b2, out);
}

// Round 2
// 337.453 us; speedup vs baseline: 2.2536x; 2.2536x over previous
//
#include <hip/hip_runtime.h>
#include <hip/hip_bf16.h>
#include <math.h>

typedef __bf16 bf16;
typedef __attribute__((ext_vector_type(8))) __bf16 bf16x8;
typedef __attribute__((ext_vector_type(4))) __bf16 bf16x4;
typedef __attribute__((ext_vector_type(4))) float f32x4;

#define NTOK 4096
#define DIM  320
#define HEADS 8
#define DHEAD 40
#define NCTX 77
#define CTXD 768
#define IFF  1280

#define QSCALE (0.15811388300841897f * 1.4426950408889634f)  // 40^-0.5 * log2(e)

__device__ __forceinline__ bf16x8 bzero8() {
    bf16x8 v;
#pragma unroll
    for (int e = 0; e < 8; ++e) v[e] = (bf16)0.0f;
    return v;
}

// ---------------- transpose + convert fp32 W[K][N] -> bf16 Wt[N][K] ----------
__global__ __launch_bounds__(256)
void transpose_to_bf16(const float* __restrict__ W, bf16* __restrict__ Wt, int K, int N) {
    __shared__ float tile[32][33];
    int n0 = blockIdx.x * 32, k0 = blockIdx.y * 32;
    int tx = threadIdx.x, ty = threadIdx.y;  // (32,8)
#pragma unroll
    for (int i = 0; i < 4; ++i)
        tile[ty + i * 8][tx] = W[(size_t)(k0 + ty + i * 8) * N + n0 + tx];
    __syncthreads();
#pragma unroll
    for (int i = 0; i < 4; ++i)
        Wt[(size_t)(n0 + ty + i * 8) * K + k0 + tx] = (bf16)tile[tx][ty + i * 8];
}

// ---------------- fp32 -> bf16 elementwise ----------------
__global__ void f32_to_bf16(const float* __restrict__ X, bf16* __restrict__ Y, int n) {
    int i = blockIdx.x * 256 + threadIdx.x;
    if (i < n) Y[i] = (bf16)X[i];
}

// ---------------- LayerNorm: fp32 in -> bf16 out, N=320 ----------------
__global__ __launch_bounds__(256)
void layernorm_kernel(const float* __restrict__ X, const float* __restrict__ g,
                      const float* __restrict__ b, bf16* __restrict__ Y) {
    int w = threadIdx.x >> 6, lane = threadIdx.x & 63;
    int row = blockIdx.x * 4 + w;
    const float* xr = X + (size_t)row * DIM;
    float v[5];
    float sum = 0.f;
#pragma unroll
    for (int c = 0; c < 5; ++c) { v[c] = xr[c * 64 + lane]; sum += v[c]; }
#pragma unroll
    for (int off = 1; off < 64; off <<= 1) sum += __shfl_xor(sum, off);
    float mu = sum * (1.f / 320.f);
    float vs = 0.f;
#pragma unroll
    for (int c = 0; c < 5; ++c) { float d = v[c] - mu; vs += d * d; }
#pragma unroll
    for (int off = 1; off < 64; off <<= 1) vs += __shfl_xor(vs, off);
    float rs = rsqrtf(vs * (1.f / 320.f) + 1e-5f);
    bf16* yr = Y + (size_t)row * DIM;
#pragma unroll
    for (int c = 0; c < 5; ++c)
        yr[c * 64 + lane] = (bf16)((v[c] - mu) * rs * g[c * 64 + lane] + b[c * 64 + lane]);
}

// ---------------- generic bf16 MFMA GEMM ----------------
// C[M][N] = A[M][K] @ B  with Bt = B^T row-major [N][K].
// EPI 0: Y0 = bf16(acc)
// EPI 1: Y0 = bf16(acc + bias)
// EPI 2: Yf = acc + bias + res  (fp32)
// EPI 4: Y0 = bf16(acc * QSCALE)
// EPI 5 (fused qkv, N=960): col<320 -> Y0(q)*QSCALE; col<640 -> Y1(k); else transposed pack4 -> Y2[(col-640)*trs + row]
// EPI 6 (fused cross kv, N=640): col<320 -> Y0(k2) [row<M guard]; else transposed pack4 -> Y2[(col-320)*trs + row] (unconditional: pad rows get acc=0)
// BM=128 BN=64 BK=64, 256 threads (4 waves, 2x2), XOR-swizzled LDS.
template <int EPI>
__global__ __launch_bounds__(256)
void gemm_bf16(const bf16* __restrict__ A, const bf16* __restrict__ Bt,
               int M, int N, int K,
               bf16* __restrict__ Y0, bf16* __restrict__ Y1, bf16* __restrict__ Y2,
               float* Yf, const float* __restrict__ bias, const float* res, int trs) {
    __shared__ char smem[24 * 1024];  // A:16KB  B:8KB
    const int t = threadIdx.x;
    const int lane = t & 63;
    const int w = t >> 6;
    const int wr = w >> 1, wc = w & 1;
    const int m0 = blockIdx.x * 128;
    const int n0 = blockIdx.y * 64;

    f32x4 acc[4][2];
#pragma unroll
    for (int mi = 0; mi < 4; ++mi)
#pragma unroll
        for (int ni = 0; ni < 2; ++ni)
#pragma unroll
            for (int r = 0; r < 4; ++r) acc[mi][ni][r] = 0.f;

    for (int k0 = 0; k0 < K; k0 += 64) {
        // stage A tile [128][64] (rows padded with zeros past M)
#pragma unroll
        for (int i = 0; i < 4; ++i) {
            int c = t + i * 256;
            int row = c >> 3, seg = c & 7;
            int gr = m0 + row;
            bf16x8 v = bzero8();
            if (gr < M) v = *(const bf16x8*)(A + (size_t)gr * K + k0 + seg * 8);
            *(bf16x8*)(smem + row * 128 + ((seg * 16) ^ ((row & 7) << 4))) = v;
        }
        // stage Bt tile [64][64]
#pragma unroll
        for (int i = 0; i < 2; ++i) {
            int c = t + i * 256;
            int row = c >> 3, seg = c & 7;
            bf16x8 v = *(const bf16x8*)(Bt + (size_t)(n0 + row) * K + k0 + seg * 8);
            *(bf16x8*)(smem + 16 * 1024 + row * 128 + ((seg * 16) ^ ((row & 7) << 4))) = v;
        }
        __syncthreads();

        bf16x8 a[4][2], bfr[2][2];
#pragma unroll
        for (int mi = 0; mi < 4; ++mi)
#pragma unroll
            for (int kh = 0; kh < 2; ++kh) {
                int row = wr * 64 + mi * 16 + (lane & 15);
                a[mi][kh] = *(const bf16x8*)(smem + row * 128 +
                             ((kh * 64 + (lane >> 4) * 16) ^ ((row & 7) << 4)));
            }
#pragma unroll
        for (int ni = 0; ni < 2; ++ni)
#pragma unroll
            for (int kh = 0; kh < 2; ++kh) {
                int row = wc * 32 + ni * 16 + (lane & 15);
                bfr[ni][kh] = *(const bf16x8*)(smem + 16 * 1024 + row * 128 +
                               ((kh * 64 + (lane >> 4) * 16) ^ ((row & 7) << 4)));
            }
#pragma unroll
        for (int mi = 0; mi < 4; ++mi)
#pragma unroll
            for (int ni = 0; ni < 2; ++ni) {
                acc[mi][ni] = __builtin_amdgcn_mfma_f32_16x16x32_bf16(a[mi][0], bfr[ni][0], acc[mi][ni], 0, 0, 0);
                acc[mi][ni] = __builtin_amdgcn_mfma_f32_16x16x32_bf16(a[mi][1], bfr[ni][1], acc[mi][ni], 0, 0, 0);
            }
        __syncthreads();
    }

#pragma unroll
    for (int mi = 0; mi < 4; ++mi)
#pragma unroll
        for (int ni = 0; ni < 2; ++ni) {
            const int col = n0 + wc * 32 + ni * 16 + (lane & 15);
            const int rowb = m0 + wr * 64 + mi * 16 + (lane >> 4) * 4;
            if (EPI == 5) {
                if (col < 320) {
#pragma unroll
                    for (int r = 0; r < 4; ++r)
                        Y0[(size_t)(rowb + r) * 320 + col] = (bf16)(acc[mi][ni][r] * QSCALE);
                } else if (col < 640) {
#pragma unroll
                    for (int r = 0; r < 4; ++r)
                        Y1[(size_t)(rowb + r) * 320 + (col - 320)] = (bf16)acc[mi][ni][r];
                } else {
                    bf16x4 tv;
#pragma unroll
                    for (int r = 0; r < 4; ++r) tv[r] = (bf16)acc[mi][ni][r];
                    *(bf16x4*)(Y2 + (size_t)(col - 640) * trs + rowb) = tv;
                }
            } else if (EPI == 6) {
                if (col < 320) {
#pragma unroll
                    for (int r = 0; r < 4; ++r)
                        if (rowb + r < M) Y0[(size_t)(rowb + r) * 320 + col] = (bf16)acc[mi][ni][r];
                } else {
                    bf16x4 tv;
#pragma unroll
                    for (int r = 0; r < 4; ++r) tv[r] = (bf16)acc[mi][ni][r];
                    *(bf16x4*)(Y2 + (size_t)(col - 320) * trs + rowb) = tv;
                }
            } else {
#pragma unroll
                for (int r = 0; r < 4; ++r) {
                    int row = rowb + r;
                    if (row < M) {
                        float v = acc[mi][ni][r];
                        if (EPI == 0) Y0[(size_t)row * N + col] = (bf16)v;
                        else if (EPI == 1) Y0[(size_t)row * N + col] = (bf16)(v + bias[col]);
                        else if (EPI == 4) Y0[(size_t)row * N + col] = (bf16)(v * QSCALE);
                        else Yf[(size_t)row * N + col] = v + bias[col] + res[(size_t)row * N + col];
                    }
                }
            }
        }
}

// ---------------- unified flash attention ----------------
// Q bf16 [4096][320] (pre-scaled by QSCALE), K bf16 [nkv][320], VT bf16 [320][vstride] (d-major),
// O bf16 [4096][320]. grid (64, 8): 64 q-rows per block (4 waves x 16), head = blockIdx.y.
// KV tiles of 128, dhead 40 padded to 64 (Q/K pad zeroed). Masking for j >= nkv.
__global__ __launch_bounds__(256)
void flash_attn(const bf16* __restrict__ Qg, const bf16* __restrict__ Kg,
                const bf16* __restrict__ VTg, bf16* __restrict__ O,
                int nkv, int vstride) {
    __shared__ char smem[52 * 1024];
    // K @0: [128][64d] rows 128B | VT @16K: [48d][128j] rows 256B | Qs @28K: +w*2K [16][64] | Ps @36K: +w*4K [16][128]
    const int t = threadIdx.x, lane = t & 63, w = t >> 6;
    const int h = blockIdx.y;
    const int qb = blockIdx.x * 64 + w * 16;
    char* Ks = smem;
    char* Vs = smem + 16 * 1024;
    char* Qs = smem + 28 * 1024 + w * 2048;
    char* Ps = smem + 36 * 1024 + w * 4096;

    // stage this wave's Q rows (already scaled), pad d 40..63 with zero
#pragma unroll
    for (int i = 0; i < 2; ++i) {
        int c = lane + i * 64;
        int row = c >> 3, seg = c & 7;
        bf16x8 v = bzero8();
        if (seg < 5) v = *(const bf16x8*)(Qg + (size_t)(qb + row) * DIM + h * DHEAD + seg * 8);
        *(bf16x8*)(Qs + row * 128 + ((seg * 16) ^ ((row & 7) << 4))) = v;
    }
    bf16x8 qf[2];
#pragma unroll
    for (int kh = 0; kh < 2; ++kh) {
        int row = lane & 15;
        qf[kh] = *(const bf16x8*)(Qs + row * 128 + ((kh * 64 + (lane >> 4) * 16) ^ ((row & 7) << 4)));
    }

    f32x4 accO[3];
#pragma unroll
    for (int dt = 0; dt < 3; ++dt)
#pragma unroll
        for (int r = 0; r < 4; ++r) accO[dt][r] = 0.f;
    float m_run[4], l_run[4];
#pragma unroll
    for (int r = 0; r < 4; ++r) { m_run[r] = -1e30f; l_run[r] = 0.f; }

    const int ntiles = (nkv + 127) >> 7;
    for (int tt = 0; tt < ntiles; ++tt) {
        const int j0 = tt << 7;
        // stage K tile [128 kv][64 d-padded]: 1024 chunks
#pragma unroll
        for (int i = 0; i < 4; ++i) {
            int c = t + i * 256;
            int row = c >> 3, seg = c & 7;
            bf16x8 v = bzero8();
            if (seg < 5 && j0 + row < nkv)
                v = *(const bf16x8*)(Kg + (size_t)(j0 + row) * DIM + h * DHEAD + seg * 8);
            *(bf16x8*)(Ks + row * 128 + ((seg * 16) ^ ((row & 7) << 4))) = v;
        }
        // stage VT tile [48 d][128 j]: 768 chunks (d>=40 zero)
#pragma unroll
        for (int i = 0; i < 3; ++i) {
            int c = t + i * 256;
            int row = c >> 4, seg = c & 15;
            bf16x8 v = bzero8();
            if (row < DHEAD)
                v = *(const bf16x8*)(VTg + (size_t)(h * DHEAD + row) * vstride + j0 + seg * 8);
            *(bf16x8*)(Vs + row * 256 + ((seg * 16) ^ ((row & 7) << 4))) = v;
        }
        __syncthreads();

        // QK^T: s[jt] 16x16 tile, col j = jt*16+(lane&15), row q = (lane>>4)*4+r
        f32x4 s[8];
#pragma unroll
        for (int jt = 0; jt < 8; ++jt) {
            int row = jt * 16 + (lane & 15);
            bf16x8 kb0 = *(const bf16x8*)(Ks + row * 128 + (((lane >> 4) * 16) ^ ((row & 7) << 4)));
            bf16x8 kb1 = *(const bf16x8*)(Ks + row * 128 + ((64 + (lane >> 4) * 16) ^ ((row & 7) << 4)));
            f32x4 z;
#pragma unroll
            for (int r = 0; r < 4; ++r) z[r] = 0.f;
            z = __builtin_amdgcn_mfma_f32_16x16x32_bf16(qf[0], kb0, z, 0, 0, 0);
            z = __builtin_amdgcn_mfma_f32_16x16x32_bf16(qf[1], kb1, z, 0, 0, 0);
            s[jt] = z;
        }
        if (j0 + 128 > nkv) {
#pragma unroll
            for (int jt = 0; jt < 8; ++jt) {
                if (j0 + jt * 16 + (lane & 15) >= nkv) {
#pragma unroll
                    for (int r = 0; r < 4; ++r) s[jt][r] = -1e30f;
                }
            }
        }

        // online softmax (log2 domain) per accumulator row r
        float p[8][4];
#pragma unroll
        for (int r = 0; r < 4; ++r) {
            float mrow = s[0][r];
#pragma unroll
            for (int jt = 1; jt < 8; ++jt) mrow = fmaxf(mrow, s[jt][r]);
#pragma unroll
            for (int off = 1; off < 16; off <<= 1)
                mrow = fmaxf(mrow, __shfl_xor(mrow, off, 16));
            float mnew = fmaxf(m_run[r], mrow);
            float f = exp2f(m_run[r] - mnew);
            m_run[r] = mnew;
            float psum = 0.f;
#pragma unroll
            for (int jt = 0; jt < 8; ++jt) {
                float pv = exp2f(s[jt][r] - mnew);
                p[jt][r] = pv;
                psum += pv;
            }
#pragma unroll
            for (int off = 1; off < 16; off <<= 1)
                psum += __shfl_xor(psum, off, 16);
            l_run[r] = l_run[r] * f + psum;
#pragma unroll
            for (int dt = 0; dt < 3; ++dt) accO[dt][r] *= f;
        }

        // write P tile (bf16) to wave-local LDS [16 q][128 j]
#pragma unroll
        for (int jt = 0; jt < 8; ++jt)
#pragma unroll
            for (int r = 0; r < 4; ++r) {
                int row = (lane >> 4) * 4 + r;
                *(bf16*)(Ps + row * 256 + ((jt * 32 + (lane & 15) * 2) ^ ((row & 7) << 4))) = (bf16)p[jt][r];
            }

        // PV: A = P [16 q][128 j], B = VT [d as col][j as k]
        bf16x8 pa[4];
#pragma unroll
        for (int kh = 0; kh < 4; ++kh) {
            int row = lane & 15;
            pa[kh] = *(const bf16x8*)(Ps + row * 256 + ((kh * 64 + (lane >> 4) * 16) ^ ((row & 7) << 4)));
        }
#pragma unroll
        for (int dt = 0; dt < 3; ++dt) {
            int row = dt * 16 + (lane & 15);
#pragma unroll
            for (int kh = 0; kh < 4; ++kh) {
                bf16x8 vb = *(const bf16x8*)(Vs + row * 256 + ((kh * 64 + (lane >> 4) * 16) ^ ((row & 7) << 4)));
                accO[dt] = __builtin_amdgcn_mfma_f32_16x16x32_bf16(pa[kh], vb, accO[dt], 0, 0, 0);
            }
        }
        __syncthreads();
    }

#pragma unroll
    for (int dt = 0; dt < 3; ++dt)
#pragma unroll
        for (int r = 0; r < 4; ++r) {
            int col = dt * 16 + (lane & 15);
            if (col < DHEAD) {
                int row = qb + (lane >> 4) * 4 + r;
                O[(size_t)row * DIM + h * DHEAD + col] = (bf16)(accO[dt][r] / l_run[r]);
            }
        }
}

// ---------------- GEGLU: H [4096][2560] -> G [4096][1280] ----------------
__global__ __launch_bounds__(256)
void geglu_kernel(const bf16* __restrict__ H, bf16* __restrict__ G) {
    size_t idx = (size_t)blockIdx.x * 256 + threadIdx.x;  // one 8-elem chunk
    size_t r = idx / 160;
    size_t c8 = idx % 160;
    bf16x8 val = *(const bf16x8*)(H + r * 2560 + c8 * 8);
    bf16x8 gate = *(const bf16x8*)(H + r * 2560 + 1280 + c8 * 8);
    bf16x8 o;
#pragma unroll
    for (int e = 0; e < 8; ++e) {
        float g = (float)gate[e];
        float gl = 0.5f * g * (1.f + erff(g * 0.70710678118654752f));
        o[e] = (bf16)((float)val[e] * gl);
    }
    *(bf16x8*)(G + r * 1280 + c8 * 8) = o;
}

// ---------------- launch ----------------
extern "C" void kernel_launch(void* const* d_in, const int* in_sizes, int n_in,
                              void* d_out, int out_size, void* d_ws, size_t ws_size,
                              hipStream_t stream) {
    const float* x     = (const float*)d_in[0];
    const float* ctx   = (const float*)d_in[1];
    const float* n1_g  = (const float*)d_in[2];
    const float* n1_b  = (const float*)d_in[3];
    const float* a1_wq = (const float*)d_in[4];
    const float* a1_wk = (const float*)d_in[5];
    const float* a1_wv = (const float*)d_in[6];
    const float* a1_wo = (const float*)d_in[7];
    const float* a1_bo = (const float*)d_in[8];
    const float* n2_g  = (const float*)d_in[9];
    const float* n2_b  = (const float*)d_in[10];
    const float* a2_wq = (const float*)d_in[11];
    const float* a2_wk = (const float*)d_in[12];
    const float* a2_wv = (const float*)d_in[13];
    const float* a2_wo = (const float*)d_in[14];
    const float* a2_bo = (const float*)d_in[15];
    const float* n2g_  = (const float*)d_in[16];  // n3_g
    const float* n3_b  = (const float*)d_in[17];
    const float* ff_w1 = (const float*)d_in[18];
    const float* ff_b1 = (const float*)d_in[19];
    const float* ff_w2 = (const float*)d_in[20];
    const float* ff_b2 = (const float*)d_in[21];
    const float* n3_g  = n2g_;

    char* ws = (char*)d_ws;
    size_t off = 0;
    auto alloc = [&](size_t bytes) -> char* {
        char* p = ws + off;
        off += (bytes + 255) & ~(size_t)255;
        return p;
    };
    bf16* lnbuf  = (bf16*)alloc((size_t)NTOK * DIM * 2);
    bf16* qbuf   = (bf16*)alloc((size_t)NTOK * DIM * 2);
    bf16* kbuf   = (bf16*)alloc((size_t)NTOK * DIM * 2);
    bf16* vtbuf  = (bf16*)alloc((size_t)DIM * NTOK * 2);   // [320 d-cols][4096 tokens]
    bf16* abuf   = (bf16*)alloc((size_t)NTOK * DIM * 2);
    bf16* hbuf   = (bf16*)alloc((size_t)NTOK * 2 * IFF * 2);
    bf16* gbuf   = (bf16*)alloc((size_t)NTOK * IFF * 2);
    bf16* ctxb   = (bf16*)alloc((size_t)NCTX * CTXD * 2);
    bf16* k2buf  = (bf16*)alloc((size_t)128 * DIM * 2);    // padded rows
    bf16* vt2buf = (bf16*)alloc((size_t)DIM * 128 * 2);    // [320][128]
    bf16* wqkvT  = (bf16*)alloc((size_t)960 * DIM * 2);    // [960][320]
    bf16* woT    = (bf16*)alloc((size_t)DIM * DIM * 2);
    bf16* q2T    = (bf16*)alloc((size_t)DIM * DIM * 2);
    bf16* wkv2T  = (bf16*)alloc((size_t)640 * CTXD * 2);   // [640][768]
    bf16* o2T    = (bf16*)alloc((size_t)DIM * DIM * 2);
    bf16* w1T    = (bf16*)alloc((size_t)2 * IFF * DIM * 2);
    bf16* w2T    = (bf16*)alloc((size_t)IFF * DIM * 2);
    float* out   = (float*)d_out;

    dim3 tb(32, 8);
    transpose_to_bf16<<<dim3(10, 10), tb, 0, stream>>>(a1_wq, wqkvT, 320, 320);
    transpose_to_bf16<<<dim3(10, 10), tb, 0, stream>>>(a1_wk, wqkvT + (size_t)320 * 320, 320, 320);
    transpose_to_bf16<<<dim3(10, 10), tb, 0, stream>>>(a1_wv, wqkvT + (size_t)640 * 320, 320, 320);
    transpose_to_bf16<<<dim3(10, 10), tb, 0, stream>>>(a1_wo, woT, 320, 320);
    transpose_to_bf16<<<dim3(10, 10), tb, 0, stream>>>(a2_wq, q2T, 320, 320);
    transpose_to_bf16<<<dim3(10, 24), tb, 0, stream>>>(a2_wk, wkv2T, 768, 320);
    transpose_to_bf16<<<dim3(10, 24), tb, 0, stream>>>(a2_wv, wkv2T + (size_t)320 * 768, 768, 320);
    transpose_to_bf16<<<dim3(10, 10), tb, 0, stream>>>(a2_wo, o2T, 320, 320);
    transpose_to_bf16<<<dim3(80, 10), tb, 0, stream>>>(ff_w1, w1T, 320, 2560);
    transpose_to_bf16<<<dim3(10, 40), tb, 0, stream>>>(ff_w2, w2T, 1280, 320);
    f32_to_bf16<<<231, 256, 0, stream>>>(ctx, ctxb, NCTX * CTXD);

    // ---- self-attention ----
    layernorm_kernel<<<1024, 256, 0, stream>>>(x, n1_g, n1_b, lnbuf);
    gemm_bf16<5><<<dim3(32, 15), 256, 0, stream>>>(lnbuf, wqkvT, NTOK, 960, DIM,
                                                   qbuf, kbuf, vtbuf, nullptr, nullptr, nullptr, NTOK);
    flash_attn<<<dim3(64, 8), 256, 0, stream>>>(qbuf, kbuf, vtbuf, abuf, NTOK, NTOK);
    gemm_bf16<2><<<dim3(32, 5), 256, 0, stream>>>(abuf, woT, NTOK, DIM, DIM,
                                                  nullptr, nullptr, nullptr, out, a1_bo, x, 0);

    // ---- cross-attention ----
    layernorm_kernel<<<1024, 256, 0, stream>>>(out, n2_g, n2_b, lnbuf);
    gemm_bf16<4><<<dim3(32, 5), 256, 0, stream>>>(lnbuf, q2T, NTOK, DIM, DIM,
                                                  qbuf, nullptr, nullptr, nullptr, nullptr, nullptr, 0);
    gemm_bf16<6><<<dim3(1, 10), 256, 0, stream>>>(ctxb, wkv2T, NCTX, 640, CTXD,
                                                  k2buf, nullptr, vt2buf, nullptr, nullptr, nullptr, 128);
    flash_attn<<<dim3(64, 8), 256, 0, stream>>>(qbuf, k2buf, vt2buf, abuf, NCTX, 128);
    gemm_bf16<2><<<dim3(32, 5), 256, 0, stream>>>(abuf, o2T, NTOK, DIM, DIM,
                                                  nullptr, nullptr, nullptr, out, a2_bo, out, 0);

    // ---- GEGLU FF ----
    layernorm_kernel<<<1024, 256, 0, stream>>>(out, n3_g, n3_b, lnbuf);
    gemm_bf16<1><<<dim3(32, 40), 256, 0, stream>>>(lnbuf, w1T, NTOK, 2 * IFF, DIM,
                                                   hbuf, nullptr, nullptr, nullptr, ff_b1, nullptr, 0);
    geglu_kernel<<<2560, 256, 0, stream>>>(hbuf, gbuf);
    gemm_bf16<2><<<dim3(32, 5), 256, 0, stream>>>(gbuf, w2T, NTOK, DIM, IFF,
                                                  nullptr, nullptr, nullptr, out, ff_b2, out, 0);
}

// Round 3
// 322.878 us; speedup vs baseline: 2.3554x; 1.0451x over previous
//
#include <hip/hip_runtime.h>
#include <hip/hip_bf16.h>
#include <math.h>

typedef __bf16 bf16;
typedef __attribute__((ext_vector_type(8))) __bf16 bf16x8;
typedef __attribute__((ext_vector_type(4))) __bf16 bf16x4;
typedef __attribute__((ext_vector_type(4))) float f32x4;
typedef __attribute__((ext_vector_type(2))) float f32x2;
typedef __attribute__((ext_vector_type(4))) short shortx4;

#define NTOK 4096
#define DIM  320
#define HEADS 8
#define DHEAD 40
#define NCTX 77
#define CTXD 768
#define IFF  1280

#define QSCALE (0.15811388300841897f * 1.4426950408889634f)  // 40^-0.5 * log2(e)

__device__ __forceinline__ bf16x8 bzero8() {
    bf16x8 v;
#pragma unroll
    for (int e = 0; e < 8; ++e) v[e] = (bf16)0.0f;
    return v;
}

// ---------------- transpose + convert fp32 W[K][N] -> bf16 Wt[N][K] ----------
__global__ __launch_bounds__(256)
void transpose_to_bf16(const float* __restrict__ W, bf16* __restrict__ Wt, int K, int N) {
    __shared__ float tile[32][33];
    int n0 = blockIdx.x * 32, k0 = blockIdx.y * 32;
    int tx = threadIdx.x, ty = threadIdx.y;  // (32,8)
#pragma unroll
    for (int i = 0; i < 4; ++i)
        tile[ty + i * 8][tx] = W[(size_t)(k0 + ty + i * 8) * N + n0 + tx];
    __syncthreads();
#pragma unroll
    for (int i = 0; i < 4; ++i)
        Wt[(size_t)(n0 + ty + i * 8) * K + k0 + tx] = (bf16)tile[tx][ty + i * 8];
}

// ---------------- fp32 -> bf16 elementwise ----------------
__global__ void f32_to_bf16(const float* __restrict__ X, bf16* __restrict__ Y, int n) {
    int i = blockIdx.x * 256 + threadIdx.x;
    if (i < n) Y[i] = (bf16)X[i];
}

// ---------------- LayerNorm: fp32 in -> bf16 out, N=320 ----------------
__global__ __launch_bounds__(256)
void layernorm_kernel(const float* __restrict__ X, const float* __restrict__ g,
                      const float* __restrict__ b, bf16* __restrict__ Y) {
    int w = threadIdx.x >> 6, lane = threadIdx.x & 63;
    int row = blockIdx.x * 4 + w;
    const float* xr = X + (size_t)row * DIM;
    float v[5];
    float sum = 0.f;
#pragma unroll
    for (int c = 0; c < 5; ++c) { v[c] = xr[c * 64 + lane]; sum += v[c]; }
#pragma unroll
    for (int off = 1; off < 64; off <<= 1) sum += __shfl_xor(sum, off);
    float mu = sum * (1.f / 320.f);
    float vs = 0.f;
#pragma unroll
    for (int c = 0; c < 5; ++c) { float d = v[c] - mu; vs += d * d; }
#pragma unroll
    for (int off = 1; off < 64; off <<= 1) vs += __shfl_xor(vs, off);
    float rs = rsqrtf(vs * (1.f / 320.f) + 1e-5f);
    bf16* yr = Y + (size_t)row * DIM;
#pragma unroll
    for (int c = 0; c < 5; ++c)
        yr[c * 64 + lane] = (bf16)((v[c] - mu) * rs * g[c * 64 + lane] + b[c * 64 + lane]);
}

// ---------------- generic bf16 MFMA GEMM ----------------
// C[M][N] = A[M][K] @ B  with Bt = B^T row-major [N][K].
// EPI 0: Y0 = bf16(acc)
// EPI 1: Y0 = bf16(acc + bias)
// EPI 2: Yf = acc + bias + res  (fp32)
// EPI 4: Y0 = bf16(acc * QSCALE)
// EPI 5 (fused qkv, N=960): col<320 -> Y0(q)*QSCALE; col<640 -> Y1(k); else transposed pack4 -> Y2[(col-640)*trs + row]
// EPI 6 (fused cross kv, N=640): col<320 -> Y0(k2) [row<M guard]; else transposed pack4 -> Y2[(col-320)*trs + row]
// BM=128 BN=64 BK=64, 256 threads (4 waves, 2x2), XOR-swizzled LDS.
template <int EPI>
__global__ __launch_bounds__(256)
void gemm_bf16(const bf16* __restrict__ A, const bf16* __restrict__ Bt,
               int M, int N, int K,
               bf16* __restrict__ Y0, bf16* __restrict__ Y1, bf16* __restrict__ Y2,
               float* Yf, const float* __restrict__ bias, const float* res, int trs) {
    __shared__ char smem[24 * 1024];  // A:16KB  B:8KB
    const int t = threadIdx.x;
    const int lane = t & 63;
    const int w = t >> 6;
    const int wr = w >> 1, wc = w & 1;
    const int m0 = blockIdx.x * 128;
    const int n0 = blockIdx.y * 64;

    f32x4 acc[4][2];
#pragma unroll
    for (int mi = 0; mi < 4; ++mi)
#pragma unroll
        for (int ni = 0; ni < 2; ++ni)
#pragma unroll
            for (int r = 0; r < 4; ++r) acc[mi][ni][r] = 0.f;

    for (int k0 = 0; k0 < K; k0 += 64) {
        // stage A tile [128][64] (rows padded with zeros past M)
#pragma unroll
        for (int i = 0; i < 4; ++i) {
            int c = t + i * 256;
            int row = c >> 3, seg = c & 7;
            int gr = m0 + row;
            bf16x8 v = bzero8();
            if (gr < M) v = *(const bf16x8*)(A + (size_t)gr * K + k0 + seg * 8);
            *(bf16x8*)(smem + row * 128 + ((seg * 16) ^ ((row & 7) << 4))) = v;
        }
        // stage Bt tile [64][64]
#pragma unroll
        for (int i = 0; i < 2; ++i) {
            int c = t + i * 256;
            int row = c >> 3, seg = c & 7;
            bf16x8 v = *(const bf16x8*)(Bt + (size_t)(n0 + row) * K + k0 + seg * 8);
            *(bf16x8*)(smem + 16 * 1024 + row * 128 + ((seg * 16) ^ ((row & 7) << 4))) = v;
        }
        __syncthreads();

        bf16x8 a[4][2], bfr[2][2];
#pragma unroll
        for (int mi = 0; mi < 4; ++mi)
#pragma unroll
            for (int kh = 0; kh < 2; ++kh) {
                int row = wr * 64 + mi * 16 + (lane & 15);
                a[mi][kh] = *(const bf16x8*)(smem + row * 128 +
                             ((kh * 64 + (lane >> 4) * 16) ^ ((row & 7) << 4)));
            }
#pragma unroll
        for (int ni = 0; ni < 2; ++ni)
#pragma unroll
            for (int kh = 0; kh < 2; ++kh) {
                int row = wc * 32 + ni * 16 + (lane & 15);
                bfr[ni][kh] = *(const bf16x8*)(smem + 16 * 1024 + row * 128 +
                               ((kh * 64 + (lane >> 4) * 16) ^ ((row & 7) << 4)));
            }
#pragma unroll
        for (int mi = 0; mi < 4; ++mi)
#pragma unroll
            for (int ni = 0; ni < 2; ++ni) {
                acc[mi][ni] = __builtin_amdgcn_mfma_f32_16x16x32_bf16(a[mi][0], bfr[ni][0], acc[mi][ni], 0, 0, 0);
                acc[mi][ni] = __builtin_amdgcn_mfma_f32_16x16x32_bf16(a[mi][1], bfr[ni][1], acc[mi][ni], 0, 0, 0);
            }
        __syncthreads();
    }

#pragma unroll
    for (int mi = 0; mi < 4; ++mi)
#pragma unroll
        for (int ni = 0; ni < 2; ++ni) {
            const int col = n0 + wc * 32 + ni * 16 + (lane & 15);
            const int rowb = m0 + wr * 64 + mi * 16 + (lane >> 4) * 4;
            if (EPI == 5) {
                if (col < 320) {
#pragma unroll
                    for (int r = 0; r < 4; ++r)
                        Y0[(size_t)(rowb + r) * 320 + col] = (bf16)(acc[mi][ni][r] * QSCALE);
                } else if (col < 640) {
#pragma unroll
                    for (int r = 0; r < 4; ++r)
                        Y1[(size_t)(rowb + r) * 320 + (col - 320)] = (bf16)acc[mi][ni][r];
                } else {
                    bf16x4 tv;
#pragma unroll
                    for (int r = 0; r < 4; ++r) tv[r] = (bf16)acc[mi][ni][r];
                    *(bf16x4*)(Y2 + (size_t)(col - 640) * trs + rowb) = tv;
                }
            } else if (EPI == 6) {
                if (col < 320) {
#pragma unroll
                    for (int r = 0; r < 4; ++r)
                        if (rowb + r < M) Y0[(size_t)(rowb + r) * 320 + col] = (bf16)acc[mi][ni][r];
                } else {
                    bf16x4 tv;
#pragma unroll
                    for (int r = 0; r < 4; ++r) tv[r] = (bf16)acc[mi][ni][r];
                    *(bf16x4*)(Y2 + (size_t)(col - 320) * trs + rowb) = tv;
                }
            } else {
#pragma unroll
                for (int r = 0; r < 4; ++r) {
                    int row = rowb + r;
                    if (row < M) {
                        float v = acc[mi][ni][r];
                        if (EPI == 0) Y0[(size_t)row * N + col] = (bf16)v;
                        else if (EPI == 1) Y0[(size_t)row * N + col] = (bf16)(v + bias[col]);
                        else if (EPI == 4) Y0[(size_t)row * N + col] = (bf16)(v * QSCALE);
                        else Yf[(size_t)row * N + col] = v + bias[col] + res[(size_t)row * N + col];
                    }
                }
            }
        }
}

// ---------------- flash attention v2: swapped QK^T, in-register softmax ------
// Q bf16 [4096][320] pre-scaled, K bf16 [nkv-ish][320], VT bf16 [320][vstride].
// grid (64, 8, nsplit). 4 waves x 16 q-rows. KV tiles of 128.
// Swapped S^T = mfma(K_frag, Q_frag): lane owns S[k=jt*16+g*4+r][q=lane&15].
// PV via mfma_16x16x16 (B-frag k = g*4+j matches ownership -> no exchange).
// DIRECT=1: write bf16 O. DIRECT=0: write fp32 partials (accO, m, l) per split.
template <int DIRECT>
__global__ __launch_bounds__(256)
void flash_attn2(const bf16* __restrict__ Qg, const bf16* __restrict__ Kg,
                 const bf16* __restrict__ VTg, bf16* __restrict__ O,
                 float* __restrict__ Opart, float* __restrict__ MLpart,
                 int nkv, int vstride, int tiles_per_split) {
    __shared__ char smem[36 * 1024];
    // K @0: [128][64d] rows 128B | VT @16K: [48d][128j] rows 256B | Qs @28K: +w*2K [16][64]
    const int t = threadIdx.x, lane = t & 63, w = t >> 6;
    const int g = lane >> 4, q = lane & 15;
    const int h = blockIdx.y, split = blockIdx.z;
    const int qb = blockIdx.x * 64 + w * 16;
    char* Ks = smem;
    char* Vs = smem + 16 * 1024;
    char* Qs = smem + 28 * 1024 + w * 2048;

    // stage this wave's Q rows (already scaled), pad d 40..63 with zero
#pragma unroll
    for (int i = 0; i < 2; ++i) {
        int c = lane + i * 64;
        int row = c >> 3, seg = c & 7;
        bf16x8 v = bzero8();
        if (seg < 5) v = *(const bf16x8*)(Qg + (size_t)(qb + row) * DIM + h * DHEAD + seg * 8);
        *(bf16x8*)(Qs + row * 128 + ((seg * 16) ^ ((row & 7) << 4))) = v;
    }
    bf16x8 qf[2];
#pragma unroll
    for (int kh = 0; kh < 2; ++kh) {
        qf[kh] = *(const bf16x8*)(Qs + q * 128 + ((kh * 64 + g * 16) ^ ((q & 7) << 4)));
    }

    f32x4 accO[3];
#pragma unroll
    for (int dt = 0; dt < 3; ++dt)
#pragma unroll
        for (int r = 0; r < 4; ++r) accO[dt][r] = 0.f;
    float m_run = -1e30f, l_run = 0.f;

    const int ntiles = (nkv + 127) >> 7;
    int tt0 = split * tiles_per_split;
    int tt1 = tt0 + tiles_per_split;
    if (tt1 > ntiles) tt1 = ntiles;
    for (int tt = tt0; tt < tt1; ++tt) {
        const int j0 = tt << 7;
        // stage K tile [128 kv][64 d-padded]
#pragma unroll
        for (int i = 0; i < 4; ++i) {
            int c = t + i * 256;
            int row = c >> 3, seg = c & 7;
            bf16x8 v = bzero8();
            if (seg < 5 && j0 + row < nkv)
                v = *(const bf16x8*)(Kg + (size_t)(j0 + row) * DIM + h * DHEAD + seg * 8);
            *(bf16x8*)(Ks + row * 128 + ((seg * 16) ^ ((row & 7) << 4))) = v;
        }
        // stage VT tile [48 d][128 j] (d>=40 zero)
#pragma unroll
        for (int i = 0; i < 3; ++i) {
            int c = t + i * 256;
            int row = c >> 4, seg = c & 15;
            bf16x8 v = bzero8();
            if (row < DHEAD)
                v = *(const bf16x8*)(VTg + (size_t)(h * DHEAD + row) * vstride + j0 + seg * 8);
            *(bf16x8*)(Vs + row * 256 + ((seg * 16) ^ ((row & 7) << 4))) = v;
        }
        __syncthreads();

        // swapped QK^T: s[jt] = S^T tile; lane holds k=jt*16+g*4+r, q=lane&15
        f32x4 s[8];
#pragma unroll
        for (int jt = 0; jt < 8; ++jt) {
            int row = jt * 16 + q;
            bf16x8 kb0 = *(const bf16x8*)(Ks + row * 128 + ((g * 16) ^ ((row & 7) << 4)));
            bf16x8 kb1 = *(const bf16x8*)(Ks + row * 128 + ((64 + g * 16) ^ ((row & 7) << 4)));
            f32x4 z;
#pragma unroll
            for (int r = 0; r < 4; ++r) z[r] = 0.f;
            z = __builtin_amdgcn_mfma_f32_16x16x32_bf16(kb0, qf[0], z, 0, 0, 0);
            z = __builtin_amdgcn_mfma_f32_16x16x32_bf16(kb1, qf[1], z, 0, 0, 0);
            s[jt] = z;
        }
        if (j0 + 128 > nkv) {
#pragma unroll
            for (int jt = 0; jt < 8; ++jt)
#pragma unroll
                for (int r = 0; r < 4; ++r)
                    if (j0 + jt * 16 + g * 4 + r >= nkv) s[jt][r] = -1e30f;
        }

        // in-register row reduce (full row = this lane's 32 + 3 partner lanes)
        f32x4 mv = s[0];
#pragma unroll
        for (int jt = 1; jt < 8; ++jt)
#pragma unroll
            for (int r = 0; r < 4; ++r) mv[r] = fmaxf(mv[r], s[jt][r]);
        float mt = fmaxf(fmaxf(mv[0], mv[1]), fmaxf(mv[2], mv[3]));
        mt = fmaxf(mt, __shfl_xor(mt, 16));
        mt = fmaxf(mt, __shfl_xor(mt, 32));
        float mnew = fmaxf(m_run, mt);
        float f = exp2f(m_run - mnew);
        m_run = mnew;
        float ps = 0.f;
#pragma unroll
        for (int jt = 0; jt < 8; ++jt)
#pragma unroll
            for (int r = 0; r < 4; ++r) {
                float pv = exp2f(s[jt][r] - mnew);
                s[jt][r] = pv;
                ps += pv;
            }
        ps += __shfl_xor(ps, 16);
        ps += __shfl_xor(ps, 32);
        l_run = l_run * f + ps;
#pragma unroll
        for (int dt = 0; dt < 3; ++dt)
#pragma unroll
            for (int r = 0; r < 4; ++r) accO[dt][r] *= f;

        // pack P to bf16 (each lane keeps its own 4 k per jt)
        union PU { bf16x4 h; shortx4 s4; } pk[8];
#pragma unroll
        for (int jt = 0; jt < 8; ++jt) {
            bf16x4 hv;
#pragma unroll
            for (int r = 0; r < 4; ++r) hv[r] = (bf16)s[jt][r];
            pk[jt].h = hv;
        }

        // PV: O^T[d][q] += V^T[d][k] * P^T[k][q] via 16x16x16 (K=16 per jt)
#pragma unroll
        for (int dt = 0; dt < 3; ++dt) {
            int row = dt * 16 + q;
            char* vrow = Vs + row * 256;
            int sw = (row & 7) << 4;
#pragma unroll
            for (int jt = 0; jt < 8; ++jt) {
                shortx4 vb = *(const shortx4*)(vrow + ((jt * 32 + g * 8) ^ sw));
                accO[dt] = __builtin_amdgcn_mfma_f32_16x16x16bf16_1k(vb, pk[jt].s4, accO[dt], 0, 0, 0);
            }
        }
        __syncthreads();
    }

    if (DIRECT) {
        float inv = 1.f / l_run;
#pragma unroll
        for (int dt = 0; dt < 3; ++dt) {
            if (dt < 2 || g < 2) {
                bf16x4 o;
#pragma unroll
                for (int r = 0; r < 4; ++r) o[r] = (bf16)(accO[dt][r] * inv);
                *(bf16x4*)(O + (size_t)(qb + q) * DIM + h * DHEAD + dt * 16 + g * 4) = o;
            }
        }
    } else {
        size_t rowi = (size_t)(split * HEADS + h) * NTOK + qb + q;
#pragma unroll
        for (int dt = 0; dt < 3; ++dt) {
            if (dt < 2 || g < 2)
                *(f32x4*)(Opart + rowi * 40 + dt * 16 + g * 4) = accO[dt];
        }
        if (lane < 16) {
            f32x2 ml;
            ml[0] = m_run; ml[1] = l_run;
            *(f32x2*)(MLpart + rowi * 2) = ml;
        }
    }
}

// ---------------- combine 2 KV-splits ----------------
__global__ __launch_bounds__(256)
void flash_combine(const float* __restrict__ Opart, const float* __restrict__ MLpart,
                   bf16* __restrict__ O) {
    int idx = blockIdx.x * 256 + threadIdx.x;  // 4096*40
    int qi = idx / 40, c = idx - qi * 40;
    int h = c / 5, c8 = c - h * 5;
    size_t r0 = (size_t)h * NTOK + qi;
    size_t r1 = (size_t)(HEADS + h) * NTOK + qi;
    f32x2 ml0 = *(const f32x2*)(MLpart + r0 * 2);
    f32x2 ml1 = *(const f32x2*)(MLpart + r1 * 2);
    float M = fmaxf(ml0[0], ml1[0]);
    float w0 = exp2f(ml0[0] - M), w1 = exp2f(ml1[0] - M);
    float inv = 1.f / (w0 * ml0[1] + w1 * ml1[1]);
    const float* o0 = Opart + r0 * 40 + c8 * 8;
    const float* o1 = Opart + r1 * 40 + c8 * 8;
    bf16x4 a, b;
#pragma unroll
    for (int e = 0; e < 4; ++e) a[e] = (bf16)((o0[e] * w0 + o1[e] * w1) * inv);
#pragma unroll
    for (int e = 0; e < 4; ++e) b[e] = (bf16)((o0[4 + e] * w0 + o1[4 + e] * w1) * inv);
    bf16* dst = O + (size_t)qi * DIM + h * DHEAD + c8 * 8;
    *(bf16x4*)dst = a;
    *(bf16x4*)(dst + 4) = b;
}

// ---------------- GEGLU: H [4096][2560] -> G [4096][1280] ----------------
__global__ __launch_bounds__(256)
void geglu_kernel(const bf16* __restrict__ H, bf16* __restrict__ G) {
    size_t idx = (size_t)blockIdx.x * 256 + threadIdx.x;  // one 8-elem chunk
    size_t r = idx / 160;
    size_t c8 = idx % 160;
    bf16x8 val = *(const bf16x8*)(H + r * 2560 + c8 * 8);
    bf16x8 gate = *(const bf16x8*)(H + r * 2560 + 1280 + c8 * 8);
    bf16x8 o;
#pragma unroll
    for (int e = 0; e < 8; ++e) {
        float gg = (float)gate[e];
        float gl = 0.5f * gg * (1.f + erff(gg * 0.70710678118654752f));
        o[e] = (bf16)((float)val[e] * gl);
    }
    *(bf16x8*)(G + r * 1280 + c8 * 8) = o;
}

// ---------------- launch ----------------
extern "C" void kernel_launch(void* const* d_in, const int* in_sizes, int n_in,
                              void* d_out, int out_size, void* d_ws, size_t ws_size,
                              hipStream_t stream) {
    const float* x     = (const float*)d_in[0];
    const float* ctx   = (const float*)d_in[1];
    const float* n1_g  = (const float*)d_in[2];
    const float* n1_b  = (const float*)d_in[3];
    const float* a1_wq = (const float*)d_in[4];
    const float* a1_wk = (const float*)d_in[5];
    const float* a1_wv = (const float*)d_in[6];
    const float* a1_wo = (const float*)d_in[7];
    const float* a1_bo = (const float*)d_in[8];
    const float* n2_g  = (const float*)d_in[9];
    const float* n2_b  = (const float*)d_in[10];
    const float* a2_wq = (const float*)d_in[11];
    const float* a2_wk = (const float*)d_in[12];
    const float* a2_wv = (const float*)d_in[13];
    const float* a2_wo = (const float*)d_in[14];
    const float* a2_bo = (const float*)d_in[15];
    const float* n3_g  = (const float*)d_in[16];
    const float* n3_b  = (const float*)d_in[17];
    const float* ff_w1 = (const float*)d_in[18];
    const float* ff_b1 = (const float*)d_in[19];
    const float* ff_w2 = (const float*)d_in[20];
    const float* ff_b2 = (const float*)d_in[21];

    char* ws = (char*)d_ws;
    size_t off = 0;
    auto alloc = [&](size_t bytes) -> char* {
        char* p = ws + off;
        off += (bytes + 255) & ~(size_t)255;
        return p;
    };
    bf16* lnbuf  = (bf16*)alloc((size_t)NTOK * DIM * 2);
    bf16* qbuf   = (bf16*)alloc((size_t)NTOK * DIM * 2);
    bf16* kbuf   = (bf16*)alloc((size_t)NTOK * DIM * 2);
    bf16* vtbuf  = (bf16*)alloc((size_t)DIM * NTOK * 2);   // [320 d-cols][4096 tokens]
    bf16* abuf   = (bf16*)alloc((size_t)NTOK * DIM * 2);
    bf16* hbuf   = (bf16*)alloc((size_t)NTOK * 2 * IFF * 2);
    bf16* gbuf   = (bf16*)alloc((size_t)NTOK * IFF * 2);
    bf16* ctxb   = (bf16*)alloc((size_t)NCTX * CTXD * 2);
    bf16* k2buf  = (bf16*)alloc((size_t)128 * DIM * 2);    // padded rows
    bf16* vt2buf = (bf16*)alloc((size_t)DIM * 128 * 2);    // [320][128]
    bf16* wqkvT  = (bf16*)alloc((size_t)960 * DIM * 2);    // [960][320]
    bf16* woT    = (bf16*)alloc((size_t)DIM * DIM * 2);
    bf16* q2T    = (bf16*)alloc((size_t)DIM * DIM * 2);
    bf16* wkv2T  = (bf16*)alloc((size_t)640 * CTXD * 2);   // [640][768]
    bf16* o2T    = (bf16*)alloc((size_t)DIM * DIM * 2);
    bf16* w1T    = (bf16*)alloc((size_t)2 * IFF * DIM * 2);
    bf16* w2T    = (bf16*)alloc((size_t)IFF * DIM * 2);
    float* out   = (float*)d_out;

    // flash partials alias hbuf (hbuf only used in FF phase, after attention)
    float* Opart  = (float*)hbuf;                         // 2*8*4096*40 f32 = 10.5 MB
    float* MLpart = Opart + (size_t)2 * HEADS * NTOK * 40; // 2*8*4096*2 f32

    dim3 tb(32, 8);
    transpose_to_bf16<<<dim3(10, 10), tb, 0, stream>>>(a1_wq, wqkvT, 320, 320);
    transpose_to_bf16<<<dim3(10, 10), tb, 0, stream>>>(a1_wk, wqkvT + (size_t)320 * 320, 320, 320);
    transpose_to_bf16<<<dim3(10, 10), tb, 0, stream>>>(a1_wv, wqkvT + (size_t)640 * 320, 320, 320);
    transpose_to_bf16<<<dim3(10, 10), tb, 0, stream>>>(a1_wo, woT, 320, 320);
    transpose_to_bf16<<<dim3(10, 10), tb, 0, stream>>>(a2_wq, q2T, 320, 320);
    transpose_to_bf16<<<dim3(10, 24), tb, 0, stream>>>(a2_wk, wkv2T, 768, 320);
    transpose_to_bf16<<<dim3(10, 24), tb, 0, stream>>>(a2_wv, wkv2T + (size_t)320 * 768, 768, 320);
    transpose_to_bf16<<<dim3(10, 10), tb, 0, stream>>>(a2_wo, o2T, 320, 320);
    transpose_to_bf16<<<dim3(80, 10), tb, 0, stream>>>(ff_w1, w1T, 320, 2560);
    transpose_to_bf16<<<dim3(10, 40), tb, 0, stream>>>(ff_w2, w2T, 1280, 320);
    f32_to_bf16<<<231, 256, 0, stream>>>(ctx, ctxb, NCTX * CTXD);

    // ---- self-attention ----
    layernorm_kernel<<<1024, 256, 0, stream>>>(x, n1_g, n1_b, lnbuf);
    gemm_bf16<5><<<dim3(32, 15), 256, 0, stream>>>(lnbuf, wqkvT, NTOK, 960, DIM,
                                                   qbuf, kbuf, vtbuf, nullptr, nullptr, nullptr, NTOK);
    flash_attn2<0><<<dim3(64, 8, 2), 256, 0, stream>>>(qbuf, kbuf, vtbuf, nullptr,
                                                       Opart, MLpart, NTOK, NTOK, 16);
    flash_combine<<<640, 256, 0, stream>>>(Opart, MLpart, abuf);
    gemm_bf16<2><<<dim3(32, 5), 256, 0, stream>>>(abuf, woT, NTOK, DIM, DIM,
                                                  nullptr, nullptr, nullptr, out, a1_bo, x, 0);

    // ---- cross-attention ----
    layernorm_kernel<<<1024, 256, 0, stream>>>(out, n2_g, n2_b, lnbuf);
    gemm_bf16<4><<<dim3(32, 5), 256, 0, stream>>>(lnbuf, q2T, NTOK, DIM, DIM,
                                                  qbuf, nullptr, nullptr, nullptr, nullptr, nullptr, 0);
    gemm_bf16<6><<<dim3(1, 10), 256, 0, stream>>>(ctxb, wkv2T, NCTX, 640, CTXD,
                                                  k2buf, nullptr, vt2buf, nullptr, nullptr, nullptr, 128);
    flash_attn2<1><<<dim3(64, 8, 1), 256, 0, stream>>>(qbuf, k2buf, vt2buf, abuf,
                                                       nullptr, nullptr, NCTX, 128, 1);
    gemm_bf16<2><<<dim3(32, 5), 256, 0, stream>>>(abuf, o2T, NTOK, DIM, DIM,
                                                  nullptr, nullptr, nullptr, out, a2_bo, out, 0);

    // ---- GEGLU FF ----
    layernorm_kernel<<<1024, 256, 0, stream>>>(out, n3_g, n3_b, lnbuf);
    gemm_bf16<1><<<dim3(32, 40), 256, 0, stream>>>(lnbuf, w1T, NTOK, 2 * IFF, DIM,
                                                   hbuf, nullptr, nullptr, nullptr, ff_b1, nullptr, 0);
    geglu_kernel<<<2560, 256, 0, stream>>>(hbuf, gbuf);
    gemm_bf16<2><<<dim3(32, 5), 256, 0, stream>>>(gbuf, w2T, NTOK, DIM, IFF,
                                                  nullptr, nullptr, nullptr, out, ff_b2, out, 0);
}

// Round 4
// 235.952 us; speedup vs baseline: 3.2231x; 1.3684x over previous
//
#include <hip/hip_runtime.h>
#include <hip/hip_bf16.h>
#include <math.h>

typedef __bf16 bf16;
typedef __attribute__((ext_vector_type(8))) __bf16 bf16x8;
typedef __attribute__((ext_vector_type(4))) __bf16 bf16x4;
typedef __attribute__((ext_vector_type(4))) float f32x4;
typedef __attribute__((ext_vector_type(2))) float f32x2;
typedef __attribute__((ext_vector_type(4))) short shortx4;

#define NTOK 4096
#define DIM  320
#define HEADS 8
#define DHEAD 40
#define NCTX 77
#define CTXD 768
#define IFF  1280

#define QSCALE (0.15811388300841897f * 1.4426950408889634f)  // 40^-0.5 * log2(e)

__device__ __forceinline__ bf16x8 bzero8() {
    bf16x8 v;
#pragma unroll
    for (int e = 0; e < 8; ++e) v[e] = (bf16)0.0f;
    return v;
}

__device__ __forceinline__ void gld_lds16(const void* g, void* l) {
    __builtin_amdgcn_global_load_lds(
        (const __attribute__((address_space(1))) void*)g,
        (__attribute__((address_space(3))) void*)l, 16, 0, 0);
}

// ---------------- transpose + convert fp32 W[K][N] -> bf16 Wt[N][K] ----------
template <int NJ>
struct TJobs { const float* s[NJ]; bf16* d[NJ]; };

template <int NJ>
__global__ __launch_bounds__(256)
void transpose_multi(TJobs<NJ> jobs, int K, int N) {
    __shared__ float tile[32][33];
    const float* W = jobs.s[blockIdx.z];
    bf16* Wt = jobs.d[blockIdx.z];
    int n0 = blockIdx.x * 32, k0 = blockIdx.y * 32;
    int tx = threadIdx.x, ty = threadIdx.y;  // (32,8)
#pragma unroll
    for (int i = 0; i < 4; ++i)
        tile[ty + i * 8][tx] = W[(size_t)(k0 + ty + i * 8) * N + n0 + tx];
    __syncthreads();
#pragma unroll
    for (int i = 0; i < 4; ++i)
        Wt[(size_t)(n0 + ty + i * 8) * K + k0 + tx] = (bf16)tile[tx][ty + i * 8];
}

// ---------------- fp32 -> bf16 elementwise ----------------
__global__ void f32_to_bf16(const float* __restrict__ X, bf16* __restrict__ Y, int n) {
    int i = blockIdx.x * 256 + threadIdx.x;
    if (i < n) Y[i] = (bf16)X[i];
}

// ---------------- LayerNorm: fp32 in -> bf16 out, N=320 ----------------
__global__ __launch_bounds__(256)
void layernorm_kernel(const float* __restrict__ X, const float* __restrict__ g,
                      const float* __restrict__ b, bf16* __restrict__ Y) {
    int w = threadIdx.x >> 6, lane = threadIdx.x & 63;
    int row = blockIdx.x * 4 + w;
    const float* xr = X + (size_t)row * DIM;
    float v[5];
    float sum = 0.f;
#pragma unroll
    for (int c = 0; c < 5; ++c) { v[c] = xr[c * 64 + lane]; sum += v[c]; }
#pragma unroll
    for (int off = 1; off < 64; off <<= 1) sum += __shfl_xor(sum, off);
    float mu = sum * (1.f / 320.f);
    float vs = 0.f;
#pragma unroll
    for (int c = 0; c < 5; ++c) { float d = v[c] - mu; vs += d * d; }
#pragma unroll
    for (int off = 1; off < 64; off <<= 1) vs += __shfl_xor(vs, off);
    float rs = rsqrtf(vs * (1.f / 320.f) + 1e-5f);
    bf16* yr = Y + (size_t)row * DIM;
#pragma unroll
    for (int c = 0; c < 5; ++c)
        yr[c * 64 + lane] = (bf16)((v[c] - mu) * rs * g[c * 64 + lane] + b[c * 64 + lane]);
}

// ---------------- generic bf16 MFMA GEMM ----------------
// C[M][N] = A[M][K] @ B  with Bt = B^T row-major [N][K].
// EPI 0: Y0=bf16(acc)  1: Y0=bf16(acc+bias)  2: Yf=acc+bias+res (fp32)
// EPI 4: Y0=bf16(acc*QSCALE)
// EPI 5 (fused qkv, N=960): col<320 -> Y0(q)*QSCALE; col<640 -> Y1(k); else transposed -> Y2
// EPI 6 (fused cross kv, N=640): col<320 -> Y0 (row guard); else transposed -> Y2
// MALIGNED=1: M%128==0, N%64==0 -> global_load_lds staging (pre-swizzled source).
// BM=128 BN=64 BK=64, 256 threads (4 waves, 2x2), XOR-swizzled LDS.
template <int EPI, int MALIGNED>
__global__ __launch_bounds__(256)
void gemm_bf16(const bf16* __restrict__ A, const bf16* __restrict__ Bt,
               int M, int N, int K,
               bf16* __restrict__ Y0, bf16* __restrict__ Y1, bf16* __restrict__ Y2,
               float* Yf, const float* __restrict__ bias, const float* res, int trs) {
    __shared__ char smem[24 * 1024];  // A:16KB  B:8KB
    const int t = threadIdx.x;
    const int lane = t & 63;
    const int w = t >> 6;
    const int wr = w >> 1, wc = w & 1;
    const int m0 = blockIdx.x * 128;
    const int n0 = blockIdx.y * 64;

    f32x4 acc[4][2];
#pragma unroll
    for (int mi = 0; mi < 4; ++mi)
#pragma unroll
        for (int ni = 0; ni < 2; ++ni)
#pragma unroll
            for (int r = 0; r < 4; ++r) acc[mi][ni][r] = 0.f;

    for (int k0 = 0; k0 < K; k0 += 64) {
        if (MALIGNED) {
            // A tile via global_load_lds, source pre-swizzled so LDS content matches XOR layout
#pragma unroll
            for (int i = 0; i < 4; ++i) {
                int ch = i * 256 + w * 64 + lane;
                int row = ch >> 3, cpos = ch & 7;
                int seg = cpos ^ (row & 7);
                gld_lds16(A + (size_t)(m0 + row) * K + k0 + seg * 8,
                          smem + (size_t)(i * 256 + w * 64) * 16);
            }
#pragma unroll
            for (int i = 0; i < 2; ++i) {
                int ch = i * 256 + w * 64 + lane;
                int row = ch >> 3, cpos = ch & 7;
                int seg = cpos ^ (row & 7);
                gld_lds16(Bt + (size_t)(n0 + row) * K + k0 + seg * 8,
                          smem + 16 * 1024 + (size_t)(i * 256 + w * 64) * 16);
            }
        } else {
#pragma unroll
            for (int i = 0; i < 4; ++i) {
                int c = t + i * 256;
                int row = c >> 3, seg = c & 7;
                int gr = m0 + row;
                bf16x8 v = bzero8();
                if (gr < M) v = *(const bf16x8*)(A + (size_t)gr * K + k0 + seg * 8);
                *(bf16x8*)(smem + row * 128 + ((seg * 16) ^ ((row & 7) << 4))) = v;
            }
#pragma unroll
            for (int i = 0; i < 2; ++i) {
                int c = t + i * 256;
                int row = c >> 3, seg = c & 7;
                bf16x8 v = *(const bf16x8*)(Bt + (size_t)(n0 + row) * K + k0 + seg * 8);
                *(bf16x8*)(smem + 16 * 1024 + row * 128 + ((seg * 16) ^ ((row & 7) << 4))) = v;
            }
        }
        __syncthreads();

        bf16x8 a[4][2], bfr[2][2];
#pragma unroll
        for (int mi = 0; mi < 4; ++mi)
#pragma unroll
            for (int kh = 0; kh < 2; ++kh) {
                int row = wr * 64 + mi * 16 + (lane & 15);
                a[mi][kh] = *(const bf16x8*)(smem + row * 128 +
                             ((kh * 64 + (lane >> 4) * 16) ^ ((row & 7) << 4)));
            }
#pragma unroll
        for (int ni = 0; ni < 2; ++ni)
#pragma unroll
            for (int kh = 0; kh < 2; ++kh) {
                int row = wc * 32 + ni * 16 + (lane & 15);
                bfr[ni][kh] = *(const bf16x8*)(smem + 16 * 1024 + row * 128 +
                               ((kh * 64 + (lane >> 4) * 16) ^ ((row & 7) << 4)));
            }
#pragma unroll
        for (int mi = 0; mi < 4; ++mi)
#pragma unroll
            for (int ni = 0; ni < 2; ++ni) {
                acc[mi][ni] = __builtin_amdgcn_mfma_f32_16x16x32_bf16(a[mi][0], bfr[ni][0], acc[mi][ni], 0, 0, 0);
                acc[mi][ni] = __builtin_amdgcn_mfma_f32_16x16x32_bf16(a[mi][1], bfr[ni][1], acc[mi][ni], 0, 0, 0);
            }
        __syncthreads();
    }

#pragma unroll
    for (int mi = 0; mi < 4; ++mi)
#pragma unroll
        for (int ni = 0; ni < 2; ++ni) {
            const int col = n0 + wc * 32 + ni * 16 + (lane & 15);
            const int rowb = m0 + wr * 64 + mi * 16 + (lane >> 4) * 4;
            if (EPI == 5) {
                if (col < 320) {
#pragma unroll
                    for (int r = 0; r < 4; ++r)
                        Y0[(size_t)(rowb + r) * 320 + col] = (bf16)(acc[mi][ni][r] * QSCALE);
                } else if (col < 640) {
#pragma unroll
                    for (int r = 0; r < 4; ++r)
                        Y1[(size_t)(rowb + r) * 320 + (col - 320)] = (bf16)acc[mi][ni][r];
                } else {
                    bf16x4 tv;
#pragma unroll
                    for (int r = 0; r < 4; ++r) tv[r] = (bf16)acc[mi][ni][r];
                    *(bf16x4*)(Y2 + (size_t)(col - 640) * trs + rowb) = tv;
                }
            } else if (EPI == 6) {
                if (col < 320) {
#pragma unroll
                    for (int r = 0; r < 4; ++r)
                        if (rowb + r < M) Y0[(size_t)(rowb + r) * 320 + col] = (bf16)acc[mi][ni][r];
                } else {
                    bf16x4 tv;
#pragma unroll
                    for (int r = 0; r < 4; ++r) tv[r] = (bf16)acc[mi][ni][r];
                    *(bf16x4*)(Y2 + (size_t)(col - 320) * trs + rowb) = tv;
                }
            } else {
#pragma unroll
                for (int r = 0; r < 4; ++r) {
                    int row = rowb + r;
                    if (row < M) {
                        float v = acc[mi][ni][r];
                        if (EPI == 0) Y0[(size_t)row * N + col] = (bf16)v;
                        else if (EPI == 1) Y0[(size_t)row * N + col] = (bf16)(v + bias[col]);
                        else if (EPI == 4) Y0[(size_t)row * N + col] = (bf16)(v * QSCALE);
                        else Yf[(size_t)row * N + col] = v + bias[col] + res[(size_t)row * N + col];
                    }
                }
            }
        }
}

// ---------------- flash attention v3 ----------------
// Swapped QK^T + in-register softmax + register-prefetch staging (T14).
// Q read direct from global (pre-scaled). K staged unpadded [128][80B] (stride-80
// rows are bank-conflict-free for the b128 frag reads). VT staged [48][256B] swizzled.
// grid (64, 8, nsplit). 4 waves x 16 q-rows. KV tiles of 128.
template <int DIRECT>
__global__ __launch_bounds__(256, 4)
void flash_attn3(const bf16* __restrict__ Qg, const bf16* __restrict__ Kg,
                 const bf16* __restrict__ VTg, bf16* __restrict__ O,
                 float* __restrict__ Opart, float* __restrict__ MLpart,
                 int nkv, int vstride, int tiles_per_split) {
    __shared__ char smem[22528];
    char* Ks = smem;            // [128][80] linear
    char* Vs = smem + 10240;    // [48][256] XOR-swizzled
    const int t = threadIdx.x, lane = t & 63, w = t >> 6;
    const int g = lane >> 4, q = lane & 15;
    const int h = blockIdx.y, split = blockIdx.z;
    const int qb = blockIdx.x * 64 + w * 16;

    // Q fragments direct from global (d 40..63 pad = zero regs)
    bf16x8 qf[2];
    qf[0] = *(const bf16x8*)(Qg + (size_t)(qb + q) * DIM + h * DHEAD + g * 8);
    qf[1] = bzero8();
    if (g == 0) qf[1] = *(const bf16x8*)(Qg + (size_t)(qb + q) * DIM + h * DHEAD + 32);

    f32x4 accO[3];
#pragma unroll
    for (int dt = 0; dt < 3; ++dt)
#pragma unroll
        for (int r = 0; r < 4; ++r) accO[dt][r] = 0.f;
    float m_run = -1e30f, l_run = 0.f;

    const int ntiles = (nkv + 127) >> 7;
    const int tt0 = split * tiles_per_split;
    int tt1 = tt0 + tiles_per_split;
    if (tt1 > ntiles) tt1 = ntiles;

    bf16x8 kpre[3], vpre[3];
    auto LOADTILE = [&](int tt) {
        const int j0 = tt << 7;
#pragma unroll
        for (int i = 0; i < 3; ++i) {
            int c = t + i * 256;
            kpre[i] = bzero8();
            if (c < 640) {
                int row = c / 5, seg = c % 5;
                if (j0 + row < nkv)
                    kpre[i] = *(const bf16x8*)(Kg + (size_t)(j0 + row) * DIM + h * DHEAD + seg * 8);
            }
        }
#pragma unroll
        for (int i = 0; i < 3; ++i) {
            int c = t + i * 256;
            int row = c >> 4, seg = c & 15;
            vpre[i] = bzero8();
            if (row < DHEAD)
                vpre[i] = *(const bf16x8*)(VTg + (size_t)(h * DHEAD + row) * vstride + j0 + seg * 8);
        }
    };
    auto WRITETILE = [&]() {
#pragma unroll
        for (int i = 0; i < 3; ++i) {
            int c = t + i * 256;
            if (c < 640) {
                int row = c / 5, seg = c % 5;
                *(bf16x8*)(Ks + row * 80 + seg * 16) = kpre[i];
            }
        }
#pragma unroll
        for (int i = 0; i < 3; ++i) {
            int c = t + i * 256;
            int row = c >> 4, seg = c & 15;
            *(bf16x8*)(Vs + row * 256 + ((seg * 16) ^ ((row & 7) << 4))) = vpre[i];
        }
    };

    LOADTILE(tt0);
    for (int tt = tt0; tt < tt1; ++tt) {
        WRITETILE();
        __syncthreads();
        if (tt + 1 < tt1) LOADTILE(tt + 1);  // in flight during compute (T14)
        const int j0 = tt << 7;

        // swapped QK^T: lane owns S^T[k=jt*16+g*4+r][q]
        f32x4 s[8];
        __builtin_amdgcn_s_setprio(1);
#pragma unroll
        for (int jt = 0; jt < 8; ++jt) {
            const char* krow = Ks + (jt * 16 + q) * 80;
            bf16x8 kb0 = *(const bf16x8*)(krow + g * 16);
            bf16x8 kb1 = bzero8();
            if (g == 0) kb1 = *(const bf16x8*)(krow + 64);
            f32x4 z;
#pragma unroll
            for (int r = 0; r < 4; ++r) z[r] = 0.f;
            z = __builtin_amdgcn_mfma_f32_16x16x32_bf16(kb0, qf[0], z, 0, 0, 0);
            z = __builtin_amdgcn_mfma_f32_16x16x32_bf16(kb1, qf[1], z, 0, 0, 0);
            s[jt] = z;
        }
        __builtin_amdgcn_s_setprio(0);
        if (j0 + 128 > nkv) {
#pragma unroll
            for (int jt = 0; jt < 8; ++jt)
#pragma unroll
                for (int r = 0; r < 4; ++r)
                    if (j0 + jt * 16 + g * 4 + r >= nkv) s[jt][r] = -1e30f;
        }

        // in-register online softmax
        f32x4 mv = s[0];
#pragma unroll
        for (int jt = 1; jt < 8; ++jt)
#pragma unroll
            for (int r = 0; r < 4; ++r) mv[r] = fmaxf(mv[r], s[jt][r]);
        float mt = fmaxf(fmaxf(mv[0], mv[1]), fmaxf(mv[2], mv[3]));
        mt = fmaxf(mt, __shfl_xor(mt, 16));
        mt = fmaxf(mt, __shfl_xor(mt, 32));
        float mnew = fmaxf(m_run, mt);
        float f = exp2f(m_run - mnew);
        m_run = mnew;
        float ps = 0.f;
#pragma unroll
        for (int jt = 0; jt < 8; ++jt)
#pragma unroll
            for (int r = 0; r < 4; ++r) {
                float pv = exp2f(s[jt][r] - mnew);
                s[jt][r] = pv;
                ps += pv;
            }
        ps += __shfl_xor(ps, 16);
        ps += __shfl_xor(ps, 32);
        l_run = l_run * f + ps;
#pragma unroll
        for (int dt = 0; dt < 3; ++dt)
#pragma unroll
            for (int r = 0; r < 4; ++r) accO[dt][r] *= f;

        // pack P to bf16 (lane-local)
        union PU { bf16x4 h; shortx4 s4; } pk[8];
#pragma unroll
        for (int jt = 0; jt < 8; ++jt) {
            bf16x4 hv;
#pragma unroll
            for (int r = 0; r < 4; ++r) hv[r] = (bf16)s[jt][r];
            pk[jt].h = hv;
        }

        // PV: O^T[d][q] += V^T[d][k] * P^T[k][q] via 16x16x16 per jt
        __builtin_amdgcn_s_setprio(1);
#pragma unroll
        for (int dt = 0; dt < 3; ++dt) {
            const char* vrow = Vs + (dt * 16 + q) * 256;
            int sw = ((dt * 16 + q) & 7) << 4;
#pragma unroll
            for (int jt = 0; jt < 8; ++jt) {
                shortx4 vb = *(const shortx4*)(vrow + ((jt * 32 + g * 8) ^ sw));
                accO[dt] = __builtin_amdgcn_mfma_f32_16x16x16bf16_1k(vb, pk[jt].s4, accO[dt], 0, 0, 0);
            }
        }
        __builtin_amdgcn_s_setprio(0);
        __syncthreads();
    }

    if (DIRECT) {
        float inv = 1.f / l_run;
#pragma unroll
        for (int dt = 0; dt < 3; ++dt) {
            if (dt < 2 || g < 2) {
                bf16x4 o;
#pragma unroll
                for (int r = 0; r < 4; ++r) o[r] = (bf16)(accO[dt][r] * inv);
                *(bf16x4*)(O + (size_t)(qb + q) * DIM + h * DHEAD + dt * 16 + g * 4) = o;
            }
        }
    } else {
        size_t rowi = (size_t)(split * HEADS + h) * NTOK + qb + q;
#pragma unroll
        for (int dt = 0; dt < 3; ++dt) {
            if (dt < 2 || g < 2)
                *(f32x4*)(Opart + rowi * 40 + dt * 16 + g * 4) = accO[dt];
        }
        if (lane < 16) {
            f32x2 ml;
            ml[0] = m_run; ml[1] = l_run;
            *(f32x2*)(MLpart + rowi * 2) = ml;
        }
    }
}

// ---------------- combine 4 KV-splits ----------------
__global__ __launch_bounds__(256)
void flash_combine(const float* __restrict__ Opart, const float* __restrict__ MLpart,
                   bf16* __restrict__ O) {
    int idx = blockIdx.x * 256 + threadIdx.x;  // 4096*40
    int qi = idx / 40, c = idx - qi * 40;
    int h = c / 5, c8 = c - h * 5;
    float mv[4], lv[4];
    float M = -1e30f;
#pragma unroll
    for (int s = 0; s < 4; ++s) {
        f32x2 ml = *(const f32x2*)(MLpart + ((size_t)(s * HEADS + h) * NTOK + qi) * 2);
        mv[s] = ml[0]; lv[s] = ml[1];
        M = fmaxf(M, ml[0]);
    }
    float wgt[4], denom = 0.f;
#pragma unroll
    for (int s = 0; s < 4; ++s) { wgt[s] = exp2f(mv[s] - M); denom += wgt[s] * lv[s]; }
    float inv = 1.f / denom;
    float o[8];
#pragma unroll
    for (int e = 0; e < 8; ++e) o[e] = 0.f;
#pragma unroll
    for (int s = 0; s < 4; ++s) {
        const float* op = Opart + ((size_t)(s * HEADS + h) * NTOK + qi) * 40 + c8 * 8;
#pragma unroll
        for (int e = 0; e < 8; ++e) o[e] += wgt[s] * op[e];
    }
    bf16x8 ov;
#pragma unroll
    for (int e = 0; e < 8; ++e) ov[e] = (bf16)(o[e] * inv);
    *(bf16x8*)(O + (size_t)qi * DIM + h * DHEAD + c8 * 8) = ov;
}

// ---------------- GEGLU: H [4096][2560] -> G [4096][1280] ----------------
__global__ __launch_bounds__(256)
void geglu_kernel(const bf16* __restrict__ H, bf16* __restrict__ G) {
    size_t idx = (size_t)blockIdx.x * 256 + threadIdx.x;
    size_t r = idx / 160;
    size_t c8 = idx % 160;
    bf16x8 val = *(const bf16x8*)(H + r * 2560 + c8 * 8);
    bf16x8 gate = *(const bf16x8*)(H + r * 2560 + 1280 + c8 * 8);
    bf16x8 o;
#pragma unroll
    for (int e = 0; e < 8; ++e) {
        float gg = (float)gate[e];
        float gl = 0.5f * gg * (1.f + erff(gg * 0.70710678118654752f));
        o[e] = (bf16)((float)val[e] * gl);
    }
    *(bf16x8*)(G + r * 1280 + c8 * 8) = o;
}

// ---------------- launch ----------------
extern "C" void kernel_launch(void* const* d_in, const int* in_sizes, int n_in,
                              void* d_out, int out_size, void* d_ws, size_t ws_size,
                              hipStream_t stream) {
    const float* x     = (const float*)d_in[0];
    const float* ctx   = (const float*)d_in[1];
    const float* n1_g  = (const float*)d_in[2];
    const float* n1_b  = (const float*)d_in[3];
    const float* a1_wq = (const float*)d_in[4];
    const float* a1_wk = (const float*)d_in[5];
    const float* a1_wv = (const float*)d_in[6];
    const float* a1_wo = (const float*)d_in[7];
    const float* a1_bo = (const float*)d_in[8];
    const float* n2_g  = (const float*)d_in[9];
    const float* n2_b  = (const float*)d_in[10];
    const float* a2_wq = (const float*)d_in[11];
    const float* a2_wk = (const float*)d_in[12];
    const float* a2_wv = (const float*)d_in[13];
    const float* a2_wo = (const float*)d_in[14];
    const float* a2_bo = (const float*)d_in[15];
    const float* n3_g  = (const float*)d_in[16];
    const float* n3_b  = (const float*)d_in[17];
    const float* ff_w1 = (const float*)d_in[18];
    const float* ff_b1 = (const float*)d_in[19];
    const float* ff_w2 = (const float*)d_in[20];
    const float* ff_b2 = (const float*)d_in[21];

    char* ws = (char*)d_ws;
    size_t off = 0;
    auto alloc = [&](size_t bytes) -> char* {
        char* p = ws + off;
        off += (bytes + 255) & ~(size_t)255;
        return p;
    };
    bf16* lnbuf  = (bf16*)alloc((size_t)NTOK * DIM * 2);
    bf16* qbuf   = (bf16*)alloc((size_t)NTOK * DIM * 2);
    bf16* kbuf   = (bf16*)alloc((size_t)NTOK * DIM * 2);
    bf16* vtbuf  = (bf16*)alloc((size_t)DIM * NTOK * 2);   // [320 d][4096 tok]
    bf16* abuf   = (bf16*)alloc((size_t)NTOK * DIM * 2);
    bf16* hbuf   = (bf16*)alloc((size_t)NTOK * 2 * IFF * 2);
    bf16* gbuf   = (bf16*)alloc((size_t)NTOK * IFF * 2);
    bf16* ctxb   = (bf16*)alloc((size_t)NCTX * CTXD * 2);
    bf16* k2buf  = (bf16*)alloc((size_t)128 * DIM * 2);
    bf16* vt2buf = (bf16*)alloc((size_t)DIM * 128 * 2);
    bf16* wqkvT  = (bf16*)alloc((size_t)960 * DIM * 2);
    bf16* woT    = (bf16*)alloc((size_t)DIM * DIM * 2);
    bf16* q2T    = (bf16*)alloc((size_t)DIM * DIM * 2);
    bf16* wkv2T  = (bf16*)alloc((size_t)640 * CTXD * 2);
    bf16* o2T    = (bf16*)alloc((size_t)DIM * DIM * 2);
    bf16* w1T    = (bf16*)alloc((size_t)2 * IFF * DIM * 2);
    bf16* w2T    = (bf16*)alloc((size_t)IFF * DIM * 2);
    float* out   = (float*)d_out;

    // flash partials alias FF buffers (unused until FF phase)
    float* Opart  = (float*)hbuf;   // 4*8*4096*40 f32 = 20.97 MB == hbuf size
    float* MLpart = (float*)gbuf;   // 4*8*4096*2 f32 = 1.05 MB <= gbuf size

    dim3 tb(32, 8);
    {
        TJobs<6> j6;
        j6.s[0] = a1_wq; j6.d[0] = wqkvT;
        j6.s[1] = a1_wk; j6.d[1] = wqkvT + (size_t)320 * 320;
        j6.s[2] = a1_wv; j6.d[2] = wqkvT + (size_t)640 * 320;
        j6.s[3] = a1_wo; j6.d[3] = woT;
        j6.s[4] = a2_wq; j6.d[4] = q2T;
        j6.s[5] = a2_wo; j6.d[5] = o2T;
        transpose_multi<6><<<dim3(10, 10, 6), tb, 0, stream>>>(j6, 320, 320);
        TJobs<2> j2;
        j2.s[0] = a2_wk; j2.d[0] = wkv2T;
        j2.s[1] = a2_wv; j2.d[1] = wkv2T + (size_t)320 * 768;
        transpose_multi<2><<<dim3(10, 24, 2), tb, 0, stream>>>(j2, 768, 320);
        TJobs<1> jw1; jw1.s[0] = ff_w1; jw1.d[0] = w1T;
        transpose_multi<1><<<dim3(80, 10, 1), tb, 0, stream>>>(jw1, 320, 2560);
        TJobs<1> jw2; jw2.s[0] = ff_w2; jw2.d[0] = w2T;
        transpose_multi<1><<<dim3(10, 40, 1), tb, 0, stream>>>(jw2, 1280, 320);
    }
    f32_to_bf16<<<231, 256, 0, stream>>>(ctx, ctxb, NCTX * CTXD);

    // ---- self-attention ----
    layernorm_kernel<<<1024, 256, 0, stream>>>(x, n1_g, n1_b, lnbuf);
    gemm_bf16<5, 1><<<dim3(32, 15), 256, 0, stream>>>(lnbuf, wqkvT, NTOK, 960, DIM,
                                                      qbuf, kbuf, vtbuf, nullptr, nullptr, nullptr, NTOK);
    flash_attn3<0><<<dim3(64, 8, 4), 256, 0, stream>>>(qbuf, kbuf, vtbuf, nullptr,
                                                       Opart, MLpart, NTOK, NTOK, 8);
    flash_combine<<<640, 256, 0, stream>>>(Opart, MLpart, abuf);
    gemm_bf16<2, 1><<<dim3(32, 5), 256, 0, stream>>>(abuf, woT, NTOK, DIM, DIM,
                                                     nullptr, nullptr, nullptr, out, a1_bo, x, 0);

    // ---- cross-attention ----
    layernorm_kernel<<<1024, 256, 0, stream>>>(out, n2_g, n2_b, lnbuf);
    gemm_bf16<4, 1><<<dim3(32, 5), 256, 0, stream>>>(lnbuf, q2T, NTOK, DIM, DIM,
                                                     qbuf, nullptr, nullptr, nullptr, nullptr, nullptr, 0);
    gemm_bf16<6, 0><<<dim3(1, 10), 256, 0, stream>>>(ctxb, wkv2T, NCTX, 640, CTXD,
                                                     k2buf, nullptr, vt2buf, nullptr, nullptr, nullptr, 128);
    flash_attn3<1><<<dim3(64, 8, 1), 256, 0, stream>>>(qbuf, k2buf, vt2buf, abuf,
                                                       nullptr, nullptr, NCTX, 128, 1);
    gemm_bf16<2, 1><<<dim3(32, 5), 256, 0, stream>>>(abuf, o2T, NTOK, DIM, DIM,
                                                     nullptr, nullptr, nullptr, out, a2_bo, out, 0);

    // ---- GEGLU FF ----
    layernorm_kernel<<<1024, 256, 0, stream>>>(out, n3_g, n3_b, lnbuf);
    gemm_bf16<1, 1><<<dim3(32, 40), 256, 0, stream>>>(lnbuf, w1T, NTOK, 2 * IFF, DIM,
                                                      hbuf, nullptr, nullptr, nullptr, ff_b1, nullptr, 0);
    geglu_kernel<<<2560, 256, 0, stream>>>(hbuf, gbuf);
    gemm_bf16<2, 1><<<dim3(32, 5), 256, 0, stream>>>(gbuf, w2T, NTOK, DIM, IFF,
                                                     nullptr, nullptr, nullptr, out, ff_b2, out, 0);
}

// Round 5
// 227.444 us; speedup vs baseline: 3.3437x; 1.0374x over previous
//
#include <hip/hip_runtime.h>
#include <hip/hip_bf16.h>
#include <math.h>

typedef __bf16 bf16;
typedef __attribute__((ext_vector_type(8))) __bf16 bf16x8;
typedef __attribute__((ext_vector_type(4))) __bf16 bf16x4;
typedef __attribute__((ext_vector_type(4))) float f32x4;
typedef __attribute__((ext_vector_type(2))) float f32x2;
typedef __attribute__((ext_vector_type(4))) short shortx4;

#define NTOK 4096
#define DIM  320
#define HEADS 8
#define DHEAD 40
#define NCTX 77
#define CTXD 768
#define IFF  1280

#define QSCALE (0.15811388300841897f * 1.4426950408889634f)  // 40^-0.5 * log2(e)

__device__ __forceinline__ bf16x8 bzero8() {
    bf16x8 v;
#pragma unroll
    for (int e = 0; e < 8; ++e) v[e] = (bf16)0.0f;
    return v;
}

__device__ __forceinline__ void gld_lds16(const void* g, void* l) {
    __builtin_amdgcn_global_load_lds(
        (const __attribute__((address_space(1))) void*)g,
        (__attribute__((address_space(3))) void*)l, 16, 0, 0);
}

// ---------------- transpose + convert fp32 W[K][N] -> bf16 Wt[N][K] ----------
template <int NJ>
struct TJobs { const float* s[NJ]; bf16* d[NJ]; };

template <int NJ>
__global__ __launch_bounds__(256)
void transpose_multi(TJobs<NJ> jobs, int K, int N) {
    __shared__ float tile[32][33];
    const float* W = jobs.s[blockIdx.z];
    bf16* Wt = jobs.d[blockIdx.z];
    int n0 = blockIdx.x * 32, k0 = blockIdx.y * 32;
    int tx = threadIdx.x, ty = threadIdx.y;  // (32,8)
#pragma unroll
    for (int i = 0; i < 4; ++i)
        tile[ty + i * 8][tx] = W[(size_t)(k0 + ty + i * 8) * N + n0 + tx];
    __syncthreads();
#pragma unroll
    for (int i = 0; i < 4; ++i)
        Wt[(size_t)(n0 + ty + i * 8) * K + k0 + tx] = (bf16)tile[tx][ty + i * 8];
}

// ---------------- fp32 -> bf16 elementwise ----------------
__global__ void f32_to_bf16(const float* __restrict__ X, bf16* __restrict__ Y, int n) {
    int i = blockIdx.x * 256 + threadIdx.x;
    if (i < n) Y[i] = (bf16)X[i];
}

// ---------------- LayerNorm: fp32 in -> bf16 out, N=320 ----------------
__global__ __launch_bounds__(256)
void layernorm_kernel(const float* __restrict__ X, const float* __restrict__ g,
                      const float* __restrict__ b, bf16* __restrict__ Y) {
    int w = threadIdx.x >> 6, lane = threadIdx.x & 63;
    int row = blockIdx.x * 4 + w;
    const float* xr = X + (size_t)row * DIM;
    float v[5];
    float sum = 0.f;
#pragma unroll
    for (int c = 0; c < 5; ++c) { v[c] = xr[c * 64 + lane]; sum += v[c]; }
#pragma unroll
    for (int off = 1; off < 64; off <<= 1) sum += __shfl_xor(sum, off);
    float mu = sum * (1.f / 320.f);
    float vs = 0.f;
#pragma unroll
    for (int c = 0; c < 5; ++c) { float d = v[c] - mu; vs += d * d; }
#pragma unroll
    for (int off = 1; off < 64; off <<= 1) vs += __shfl_xor(vs, off);
    float rs = rsqrtf(vs * (1.f / 320.f) + 1e-5f);
    bf16* yr = Y + (size_t)row * DIM;
#pragma unroll
    for (int c = 0; c < 5; ++c)
        yr[c * 64 + lane] = (bf16)((v[c] - mu) * rs * g[c * 64 + lane] + b[c * 64 + lane]);
}

// ---------------- generic bf16 MFMA GEMM ----------------
// (unchanged from round 4 — passed, not in top-5)
template <int EPI, int MALIGNED>
__global__ __launch_bounds__(256)
void gemm_bf16(const bf16* __restrict__ A, const bf16* __restrict__ Bt,
               int M, int N, int K,
               bf16* __restrict__ Y0, bf16* __restrict__ Y1, bf16* __restrict__ Y2,
               float* Yf, const float* __restrict__ bias, const float* res, int trs) {
    __shared__ char smem[24 * 1024];  // A:16KB  B:8KB
    const int t = threadIdx.x;
    const int lane = t & 63;
    const int w = t >> 6;
    const int wr = w >> 1, wc = w & 1;
    const int m0 = blockIdx.x * 128;
    const int n0 = blockIdx.y * 64;

    f32x4 acc[4][2];
#pragma unroll
    for (int mi = 0; mi < 4; ++mi)
#pragma unroll
        for (int ni = 0; ni < 2; ++ni)
#pragma unroll
            for (int r = 0; r < 4; ++r) acc[mi][ni][r] = 0.f;

    for (int k0 = 0; k0 < K; k0 += 64) {
        if (MALIGNED) {
#pragma unroll
            for (int i = 0; i < 4; ++i) {
                int ch = i * 256 + w * 64 + lane;
                int row = ch >> 3, cpos = ch & 7;
                int seg = cpos ^ (row & 7);
                gld_lds16(A + (size_t)(m0 + row) * K + k0 + seg * 8,
                          smem + (size_t)(i * 256 + w * 64) * 16);
            }
#pragma unroll
            for (int i = 0; i < 2; ++i) {
                int ch = i * 256 + w * 64 + lane;
                int row = ch >> 3, cpos = ch & 7;
                int seg = cpos ^ (row & 7);
                gld_lds16(Bt + (size_t)(n0 + row) * K + k0 + seg * 8,
                          smem + 16 * 1024 + (size_t)(i * 256 + w * 64) * 16);
            }
        } else {
#pragma unroll
            for (int i = 0; i < 4; ++i) {
                int c = t + i * 256;
                int row = c >> 3, seg = c & 7;
                int gr = m0 + row;
                bf16x8 v = bzero8();
                if (gr < M) v = *(const bf16x8*)(A + (size_t)gr * K + k0 + seg * 8);
                *(bf16x8*)(smem + row * 128 + ((seg * 16) ^ ((row & 7) << 4))) = v;
            }
#pragma unroll
            for (int i = 0; i < 2; ++i) {
                int c = t + i * 256;
                int row = c >> 3, seg = c & 7;
                bf16x8 v = *(const bf16x8*)(Bt + (size_t)(n0 + row) * K + k0 + seg * 8);
                *(bf16x8*)(smem + 16 * 1024 + row * 128 + ((seg * 16) ^ ((row & 7) << 4))) = v;
            }
        }
        __syncthreads();

        bf16x8 a[4][2], bfr[2][2];
#pragma unroll
        for (int mi = 0; mi < 4; ++mi)
#pragma unroll
            for (int kh = 0; kh < 2; ++kh) {
                int row = wr * 64 + mi * 16 + (lane & 15);
                a[mi][kh] = *(const bf16x8*)(smem + row * 128 +
                             ((kh * 64 + (lane >> 4) * 16) ^ ((row & 7) << 4)));
            }
#pragma unroll
        for (int ni = 0; ni < 2; ++ni)
#pragma unroll
            for (int kh = 0; kh < 2; ++kh) {
                int row = wc * 32 + ni * 16 + (lane & 15);
                bfr[ni][kh] = *(const bf16x8*)(smem + 16 * 1024 + row * 128 +
                               ((kh * 64 + (lane >> 4) * 16) ^ ((row & 7) << 4)));
            }
#pragma unroll
        for (int mi = 0; mi < 4; ++mi)
#pragma unroll
            for (int ni = 0; ni < 2; ++ni) {
                acc[mi][ni] = __builtin_amdgcn_mfma_f32_16x16x32_bf16(a[mi][0], bfr[ni][0], acc[mi][ni], 0, 0, 0);
                acc[mi][ni] = __builtin_amdgcn_mfma_f32_16x16x32_bf16(a[mi][1], bfr[ni][1], acc[mi][ni], 0, 0, 0);
            }
        __syncthreads();
    }

#pragma unroll
    for (int mi = 0; mi < 4; ++mi)
#pragma unroll
        for (int ni = 0; ni < 2; ++ni) {
            const int col = n0 + wc * 32 + ni * 16 + (lane & 15);
            const int rowb = m0 + wr * 64 + mi * 16 + (lane >> 4) * 4;
            if (EPI == 5) {
                if (col < 320) {
#pragma unroll
                    for (int r = 0; r < 4; ++r)
                        Y0[(size_t)(rowb + r) * 320 + col] = (bf16)(acc[mi][ni][r] * QSCALE);
                } else if (col < 640) {
#pragma unroll
                    for (int r = 0; r < 4; ++r)
                        Y1[(size_t)(rowb + r) * 320 + (col - 320)] = (bf16)acc[mi][ni][r];
                } else {
                    bf16x4 tv;
#pragma unroll
                    for (int r = 0; r < 4; ++r) tv[r] = (bf16)acc[mi][ni][r];
                    *(bf16x4*)(Y2 + (size_t)(col - 640) * trs + rowb) = tv;
                }
            } else if (EPI == 6) {
                if (col < 320) {
#pragma unroll
                    for (int r = 0; r < 4; ++r)
                        if (rowb + r < M) Y0[(size_t)(rowb + r) * 320 + col] = (bf16)acc[mi][ni][r];
                } else {
                    bf16x4 tv;
#pragma unroll
                    for (int r = 0; r < 4; ++r) tv[r] = (bf16)acc[mi][ni][r];
                    *(bf16x4*)(Y2 + (size_t)(col - 320) * trs + rowb) = tv;
                }
            } else {
#pragma unroll
                for (int r = 0; r < 4; ++r) {
                    int row = rowb + r;
                    if (row < M) {
                        float v = acc[mi][ni][r];
                        if (EPI == 0) Y0[(size_t)row * N + col] = (bf16)v;
                        else if (EPI == 1) Y0[(size_t)row * N + col] = (bf16)(v + bias[col]);
                        else if (EPI == 4) Y0[(size_t)row * N + col] = (bf16)(v * QSCALE);
                        else Yf[(size_t)row * N + col] = v + bias[col] + res[(size_t)row * N + col];
                    }
                }
            }
        }
}

// ---------------- flash attention v4: gld_lds double-buffered staging --------
// KV tiles of 64. K [64][80B] linear, V [48][128B] read-XOR-swizzled
// (source pre-swizzled). 2-phase async pipeline: STAGE(next) -> compute(cur)
// -> syncthreads. Swapped QK^T + in-register softmax (unchanged math).
#define KVT 64
#define KBYTES 5120    // 64*80
#define VBYTES 6144    // 48*128
#define FBUF (KBYTES + VBYTES)

template <int DIRECT>
__global__ __launch_bounds__(256, 4)
void flash_attn4(const bf16* __restrict__ Qg, const bf16* __restrict__ Kg,
                 const bf16* __restrict__ VTg, bf16* __restrict__ O,
                 float* __restrict__ Opart, float* __restrict__ MLpart,
                 int nkv, int vstride, int tiles_per_split) {
    __shared__ char smem[2 * FBUF];   // 22528 B
    const int t = threadIdx.x, lane = t & 63, w = t >> 6;
    const int g = lane >> 4, q = lane & 15;
    const int h = blockIdx.y, split = blockIdx.z;
    const int qb = blockIdx.x * 64 + w * 16;

    // --- per-thread staging slots: 11 wave-chunks (K:5, V:6) over 4 waves ---
    // w0: K0 K1 K2 | w1: K3 K4 V0 | w2: V1 V2 V3 | w3: V4 V5
    const int nslot = (w == 3) ? 2 : 3;
    size_t srcoff[3];
    int dstoff[3];
    bool sK[3];
#pragma unroll
    for (int s = 0; s < 3; ++s) {
        int id = w * 3 + s;
        if (id < 5) {           // K chunk
            int c16 = id * 64 + lane;
            int row = c16 / 5, seg = c16 - row * 5;
            sK[s] = true;
            srcoff[s] = (size_t)row * DIM + seg * 8;
            dstoff[s] = id * 1024;
        } else {                // V chunk
            int v = id - 5;
            int c16 = v * 64 + lane;
            int row = c16 >> 3, seg = c16 & 7;
            seg ^= (row & 7);   // pre-swizzle source
            sK[s] = false;
            srcoff[s] = (size_t)row * vstride + seg * 8;
            dstoff[s] = KBYTES + v * 1024;
        }
    }

    // Q fragments direct from global (d 40..63 pad = zero regs)
    bf16x8 qf[2];
    qf[0] = *(const bf16x8*)(Qg + (size_t)(qb + q) * DIM + h * DHEAD + g * 8);
    qf[1] = bzero8();
    if (g == 0) qf[1] = *(const bf16x8*)(Qg + (size_t)(qb + q) * DIM + h * DHEAD + 32);

    f32x4 accO[3];
#pragma unroll
    for (int dt = 0; dt < 3; ++dt)
#pragma unroll
        for (int r = 0; r < 4; ++r) accO[dt][r] = 0.f;
    float m_run = -1e30f, l_run = 0.f;

    const int ntiles = (nkv + KVT - 1) / KVT;
    const int tt0 = split * tiles_per_split;
    int tt1 = tt0 + tiles_per_split;
    if (tt1 > ntiles) tt1 = ntiles;

    const bf16* kbase = Kg + (size_t)tt0 * KVT * DIM + h * DHEAD;
    const bf16* vbase = VTg + (size_t)h * DHEAD * vstride + tt0 * KVT;

    auto STAGE = [&](int bufsel, const bf16* kb, const bf16* vb) {
        char* base = smem + bufsel * FBUF;
#pragma unroll
        for (int s = 0; s < 3; ++s) {
            if (s < nslot)
                gld_lds16((sK[s] ? kb : vb) + srcoff[s], base + dstoff[s]);
        }
    };

    int buf = 0;
    STAGE(0, kbase, vbase);
    __syncthreads();

    for (int tt = tt0; tt < tt1; ++tt) {
        if (tt + 1 < tt1) STAGE(buf ^ 1, kbase + KVT * DIM, vbase + KVT);
        kbase += KVT * DIM; vbase += KVT;
        const int j0 = tt * KVT;
        const char* Ks = smem + buf * FBUF;
        const char* Vs = Ks + KBYTES;

        // swapped QK^T: lane owns S^T[k=jt*16+g*4+r][q]
        f32x4 s[4];
        __builtin_amdgcn_s_setprio(1);
#pragma unroll
        for (int jt = 0; jt < 4; ++jt) {
            const char* krow = Ks + (jt * 16 + q) * 80;
            bf16x8 kb0 = *(const bf16x8*)(krow + g * 16);
            bf16x8 kb1 = bzero8();
            if (g == 0) kb1 = *(const bf16x8*)(krow + 64);
            f32x4 z;
#pragma unroll
            for (int r = 0; r < 4; ++r) z[r] = 0.f;
            z = __builtin_amdgcn_mfma_f32_16x16x32_bf16(kb0, qf[0], z, 0, 0, 0);
            z = __builtin_amdgcn_mfma_f32_16x16x32_bf16(kb1, qf[1], z, 0, 0, 0);
            s[jt] = z;
        }
        __builtin_amdgcn_s_setprio(0);
        if (j0 + KVT > nkv) {
#pragma unroll
            for (int jt = 0; jt < 4; ++jt)
#pragma unroll
                for (int r = 0; r < 4; ++r)
                    if (j0 + jt * 16 + g * 4 + r >= nkv) s[jt][r] = -1e30f;
        }

        // in-register online softmax (16 scores/lane)
        f32x4 mv = s[0];
#pragma unroll
        for (int jt = 1; jt < 4; ++jt)
#pragma unroll
            for (int r = 0; r < 4; ++r) mv[r] = fmaxf(mv[r], s[jt][r]);
        float mt = fmaxf(fmaxf(mv[0], mv[1]), fmaxf(mv[2], mv[3]));
        mt = fmaxf(mt, __shfl_xor(mt, 16));
        mt = fmaxf(mt, __shfl_xor(mt, 32));
        float mnew = fmaxf(m_run, mt);
        float f = exp2f(m_run - mnew);
        m_run = mnew;
        float ps = 0.f;
#pragma unroll
        for (int jt = 0; jt < 4; ++jt)
#pragma unroll
            for (int r = 0; r < 4; ++r) {
                float pv = exp2f(s[jt][r] - mnew);
                s[jt][r] = pv;
                ps += pv;
            }
        ps += __shfl_xor(ps, 16);
        ps += __shfl_xor(ps, 32);
        l_run = l_run * f + ps;
#pragma unroll
        for (int dt = 0; dt < 3; ++dt)
#pragma unroll
            for (int r = 0; r < 4; ++r) accO[dt][r] *= f;

        // pack P to bf16 (lane-local)
        union PU { bf16x4 hv; shortx4 s4; } pk[4];
#pragma unroll
        for (int jt = 0; jt < 4; ++jt) {
            bf16x4 hv;
#pragma unroll
            for (int r = 0; r < 4; ++r) hv[r] = (bf16)s[jt][r];
            pk[jt].hv = hv;
        }

        // PV: O^T[d][q] += V^T[d][k] * P^T[k][q] via 16x16x16 per jt
        __builtin_amdgcn_s_setprio(1);
#pragma unroll
        for (int dt = 0; dt < 3; ++dt) {
            const char* vrow = Vs + (dt * 16 + q) * 128;
            int sw = ((dt * 16 + q) & 7) << 4;
#pragma unroll
            for (int jt = 0; jt < 4; ++jt) {
                shortx4 vb = *(const shortx4*)(vrow + ((jt * 32 + g * 8) ^ sw));
                accO[dt] = __builtin_amdgcn_mfma_f32_16x16x16bf16_1k(vb, pk[jt].s4, accO[dt], 0, 0, 0);
            }
        }
        __builtin_amdgcn_s_setprio(0);
        __syncthreads();
        buf ^= 1;
    }

    if (DIRECT) {
        float inv = 1.f / l_run;
#pragma unroll
        for (int dt = 0; dt < 3; ++dt) {
            if (dt < 2 || g < 2) {
                bf16x4 o;
#pragma unroll
                for (int r = 0; r < 4; ++r) o[r] = (bf16)(accO[dt][r] * inv);
                *(bf16x4*)(O + (size_t)(qb + q) * DIM + h * DHEAD + dt * 16 + g * 4) = o;
            }
        }
    } else {
        size_t rowi = (size_t)(split * HEADS + h) * NTOK + qb + q;
#pragma unroll
        for (int dt = 0; dt < 3; ++dt) {
            if (dt < 2 || g < 2)
                *(f32x4*)(Opart + rowi * 40 + dt * 16 + g * 4) = accO[dt];
        }
        if (lane < 16) {
            f32x2 ml;
            ml[0] = m_run; ml[1] = l_run;
            *(f32x2*)(MLpart + rowi * 2) = ml;
        }
    }
}

// ---------------- combine 4 KV-splits ----------------
__global__ __launch_bounds__(256)
void flash_combine(const float* __restrict__ Opart, const float* __restrict__ MLpart,
                   bf16* __restrict__ O) {
    int idx = blockIdx.x * 256 + threadIdx.x;  // 4096*40
    int qi = idx / 40, c = idx - qi * 40;
    int h = c / 5, c8 = c - h * 5;
    float mv[4], lv[4];
    float M = -1e30f;
#pragma unroll
    for (int s = 0; s < 4; ++s) {
        f32x2 ml = *(const f32x2*)(MLpart + ((size_t)(s * HEADS + h) * NTOK + qi) * 2);
        mv[s] = ml[0]; lv[s] = ml[1];
        M = fmaxf(M, ml[0]);
    }
    float wgt[4], denom = 0.f;
#pragma unroll
    for (int s = 0; s < 4; ++s) { wgt[s] = exp2f(mv[s] - M); denom += wgt[s] * lv[s]; }
    float inv = 1.f / denom;
    float o[8];
#pragma unroll
    for (int e = 0; e < 8; ++e) o[e] = 0.f;
#pragma unroll
    for (int s = 0; s < 4; ++s) {
        const float* op = Opart + ((size_t)(s * HEADS + h) * NTOK + qi) * 40 + c8 * 8;
#pragma unroll
        for (int e = 0; e < 8; ++e) o[e] += wgt[s] * op[e];
    }
    bf16x8 ov;
#pragma unroll
    for (int e = 0; e < 8; ++e) ov[e] = (bf16)(o[e] * inv);
    *(bf16x8*)(O + (size_t)qi * DIM + h * DHEAD + c8 * 8) = ov;
}

// ---------------- GEGLU: H [4096][2560] -> G [4096][1280] ----------------
__global__ __launch_bounds__(256)
void geglu_kernel(const bf16* __restrict__ H, bf16* __restrict__ G) {
    size_t idx = (size_t)blockIdx.x * 256 + threadIdx.x;
    size_t r = idx / 160;
    size_t c8 = idx % 160;
    bf16x8 val = *(const bf16x8*)(H + r * 2560 + c8 * 8);
    bf16x8 gate = *(const bf16x8*)(H + r * 2560 + 1280 + c8 * 8);
    bf16x8 o;
#pragma unroll
    for (int e = 0; e < 8; ++e) {
        float gg = (float)gate[e];
        float gl = 0.5f * gg * (1.f + erff(gg * 0.70710678118654752f));
        o[e] = (bf16)((float)val[e] * gl);
    }
    *(bf16x8*)(G + r * 1280 + c8 * 8) = o;
}

// ---------------- launch ----------------
extern "C" void kernel_launch(void* const* d_in, const int* in_sizes, int n_in,
                              void* d_out, int out_size, void* d_ws, size_t ws_size,
                              hipStream_t stream) {
    const float* x     = (const float*)d_in[0];
    const float* ctx   = (const float*)d_in[1];
    const float* n1_g  = (const float*)d_in[2];
    const float* n1_b  = (const float*)d_in[3];
    const float* a1_wq = (const float*)d_in[4];
    const float* a1_wk = (const float*)d_in[5];
    const float* a1_wv = (const float*)d_in[6];
    const float* a1_wo = (const float*)d_in[7];
    const float* a1_bo = (const float*)d_in[8];
    const float* n2_g  = (const float*)d_in[9];
    const float* n2_b  = (const float*)d_in[10];
    const float* a2_wq = (const float*)d_in[11];
    const float* a2_wk = (const float*)d_in[12];
    const float* a2_wv = (const float*)d_in[13];
    const float* a2_wo = (const float*)d_in[14];
    const float* a2_bo = (const float*)d_in[15];
    const float* n3_g  = (const float*)d_in[16];
    const float* n3_b  = (const float*)d_in[17];
    const float* ff_w1 = (const float*)d_in[18];
    const float* ff_b1 = (const float*)d_in[19];
    const float* ff_w2 = (const float*)d_in[20];
    const float* ff_b2 = (const float*)d_in[21];

    char* ws = (char*)d_ws;
    size_t off = 0;
    auto alloc = [&](size_t bytes) -> char* {
        char* p = ws + off;
        off += (bytes + 255) & ~(size_t)255;
        return p;
    };
    bf16* lnbuf  = (bf16*)alloc((size_t)NTOK * DIM * 2);
    bf16* qbuf   = (bf16*)alloc((size_t)NTOK * DIM * 2);
    bf16* kbuf   = (bf16*)alloc((size_t)NTOK * DIM * 2);
    bf16* vtbuf  = (bf16*)alloc((size_t)328 * NTOK * 2);   // [320+8 pad d][4096 tok]
    bf16* abuf   = (bf16*)alloc((size_t)NTOK * DIM * 2);
    bf16* hbuf   = (bf16*)alloc((size_t)NTOK * 2 * IFF * 2);
    bf16* gbuf   = (bf16*)alloc((size_t)NTOK * IFF * 2);
    bf16* ctxb   = (bf16*)alloc((size_t)NCTX * CTXD * 2);
    bf16* k2buf  = (bf16*)alloc((size_t)128 * DIM * 2);
    bf16* vt2buf = (bf16*)alloc((size_t)328 * 128 * 2);    // pad rows for d 40..47 reads
    bf16* wqkvT  = (bf16*)alloc((size_t)960 * DIM * 2);
    bf16* woT    = (bf16*)alloc((size_t)DIM * DIM * 2);
    bf16* q2T    = (bf16*)alloc((size_t)DIM * DIM * 2);
    bf16* wkv2T  = (bf16*)alloc((size_t)640 * CTXD * 2);
    bf16* o2T    = (bf16*)alloc((size_t)DIM * DIM * 2);
    bf16* w1T    = (bf16*)alloc((size_t)2 * IFF * DIM * 2);
    bf16* w2T    = (bf16*)alloc((size_t)IFF * DIM * 2);
    float* out   = (float*)d_out;

    // flash partials alias FF buffers (unused until FF phase)
    float* Opart  = (float*)hbuf;   // 4*8*4096*40 f32 = 20.97 MB == hbuf size
    float* MLpart = (float*)gbuf;   // 4*8*4096*2 f32 = 1.05 MB <= gbuf size

    dim3 tb(32, 8);
    {
        TJobs<6> j6;
        j6.s[0] = a1_wq; j6.d[0] = wqkvT;
        j6.s[1] = a1_wk; j6.d[1] = wqkvT + (size_t)320 * 320;
        j6.s[2] = a1_wv; j6.d[2] = wqkvT + (size_t)640 * 320;
        j6.s[3] = a1_wo; j6.d[3] = woT;
        j6.s[4] = a2_wq; j6.d[4] = q2T;
        j6.s[5] = a2_wo; j6.d[5] = o2T;
        transpose_multi<6><<<dim3(10, 10, 6), tb, 0, stream>>>(j6, 320, 320);
        TJobs<2> j2;
        j2.s[0] = a2_wk; j2.d[0] = wkv2T;
        j2.s[1] = a2_wv; j2.d[1] = wkv2T + (size_t)320 * 768;
        transpose_multi<2><<<dim3(10, 24, 2), tb, 0, stream>>>(j2, 768, 320);
        TJobs<1> jw1; jw1.s[0] = ff_w1; jw1.d[0] = w1T;
        transpose_multi<1><<<dim3(80, 10, 1), tb, 0, stream>>>(jw1, 320, 2560);
        TJobs<1> jw2; jw2.s[0] = ff_w2; jw2.d[0] = w2T;
        transpose_multi<1><<<dim3(10, 40, 1), tb, 0, stream>>>(jw2, 1280, 320);
    }
    f32_to_bf16<<<231, 256, 0, stream>>>(ctx, ctxb, NCTX * CTXD);

    // ---- self-attention ----
    layernorm_kernel<<<1024, 256, 0, stream>>>(x, n1_g, n1_b, lnbuf);
    gemm_bf16<5, 1><<<dim3(32, 15), 256, 0, stream>>>(lnbuf, wqkvT, NTOK, 960, DIM,
                                                      qbuf, kbuf, vtbuf, nullptr, nullptr, nullptr, NTOK);
    flash_attn4<0><<<dim3(64, 8, 4), 256, 0, stream>>>(qbuf, kbuf, vtbuf, nullptr,
                                                       Opart, MLpart, NTOK, NTOK, 16);
    flash_combine<<<640, 256, 0, stream>>>(Opart, MLpart, abuf);
    gemm_bf16<2, 1><<<dim3(32, 5), 256, 0, stream>>>(abuf, woT, NTOK, DIM, DIM,
                                                     nullptr, nullptr, nullptr, out, a1_bo, x, 0);

    // ---- cross-attention ----
    layernorm_kernel<<<1024, 256, 0, stream>>>(out, n2_g, n2_b, lnbuf);
    gemm_bf16<4, 1><<<dim3(32, 5), 256, 0, stream>>>(lnbuf, q2T, NTOK, DIM, DIM,
                                                     qbuf, nullptr, nullptr, nullptr, nullptr, nullptr, 0);
    gemm_bf16<6, 0><<<dim3(1, 10), 256, 0, stream>>>(ctxb, wkv2T, NCTX, 640, CTXD,
                                                     k2buf, nullptr, vt2buf, nullptr, nullptr, nullptr, 128);
    flash_attn4<1><<<dim3(64, 8, 1), 256, 0, stream>>>(qbuf, k2buf, vt2buf, abuf,
                                                       nullptr, nullptr, NCTX, 128, 2);
    gemm_bf16<2, 1><<<dim3(32, 5), 256, 0, stream>>>(abuf, o2T, NTOK, DIM, DIM,
                                                     nullptr, nullptr, nullptr, out, a2_bo, out, 0);

    // ---- GEGLU FF ----
    layernorm_kernel<<<1024, 256, 0, stream>>>(out, n3_g, n3_b, lnbuf);
    gemm_bf16<1, 1><<<dim3(32, 40), 256, 0, stream>>>(lnbuf, w1T, NTOK, 2 * IFF, DIM,
                                                      hbuf, nullptr, nullptr, nullptr, ff_b1, nullptr, 0);
    geglu_kernel<<<2560, 256, 0, stream>>>(hbuf, gbuf);
    gemm_bf16<2, 1><<<dim3(32, 5), 256, 0, stream>>>(gbuf, w2T, NTOK, DIM, IFF,
                                                     nullptr, nullptr, nullptr, out, ff_b2, out, 0);
}

// Round 6
// 213.234 us; speedup vs baseline: 3.5665x; 1.0666x over previous
//
#include <hip/hip_runtime.h>
#include <hip/hip_bf16.h>
#include <math.h>

typedef __bf16 bf16;
typedef __attribute__((ext_vector_type(8))) __bf16 bf16x8;
typedef __attribute__((ext_vector_type(4))) __bf16 bf16x4;
typedef __attribute__((ext_vector_type(4))) float f32x4;
typedef __attribute__((ext_vector_type(2))) float f32x2;
typedef __attribute__((ext_vector_type(4))) short shortx4;

#define NTOK 4096
#define DIM  320
#define HEADS 8
#define DHEAD 40
#define NCTX 77
#define CTXD 768
#define IFF  1280

#define QSCALE (0.15811388300841897f * 1.4426950408889634f)  // 40^-0.5 * log2(e)

__device__ __forceinline__ bf16x8 bzero8() {
    bf16x8 v;
#pragma unroll
    for (int e = 0; e < 8; ++e) v[e] = (bf16)0.0f;
    return v;
}

__device__ __forceinline__ void gld_lds16(const void* g, void* l) {
    __builtin_amdgcn_global_load_lds(
        (const __attribute__((address_space(1))) void*)g,
        (__attribute__((address_space(3))) void*)l, 16, 0, 0);
}

// ---------------- transpose + convert fp32 W[K][N] -> bf16 Wt[N][K] ----------
// PERM=1: dest row n' = (n<1280) ? 2n : 2(n-1280)+1  (val/gate interleave for FF1)
template <int NJ>
struct TJobs { const float* s[NJ]; bf16* d[NJ]; };

template <int NJ, int PERM>
__global__ __launch_bounds__(256)
void transpose_multi(TJobs<NJ> jobs, int K, int N) {
    __shared__ float tile[32][33];
    const float* W = jobs.s[blockIdx.z];
    bf16* Wt = jobs.d[blockIdx.z];
    int n0 = blockIdx.x * 32, k0 = blockIdx.y * 32;
    int tx = threadIdx.x, ty = threadIdx.y;  // (32,8)
#pragma unroll
    for (int i = 0; i < 4; ++i)
        tile[ty + i * 8][tx] = W[(size_t)(k0 + ty + i * 8) * N + n0 + tx];
    __syncthreads();
#pragma unroll
    for (int i = 0; i < 4; ++i) {
        int n = n0 + ty + i * 8;
        int nd = PERM ? ((n < 1280) ? 2 * n : 2 * (n - 1280) + 1) : n;
        Wt[(size_t)nd * K + k0 + tx] = (bf16)tile[tx][ty + i * 8];
    }
}

// ---------------- fp32 -> bf16 elementwise ----------------
__global__ void f32_to_bf16(const float* __restrict__ X, bf16* __restrict__ Y, int n) {
    int i = blockIdx.x * 256 + threadIdx.x;
    if (i < n) Y[i] = (bf16)X[i];
}

// ---------------- LayerNorm: fp32 in -> bf16 out, N=320 ----------------
__global__ __launch_bounds__(256)
void layernorm_kernel(const float* __restrict__ X, const float* __restrict__ g,
                      const float* __restrict__ b, bf16* __restrict__ Y) {
    int w = threadIdx.x >> 6, lane = threadIdx.x & 63;
    int row = blockIdx.x * 4 + w;
    const float* xr = X + (size_t)row * DIM;
    float v[5];
    float sum = 0.f;
#pragma unroll
    for (int c = 0; c < 5; ++c) { v[c] = xr[c * 64 + lane]; sum += v[c]; }
#pragma unroll
    for (int off = 1; off < 64; off <<= 1) sum += __shfl_xor(sum, off);
    float mu = sum * (1.f / 320.f);
    float vs = 0.f;
#pragma unroll
    for (int c = 0; c < 5; ++c) { float d = v[c] - mu; vs += d * d; }
#pragma unroll
    for (int off = 1; off < 64; off <<= 1) vs += __shfl_xor(vs, off);
    float rs = rsqrtf(vs * (1.f / 320.f) + 1e-5f);
    bf16* yr = Y + (size_t)row * DIM;
#pragma unroll
    for (int c = 0; c < 5; ++c)
        yr[c * 64 + lane] = (bf16)((v[c] - mu) * rs * g[c * 64 + lane] + b[c * 64 + lane]);
}

// ---------------- generic bf16 MFMA GEMM ----------------
// EPI 2: Yf = acc + bias + res (fp32)
// EPI 4: Y0 = bf16(acc * QSCALE)
// EPI 5 (fused qkv, N=960): col<320 -> Y0(q)*QSCALE; col<640 -> Y1(k); else transposed -> Y2
// EPI 6 (fused cross kv, N=640): col<320 -> Y0 (row guard); else transposed -> Y2
// EPI 7 (FF1+GEGLU, N=2560 permuted): even col=val, odd col=gate; Y0[row][col>>1]=val*gelu(gate)
template <int EPI, int MALIGNED>
__global__ __launch_bounds__(256)
void gemm_bf16(const bf16* __restrict__ A, const bf16* __restrict__ Bt,
               int M, int N, int K,
               bf16* __restrict__ Y0, bf16* __restrict__ Y1, bf16* __restrict__ Y2,
               float* Yf, const float* __restrict__ bias, const float* res, int trs) {
    __shared__ char smem[24 * 1024];  // A:16KB  B:8KB
    const int t = threadIdx.x;
    const int lane = t & 63;
    const int w = t >> 6;
    const int wr = w >> 1, wc = w & 1;
    const int m0 = blockIdx.x * 128;
    const int n0 = blockIdx.y * 64;

    f32x4 acc[4][2];
#pragma unroll
    for (int mi = 0; mi < 4; ++mi)
#pragma unroll
        for (int ni = 0; ni < 2; ++ni)
#pragma unroll
            for (int r = 0; r < 4; ++r) acc[mi][ni][r] = 0.f;

    for (int k0 = 0; k0 < K; k0 += 64) {
        if (MALIGNED) {
#pragma unroll
            for (int i = 0; i < 4; ++i) {
                int ch = i * 256 + w * 64 + lane;
                int row = ch >> 3, cpos = ch & 7;
                int seg = cpos ^ (row & 7);
                gld_lds16(A + (size_t)(m0 + row) * K + k0 + seg * 8,
                          smem + (size_t)(i * 256 + w * 64) * 16);
            }
#pragma unroll
            for (int i = 0; i < 2; ++i) {
                int ch = i * 256 + w * 64 + lane;
                int row = ch >> 3, cpos = ch & 7;
                int seg = cpos ^ (row & 7);
                gld_lds16(Bt + (size_t)(n0 + row) * K + k0 + seg * 8,
                          smem + 16 * 1024 + (size_t)(i * 256 + w * 64) * 16);
            }
        } else {
#pragma unroll
            for (int i = 0; i < 4; ++i) {
                int c = t + i * 256;
                int row = c >> 3, seg = c & 7;
                int gr = m0 + row;
                bf16x8 v = bzero8();
                if (gr < M) v = *(const bf16x8*)(A + (size_t)gr * K + k0 + seg * 8);
                *(bf16x8*)(smem + row * 128 + ((seg * 16) ^ ((row & 7) << 4))) = v;
            }
#pragma unroll
            for (int i = 0; i < 2; ++i) {
                int c = t + i * 256;
                int row = c >> 3, seg = c & 7;
                bf16x8 v = *(const bf16x8*)(Bt + (size_t)(n0 + row) * K + k0 + seg * 8);
                *(bf16x8*)(smem + 16 * 1024 + row * 128 + ((seg * 16) ^ ((row & 7) << 4))) = v;
            }
        }
        __syncthreads();

        bf16x8 a[4][2], bfr[2][2];
#pragma unroll
        for (int mi = 0; mi < 4; ++mi)
#pragma unroll
            for (int kh = 0; kh < 2; ++kh) {
                int row = wr * 64 + mi * 16 + (lane & 15);
                a[mi][kh] = *(const bf16x8*)(smem + row * 128 +
                             ((kh * 64 + (lane >> 4) * 16) ^ ((row & 7) << 4)));
            }
#pragma unroll
        for (int ni = 0; ni < 2; ++ni)
#pragma unroll
            for (int kh = 0; kh < 2; ++kh) {
                int row = wc * 32 + ni * 16 + (lane & 15);
                bfr[ni][kh] = *(const bf16x8*)(smem + 16 * 1024 + row * 128 +
                               ((kh * 64 + (lane >> 4) * 16) ^ ((row & 7) << 4)));
            }
#pragma unroll
        for (int mi = 0; mi < 4; ++mi)
#pragma unroll
            for (int ni = 0; ni < 2; ++ni) {
                acc[mi][ni] = __builtin_amdgcn_mfma_f32_16x16x32_bf16(a[mi][0], bfr[ni][0], acc[mi][ni], 0, 0, 0);
                acc[mi][ni] = __builtin_amdgcn_mfma_f32_16x16x32_bf16(a[mi][1], bfr[ni][1], acc[mi][ni], 0, 0, 0);
            }
        __syncthreads();
    }

#pragma unroll
    for (int mi = 0; mi < 4; ++mi)
#pragma unroll
        for (int ni = 0; ni < 2; ++ni) {
            const int col = n0 + wc * 32 + ni * 16 + (lane & 15);
            const int rowb = m0 + wr * 64 + mi * 16 + (lane >> 4) * 4;
            if (EPI == 5) {
                if (col < 320) {
#pragma unroll
                    for (int r = 0; r < 4; ++r)
                        Y0[(size_t)(rowb + r) * 320 + col] = (bf16)(acc[mi][ni][r] * QSCALE);
                } else if (col < 640) {
#pragma unroll
                    for (int r = 0; r < 4; ++r)
                        Y1[(size_t)(rowb + r) * 320 + (col - 320)] = (bf16)acc[mi][ni][r];
                } else {
                    bf16x4 tv;
#pragma unroll
                    for (int r = 0; r < 4; ++r) tv[r] = (bf16)acc[mi][ni][r];
                    *(bf16x4*)(Y2 + (size_t)(col - 640) * trs + rowb) = tv;
                }
            } else if (EPI == 6) {
                if (col < 320) {
#pragma unroll
                    for (int r = 0; r < 4; ++r)
                        if (rowb + r < M) Y0[(size_t)(rowb + r) * 320 + col] = (bf16)acc[mi][ni][r];
                } else {
                    bf16x4 tv;
#pragma unroll
                    for (int r = 0; r < 4; ++r) tv[r] = (bf16)acc[mi][ni][r];
                    *(bf16x4*)(Y2 + (size_t)(col - 320) * trs + rowb) = tv;
                }
            } else if (EPI == 7) {
                int bidx = (col & 1) ? (1280 + (col >> 1)) : (col >> 1);
                float bc = bias[bidx];
#pragma unroll
                for (int r = 0; r < 4; ++r) {
                    float v = acc[mi][ni][r] + bc;
                    float other = __shfl_xor(v, 1);
                    if (!(col & 1)) {
                        float gl = 0.5f * other * (1.f + erff(other * 0.70710678118654752f));
                        Y0[(size_t)(rowb + r) * 1280 + (col >> 1)] = (bf16)(v * gl);
                    }
                }
            } else {
#pragma unroll
                for (int r = 0; r < 4; ++r) {
                    int row = rowb + r;
                    float v = acc[mi][ni][r];
                    if (EPI == 4) Y0[(size_t)row * N + col] = (bf16)(v * QSCALE);
                    else Yf[(size_t)row * N + col] = v + bias[col] + res[(size_t)row * N + col];
                }
            }
        }
}

// ---------------- flash attention v5 ----------------
// gld_lds staging + 2-phase unroll (compile-time LDS bases -> hoisted addrs),
// l-sum via ones-row in V (row 40 = 1.0), defer-max (thr 8, log2 domain).
#define KVT 64
#define KBYTES 5120    // 64*80
#define VBYTES 6144    // 48*128
#define FBUF (KBYTES + VBYTES)

template <int DIRECT>
__global__ __launch_bounds__(256, 4)
void flash_attn5(const bf16* __restrict__ Qg, const bf16* __restrict__ Kg,
                 const bf16* __restrict__ VTg, bf16* __restrict__ O,
                 float* __restrict__ Opart, float* __restrict__ MLpart,
                 int nkv, int vstride, int tiles_per_split) {
    __shared__ char smem[2 * FBUF];   // 22528 B
    const int t = threadIdx.x, lane = t & 63, w = t >> 6;
    const int g = lane >> 4, q = lane & 15;
    const int h = blockIdx.y, split = blockIdx.z;
    const int qb = blockIdx.x * 64 + w * 16;

    const int ntiles = (nkv + KVT - 1) / KVT;
    const int tt0 = split * tiles_per_split;
    int tt1 = tt0 + tiles_per_split;
    if (tt1 > ntiles) tt1 = ntiles;

    // ones-row init: LDS V rows 40-47 of BOTH buffers (row 40 = 1.0 -> l in accO)
    if (t < 128) {
        bf16x8 v = bzero8();
        if (((t & 63) >> 3) == 0) {
#pragma unroll
            for (int e = 0; e < 8; ++e) v[e] = (bf16)1.0f;
        }
        *(bf16x8*)(smem + (t >> 6) * FBUF + KBYTES + 5120 + (t & 63) * 16) = v;
    }

    // staging slots: w0: K0 K1 K2 | w1: K3 K4 V0 | w2: V1 V2 V3 | w3: V4
    const int nslot = (w == 3) ? 1 : 3;
    const bf16* srcp[3];
    int dstoff[3], sstep[3];
#pragma unroll
    for (int s = 0; s < 3; ++s) {
        int id = w * 3 + s;
        if (id < 5) {
            int c16 = id * 64 + lane;
            int row = c16 / 5, seg = c16 - row * 5;
            srcp[s] = Kg + (size_t)(tt0 * KVT + row) * DIM + h * DHEAD + seg * 8;
            sstep[s] = KVT * DIM;
            dstoff[s] = id * 1024;
        } else {
            int vv = id - 5;  // 0..4 -> V rows vv*8..vv*8+7 (d 0..39)
            int c16 = vv * 64 + lane;
            int row = c16 >> 3, seg = (c16 & 7) ^ (row & 7);   // pre-swizzled source
            srcp[s] = VTg + (size_t)(h * DHEAD + row) * vstride + tt0 * KVT + seg * 8;
            sstep[s] = KVT;
            dstoff[s] = KBYTES + vv * 1024;
        }
    }

#define STAGE(BUFOFF)                                                     \
    do {                                                                  \
        _Pragma("unroll")                                                 \
        for (int s = 0; s < 3; ++s) {                                     \
            if (s < nslot) {                                              \
                gld_lds16(srcp[s], smem + (BUFOFF) + dstoff[s]);          \
                srcp[s] += sstep[s];                                      \
            }                                                             \
        }                                                                 \
    } while (0)

    // Q fragments direct from global (d 40..63 pad = zero regs)
    bf16x8 qf0 = *(const bf16x8*)(Qg + (size_t)(qb + q) * DIM + h * DHEAD + g * 8);
    bf16x8 qf1 = bzero8();
    if (g == 0) qf1 = *(const bf16x8*)(Qg + (size_t)(qb + q) * DIM + h * DHEAD + 32);

    f32x4 accO[3];
#pragma unroll
    for (int dt = 0; dt < 3; ++dt)
#pragma unroll
        for (int r = 0; r < 4; ++r) accO[dt][r] = 0.f;
    float m_run = -1e30f;

#define TILE_BODY(KSC, J0)                                                        \
    do {                                                                          \
        const char* Ks_ = (KSC);                                                  \
        const char* Vs_ = Ks_ + KBYTES;                                           \
        f32x4 s4[4];                                                              \
        __builtin_amdgcn_s_setprio(1);                                            \
        _Pragma("unroll")                                                         \
        for (int jt = 0; jt < 4; ++jt) {                                          \
            const char* krow = Ks_ + (jt * 16 + q) * 80;                          \
            bf16x8 kb0 = *(const bf16x8*)(krow + g * 16);                         \
            bf16x8 kb1 = bzero8();                                                \
            if (g == 0) kb1 = *(const bf16x8*)(krow + 64);                        \
            f32x4 z;                                                              \
            _Pragma("unroll") for (int r = 0; r < 4; ++r) z[r] = 0.f;             \
            z = __builtin_amdgcn_mfma_f32_16x16x32_bf16(kb0, qf0, z, 0, 0, 0);    \
            z = __builtin_amdgcn_mfma_f32_16x16x32_bf16(kb1, qf1, z, 0, 0, 0);    \
            s4[jt] = z;                                                           \
        }                                                                         \
        __builtin_amdgcn_s_setprio(0);                                            \
        if ((J0) + KVT > nkv) {                                                   \
            _Pragma("unroll") for (int jt = 0; jt < 4; ++jt)                      \
            _Pragma("unroll") for (int r = 0; r < 4; ++r)                         \
                if ((J0) + jt * 16 + g * 4 + r >= nkv) s4[jt][r] = -1e30f;        \
        }                                                                         \
        f32x4 mvv = s4[0];                                                        \
        _Pragma("unroll") for (int jt = 1; jt < 4; ++jt)                          \
        _Pragma("unroll") for (int r = 0; r < 4; ++r)                             \
            mvv[r] = fmaxf(mvv[r], s4[jt][r]);                                    \
        float mt = fmaxf(fmaxf(mvv[0], mvv[1]), fmaxf(mvv[2], mvv[3]));           \
        mt = fmaxf(mt, __shfl_xor(mt, 16));                                       \
        mt = fmaxf(mt, __shfl_xor(mt, 32));                                       \
        if (!__all(mt <= m_run + 8.f)) {                                          \
            float mnew = fmaxf(m_run, mt);                                        \
            float f = exp2f(m_run - mnew);                                        \
            m_run = mnew;                                                         \
            _Pragma("unroll") for (int dt = 0; dt < 3; ++dt)                      \
            _Pragma("unroll") for (int r = 0; r < 4; ++r) accO[dt][r] *= f;       \
        }                                                                         \
        union PU { bf16x4 hv; shortx4 sv; } pk[4];                                \
        _Pragma("unroll") for (int jt = 0; jt < 4; ++jt) {                        \
            bf16x4 hv;                                                            \
            _Pragma("unroll") for (int r = 0; r < 4; ++r)                         \
                hv[r] = (bf16)exp2f(s4[jt][r] - m_run);                           \
            pk[jt].hv = hv;                                                       \
        }                                                                         \
        __builtin_amdgcn_s_setprio(1);                                            \
        _Pragma("unroll") for (int dt = 0; dt < 3; ++dt) {                        \
            const char* vrow = Vs_ + (dt * 16 + q) * 128;                         \
            _Pragma("unroll") for (int jt = 0; jt < 4; ++jt) {                    \
                shortx4 vb = *(const shortx4*)(vrow +                             \
                               ((jt * 32 + g * 8) ^ ((q & 7) << 4)));             \
                accO[dt] = __builtin_amdgcn_mfma_f32_16x16x16bf16_1k(             \
                               vb, pk[jt].sv, accO[dt], 0, 0, 0);                 \
            }                                                                     \
        }                                                                         \
        __builtin_amdgcn_s_setprio(0);                                            \
        __syncthreads();                                                          \
    } while (0)

    STAGE(0);
    __syncthreads();

    int tt = tt0;
    while (tt < tt1) {
        if (tt + 1 < tt1) STAGE(FBUF);
        TILE_BODY(smem, tt * KVT);
        ++tt;
        if (tt >= tt1) break;
        if (tt + 1 < tt1) STAGE(0);
        TILE_BODY(smem + FBUF, tt * KVT);
        ++tt;
    }
#undef TILE_BODY
#undef STAGE

    // l = O^T row 40 (ones row), held by lane 32+q at accO[2][0]
    float l = __shfl(accO[2][0], 32 + q);

    if (DIRECT) {
        float inv = 1.f / l;
#pragma unroll
        for (int dt = 0; dt < 3; ++dt) {
            if (dt < 2 || g < 2) {
                bf16x4 o;
#pragma unroll
                for (int r = 0; r < 4; ++r) o[r] = (bf16)(accO[dt][r] * inv);
                *(bf16x4*)(O + (size_t)(qb + q) * DIM + h * DHEAD + dt * 16 + g * 4) = o;
            }
        }
    } else {
        size_t rowi = (size_t)(split * HEADS + h) * NTOK + qb + q;
#pragma unroll
        for (int dt = 0; dt < 3; ++dt) {
            if (dt < 2 || g < 2)
                *(f32x4*)(Opart + rowi * 40 + dt * 16 + g * 4) = accO[dt];
        }
        if (g == 2) {
            f32x2 ml;
            ml[0] = m_run; ml[1] = accO[2][0];
            *(f32x2*)(MLpart + rowi * 2) = ml;
        }
    }
}

// ---------------- combine 4 KV-splits ----------------
__global__ __launch_bounds__(256)
void flash_combine(const float* __restrict__ Opart, const float* __restrict__ MLpart,
                   bf16* __restrict__ O) {
    int idx = blockIdx.x * 256 + threadIdx.x;  // 4096*40
    int qi = idx / 40, c = idx - qi * 40;
    int h = c / 5, c8 = c - h * 5;
    float mv[4], lv[4];
    float M = -1e30f;
#pragma unroll
    for (int s = 0; s < 4; ++s) {
        f32x2 ml = *(const f32x2*)(MLpart + ((size_t)(s * HEADS + h) * NTOK + qi) * 2);
        mv[s] = ml[0]; lv[s] = ml[1];
        M = fmaxf(M, ml[0]);
    }
    float wgt[4], denom = 0.f;
#pragma unroll
    for (int s = 0; s < 4; ++s) { wgt[s] = exp2f(mv[s] - M); denom += wgt[s] * lv[s]; }
    float inv = 1.f / denom;
    float o[8];
#pragma unroll
    for (int e = 0; e < 8; ++e) o[e] = 0.f;
#pragma unroll
    for (int s = 0; s < 4; ++s) {
        const float* op = Opart + ((size_t)(s * HEADS + h) * NTOK + qi) * 40 + c8 * 8;
#pragma unroll
        for (int e = 0; e < 8; ++e) o[e] += wgt[s] * op[e];
    }
    bf16x8 ov;
#pragma unroll
    for (int e = 0; e < 8; ++e) ov[e] = (bf16)(o[e] * inv);
    *(bf16x8*)(O + (size_t)qi * DIM + h * DHEAD + c8 * 8) = ov;
}

// ---------------- launch ----------------
extern "C" void kernel_launch(void* const* d_in, const int* in_sizes, int n_in,
                              void* d_out, int out_size, void* d_ws, size_t ws_size,
                              hipStream_t stream) {
    const float* x     = (const float*)d_in[0];
    const float* ctx   = (const float*)d_in[1];
    const float* n1_g  = (const float*)d_in[2];
    const float* n1_b  = (const float*)d_in[3];
    const float* a1_wq = (const float*)d_in[4];
    const float* a1_wk = (const float*)d_in[5];
    const float* a1_wv = (const float*)d_in[6];
    const float* a1_wo = (const float*)d_in[7];
    const float* a1_bo = (const float*)d_in[8];
    const float* n2_g  = (const float*)d_in[9];
    const float* n2_b  = (const float*)d_in[10];
    const float* a2_wq = (const float*)d_in[11];
    const float* a2_wk = (const float*)d_in[12];
    const float* a2_wv = (const float*)d_in[13];
    const float* a2_wo = (const float*)d_in[14];
    const float* a2_bo = (const float*)d_in[15];
    const float* n3_g  = (const float*)d_in[16];
    const float* n3_b  = (const float*)d_in[17];
    const float* ff_w1 = (const float*)d_in[18];
    const float* ff_b1 = (const float*)d_in[19];
    const float* ff_w2 = (const float*)d_in[20];
    const float* ff_b2 = (const float*)d_in[21];

    char* ws = (char*)d_ws;
    size_t off = 0;
    auto alloc = [&](size_t bytes) -> char* {
        char* p = ws + off;
        off += (bytes + 255) & ~(size_t)255;
        return p;
    };
    bf16* lnbuf  = (bf16*)alloc((size_t)NTOK * DIM * 2);
    bf16* qbuf   = (bf16*)alloc((size_t)NTOK * DIM * 2);
    bf16* kbuf   = (bf16*)alloc((size_t)NTOK * DIM * 2);
    bf16* vtbuf  = (bf16*)alloc((size_t)DIM * NTOK * 2);   // [320 d][4096 tok]
    bf16* abuf   = (bf16*)alloc((size_t)NTOK * DIM * 2);
    bf16* hbuf   = (bf16*)alloc((size_t)NTOK * 2 * IFF * 2);  // Opart alias only
    bf16* gbuf   = (bf16*)alloc((size_t)NTOK * IFF * 2);
    bf16* ctxb   = (bf16*)alloc((size_t)NCTX * CTXD * 2);
    bf16* k2buf  = (bf16*)alloc((size_t)128 * DIM * 2);
    bf16* vt2buf = (bf16*)alloc((size_t)DIM * 128 * 2);
    bf16* wqkvT  = (bf16*)alloc((size_t)960 * DIM * 2);
    bf16* woT    = (bf16*)alloc((size_t)DIM * DIM * 2);
    bf16* q2T    = (bf16*)alloc((size_t)DIM * DIM * 2);
    bf16* wkv2T  = (bf16*)alloc((size_t)640 * CTXD * 2);
    bf16* o2T    = (bf16*)alloc((size_t)DIM * DIM * 2);
    bf16* w1T    = (bf16*)alloc((size_t)2 * IFF * DIM * 2);
    bf16* w2T    = (bf16*)alloc((size_t)IFF * DIM * 2);
    float* out   = (float*)d_out;

    float* Opart  = (float*)hbuf;   // 4*8*4096*40 f32 = 20.97 MB
    float* MLpart = (float*)gbuf;   // consumed by combine before FF1 writes gbuf

    dim3 tb(32, 8);
    {
        TJobs<6> j6;
        j6.s[0] = a1_wq; j6.d[0] = wqkvT;
        j6.s[1] = a1_wk; j6.d[1] = wqkvT + (size_t)320 * 320;
        j6.s[2] = a1_wv; j6.d[2] = wqkvT + (size_t)640 * 320;
        j6.s[3] = a1_wo; j6.d[3] = woT;
        j6.s[4] = a2_wq; j6.d[4] = q2T;
        j6.s[5] = a2_wo; j6.d[5] = o2T;
        transpose_multi<6, 0><<<dim3(10, 10, 6), tb, 0, stream>>>(j6, 320, 320);
        TJobs<2> j2;
        j2.s[0] = a2_wk; j2.d[0] = wkv2T;
        j2.s[1] = a2_wv; j2.d[1] = wkv2T + (size_t)320 * 768;
        transpose_multi<2, 0><<<dim3(10, 24, 2), tb, 0, stream>>>(j2, 768, 320);
        TJobs<1> jw1; jw1.s[0] = ff_w1; jw1.d[0] = w1T;
        transpose_multi<1, 1><<<dim3(80, 10, 1), tb, 0, stream>>>(jw1, 320, 2560);
        TJobs<1> jw2; jw2.s[0] = ff_w2; jw2.d[0] = w2T;
        transpose_multi<1, 0><<<dim3(10, 40, 1), tb, 0, stream>>>(jw2, 1280, 320);
    }
    f32_to_bf16<<<231, 256, 0, stream>>>(ctx, ctxb, NCTX * CTXD);

    // ---- self-attention ----
    layernorm_kernel<<<1024, 256, 0, stream>>>(x, n1_g, n1_b, lnbuf);
    gemm_bf16<5, 1><<<dim3(32, 15), 256, 0, stream>>>(lnbuf, wqkvT, NTOK, 960, DIM,
                                                      qbuf, kbuf, vtbuf, nullptr, nullptr, nullptr, NTOK);
    flash_attn5<0><<<dim3(64, 8, 4), 256, 0, stream>>>(qbuf, kbuf, vtbuf, nullptr,
                                                       Opart, MLpart, NTOK, NTOK, 16);
    flash_combine<<<640, 256, 0, stream>>>(Opart, MLpart, abuf);
    gemm_bf16<2, 1><<<dim3(32, 5), 256, 0, stream>>>(abuf, woT, NTOK, DIM, DIM,
                                                     nullptr, nullptr, nullptr, out, a1_bo, x, 0);

    // ---- cross-attention ----
    layernorm_kernel<<<1024, 256, 0, stream>>>(out, n2_g, n2_b, lnbuf);
    gemm_bf16<4, 1><<<dim3(32, 5), 256, 0, stream>>>(lnbuf, q2T, NTOK, DIM, DIM,
                                                     qbuf, nullptr, nullptr, nullptr, nullptr, nullptr, 0);
    gemm_bf16<6, 0><<<dim3(1, 10), 256, 0, stream>>>(ctxb, wkv2T, NCTX, 640, CTXD,
                                                     k2buf, nullptr, vt2buf, nullptr, nullptr, nullptr, 128);
    flash_attn5<1><<<dim3(64, 8, 1), 256, 0, stream>>>(qbuf, k2buf, vt2buf, abuf,
                                                       nullptr, nullptr, NCTX, 128, 2);
    gemm_bf16<2, 1><<<dim3(32, 5), 256, 0, stream>>>(abuf, o2T, NTOK, DIM, DIM,
                                                     nullptr, nullptr, nullptr, out, a2_bo, out, 0);

    // ---- GEGLU FF (geglu fused into FF1 epilogue) ----
    layernorm_kernel<<<1024, 256, 0, stream>>>(out, n3_g, n3_b, lnbuf);
    gemm_bf16<7, 1><<<dim3(32, 40), 256, 0, stream>>>(lnbuf, w1T, NTOK, 2 * IFF, DIM,
                                                      gbuf, nullptr, nullptr, nullptr, ff_b1, nullptr, 0);
    gemm_bf16<2, 1><<<dim3(32, 5), 256, 0, stream>>>(gbuf, w2T, NTOK, DIM, IFF,
                                                     nullptr, nullptr, nullptr, out, ff_b2, out, 0);
}

// Round 8
// 200.675 us; speedup vs baseline: 3.7897x; 1.0626x over previous
//
#include <hip/hip_runtime.h>
#include <hip/hip_bf16.h>
#include <math.h>

typedef __bf16 bf16;
typedef __attribute__((ext_vector_type(8))) __bf16 bf16x8;
typedef __attribute__((ext_vector_type(4))) __bf16 bf16x4;
typedef __attribute__((ext_vector_type(4))) float f32x4;
typedef __attribute__((ext_vector_type(2))) float f32x2;
typedef __attribute__((ext_vector_type(4))) short shortx4;

#define NTOK 4096
#define DIM  320
#define HEADS 8
#define DHEAD 40
#define NCTX 77
#define CTXD 768
#define IFF  1280

#define QSCALE (0.15811388300841897f * 1.4426950408889634f)  // 40^-0.5 * log2(e)

__device__ __forceinline__ bf16x8 bzero8() {
    bf16x8 v;
#pragma unroll
    for (int e = 0; e < 8; ++e) v[e] = (bf16)0.0f;
    return v;
}

__device__ __forceinline__ void gld_lds16(const void* g, void* l) {
    __builtin_amdgcn_global_load_lds(
        (const __attribute__((address_space(1))) void*)g,
        (__attribute__((address_space(3))) void*)l, 16, 0, 0);
}

// ---------------- transpose + convert fp32 W[K][N] -> bf16 Wt[N][K] ----------
template <int NJ>
struct TJobs { const float* s[NJ]; bf16* d[NJ]; };

template <int NJ, int PERM>
__global__ __launch_bounds__(256)
void transpose_multi(TJobs<NJ> jobs, int K, int N) {
    __shared__ float tile[32][33];
    const float* W = jobs.s[blockIdx.z];
    bf16* Wt = jobs.d[blockIdx.z];
    int n0 = blockIdx.x * 32, k0 = blockIdx.y * 32;
    int tx = threadIdx.x, ty = threadIdx.y;  // (32,8)
#pragma unroll
    for (int i = 0; i < 4; ++i)
        tile[ty + i * 8][tx] = W[(size_t)(k0 + ty + i * 8) * N + n0 + tx];
    __syncthreads();
#pragma unroll
    for (int i = 0; i < 4; ++i) {
        int n = n0 + ty + i * 8;
        int nd = PERM ? ((n < 1280) ? 2 * n : 2 * (n - 1280) + 1) : n;
        Wt[(size_t)nd * K + k0 + tx] = (bf16)tile[tx][ty + i * 8];
    }
}

// ---------------- fp32 -> bf16 elementwise ----------------
__global__ void f32_to_bf16(const float* __restrict__ X, bf16* __restrict__ Y, int n) {
    int i = blockIdx.x * 256 + threadIdx.x;
    if (i < n) Y[i] = (bf16)X[i];
}

// ---------------- LayerNorm: fp32 in -> bf16 out, N=320 ----------------
__global__ __launch_bounds__(256)
void layernorm_kernel(const float* __restrict__ X, const float* __restrict__ g,
                      const float* __restrict__ b, bf16* __restrict__ Y) {
    int w = threadIdx.x >> 6, lane = threadIdx.x & 63;
    int row = blockIdx.x * 4 + w;
    const float* xr = X + (size_t)row * DIM;
    float v[5];
    float sum = 0.f;
#pragma unroll
    for (int c = 0; c < 5; ++c) { v[c] = xr[c * 64 + lane]; sum += v[c]; }
#pragma unroll
    for (int off = 1; off < 64; off <<= 1) sum += __shfl_xor(sum, off);
    float mu = sum * (1.f / 320.f);
    float vs = 0.f;
#pragma unroll
    for (int c = 0; c < 5; ++c) { float d = v[c] - mu; vs += d * d; }
#pragma unroll
    for (int off = 1; off < 64; off <<= 1) vs += __shfl_xor(vs, off);
    float rs = rsqrtf(vs * (1.f / 320.f) + 1e-5f);
    bf16* yr = Y + (size_t)row * DIM;
#pragma unroll
    for (int c = 0; c < 5; ++c)
        yr[c * 64 + lane] = (bf16)((v[c] - mu) * rs * g[c * 64 + lane] + b[c * 64 + lane]);
}

// ---------------- two-barrier bf16 MFMA GEMM (round-6 proven body, BM param) --
// EPI 2: Yf = acc + bias + res (fp32)
// EPI 4: Y0 = bf16(acc * QSCALE)
// EPI 5 (fused qkv, N=960): col<320 -> Y0(q)*QSCALE; col<640 -> Y1(k); else transposed -> Y2
// EPI 7 (FF1+GEGLU, N=2560 permuted): even col=val, odd col=gate -> Y0[row][col>>1]
// Requires M % BM == 0, N % 64 == 0, K % 64 == 0. gld_lds staging, pre-swizzled source.
template <int EPI, int BM>
__global__ __launch_bounds__(256)
void gemm_tb(const bf16* __restrict__ A, const bf16* __restrict__ Bt,
             int M, int N, int K,
             bf16* __restrict__ Y0, bf16* __restrict__ Y1, bf16* __restrict__ Y2,
             float* Yf, const float* __restrict__ bias, const float* res, int trs) {
    constexpr int ABYTES = BM * 128;   // BM rows x 64 k x 2B
    constexpr int ACH = BM / 32;       // A staging chunk-iters
    constexpr int WM = BM / 2;         // rows per wave
    constexpr int MI = WM / 16;        // m-frags per wave
    __shared__ char smem[ABYTES + 8192];
    const int t = threadIdx.x;
    const int lane = t & 63;
    const int w = t >> 6;
    const int wr = w >> 1, wc = w & 1;
    const int m0 = blockIdx.x * BM;
    const int n0 = blockIdx.y * 64;

    f32x4 acc[MI][2];
#pragma unroll
    for (int mi = 0; mi < MI; ++mi)
#pragma unroll
        for (int ni = 0; ni < 2; ++ni)
#pragma unroll
            for (int r = 0; r < 4; ++r) acc[mi][ni][r] = 0.f;

    for (int k0 = 0; k0 < K; k0 += 64) {
#pragma unroll
        for (int i = 0; i < ACH; ++i) {
            int ch = i * 256 + w * 64 + lane;
            int row = ch >> 3, cpos = ch & 7;
            int seg = cpos ^ (row & 7);
            gld_lds16(A + (size_t)(m0 + row) * K + k0 + seg * 8,
                      smem + (size_t)(i * 256 + w * 64) * 16);
        }
#pragma unroll
        for (int i = 0; i < 2; ++i) {
            int ch = i * 256 + w * 64 + lane;
            int row = ch >> 3, cpos = ch & 7;
            int seg = cpos ^ (row & 7);
            gld_lds16(Bt + (size_t)(n0 + row) * K + k0 + seg * 8,
                      smem + ABYTES + (size_t)(i * 256 + w * 64) * 16);
        }
        __syncthreads();

        bf16x8 a[MI][2], bfr[2][2];
#pragma unroll
        for (int mi = 0; mi < MI; ++mi)
#pragma unroll
            for (int kh = 0; kh < 2; ++kh) {
                int row = wr * WM + mi * 16 + (lane & 15);
                a[mi][kh] = *(const bf16x8*)(smem + row * 128 +
                             ((kh * 64 + (lane >> 4) * 16) ^ ((row & 7) << 4)));
            }
#pragma unroll
        for (int ni = 0; ni < 2; ++ni)
#pragma unroll
            for (int kh = 0; kh < 2; ++kh) {
                int row = wc * 32 + ni * 16 + (lane & 15);
                bfr[ni][kh] = *(const bf16x8*)(smem + ABYTES + row * 128 +
                               ((kh * 64 + (lane >> 4) * 16) ^ ((row & 7) << 4)));
            }
#pragma unroll
        for (int mi = 0; mi < MI; ++mi)
#pragma unroll
            for (int ni = 0; ni < 2; ++ni) {
                acc[mi][ni] = __builtin_amdgcn_mfma_f32_16x16x32_bf16(a[mi][0], bfr[ni][0], acc[mi][ni], 0, 0, 0);
                acc[mi][ni] = __builtin_amdgcn_mfma_f32_16x16x32_bf16(a[mi][1], bfr[ni][1], acc[mi][ni], 0, 0, 0);
            }
        __syncthreads();
    }

#pragma unroll
    for (int mi = 0; mi < MI; ++mi)
#pragma unroll
        for (int ni = 0; ni < 2; ++ni) {
            const int col = n0 + wc * 32 + ni * 16 + (lane & 15);
            const int rowb = m0 + wr * WM + mi * 16 + (lane >> 4) * 4;
            if (EPI == 5) {
                if (col < 320) {
#pragma unroll
                    for (int r = 0; r < 4; ++r)
                        Y0[(size_t)(rowb + r) * 320 + col] = (bf16)(acc[mi][ni][r] * QSCALE);
                } else if (col < 640) {
#pragma unroll
                    for (int r = 0; r < 4; ++r)
                        Y1[(size_t)(rowb + r) * 320 + (col - 320)] = (bf16)acc[mi][ni][r];
                } else {
                    bf16x4 tv;
#pragma unroll
                    for (int r = 0; r < 4; ++r) tv[r] = (bf16)acc[mi][ni][r];
                    *(bf16x4*)(Y2 + (size_t)(col - 640) * trs + rowb) = tv;
                }
            } else if (EPI == 7) {
                int bidx = (col & 1) ? (1280 + (col >> 1)) : (col >> 1);
                float bc = bias[bidx];
#pragma unroll
                for (int r = 0; r < 4; ++r) {
                    float v = acc[mi][ni][r] + bc;
                    float other = __shfl_xor(v, 1);
                    if (!(col & 1)) {
                        float gl = 0.5f * other * (1.f + erff(other * 0.70710678118654752f));
                        Y0[(size_t)(rowb + r) * 1280 + (col >> 1)] = (bf16)(v * gl);
                    }
                }
            } else {
#pragma unroll
                for (int r = 0; r < 4; ++r) {
                    int row = rowb + r;
                    if (row < M) {
                        float v = acc[mi][ni][r];
                        if (EPI == 4) Y0[(size_t)row * N + col] = (bf16)(v * QSCALE);
                        else Yf[(size_t)row * N + col] = v + bias[col] + res[(size_t)row * N + col];
                    }
                }
            }
        }
}

// ---------------- small GEMM (M=77 cross-KV), register-staged ----------------
// col<320 -> Y0 (row guard); else transposed pack4 -> Y2 (pad rows give acc=0)
__global__ __launch_bounds__(256)
void gemm_small6(const bf16* __restrict__ A, const bf16* __restrict__ Bt,
                 int M, int N, int K,
                 bf16* __restrict__ Y0, bf16* __restrict__ Y2, int trs) {
    __shared__ char smem[24 * 1024];
    const int t = threadIdx.x;
    const int lane = t & 63;
    const int w = t >> 6;
    const int wr = w >> 1, wc = w & 1;
    const int m0 = 0;
    const int n0 = blockIdx.y * 64;

    f32x4 acc[4][2];
#pragma unroll
    for (int mi = 0; mi < 4; ++mi)
#pragma unroll
        for (int ni = 0; ni < 2; ++ni)
#pragma unroll
            for (int r = 0; r < 4; ++r) acc[mi][ni][r] = 0.f;

    for (int k0 = 0; k0 < K; k0 += 64) {
#pragma unroll
        for (int i = 0; i < 4; ++i) {
            int c = t + i * 256;
            int row = c >> 3, seg = c & 7;
            int gr = m0 + row;
            bf16x8 v = bzero8();
            if (gr < M) v = *(const bf16x8*)(A + (size_t)gr * K + k0 + seg * 8);
            *(bf16x8*)(smem + row * 128 + ((seg * 16) ^ ((row & 7) << 4))) = v;
        }
#pragma unroll
        for (int i = 0; i < 2; ++i) {
            int c = t + i * 256;
            int row = c >> 3, seg = c & 7;
            bf16x8 v = *(const bf16x8*)(Bt + (size_t)(n0 + row) * K + k0 + seg * 8);
            *(bf16x8*)(smem + 16 * 1024 + row * 128 + ((seg * 16) ^ ((row & 7) << 4))) = v;
        }
        __syncthreads();

        bf16x8 a[4][2], bfr[2][2];
#pragma unroll
        for (int mi = 0; mi < 4; ++mi)
#pragma unroll
            for (int kh = 0; kh < 2; ++kh) {
                int row = wr * 64 + mi * 16 + (lane & 15);
                a[mi][kh] = *(const bf16x8*)(smem + row * 128 +
                             ((kh * 64 + (lane >> 4) * 16) ^ ((row & 7) << 4)));
            }
#pragma unroll
        for (int ni = 0; ni < 2; ++ni)
#pragma unroll
            for (int kh = 0; kh < 2; ++kh) {
                int row = wc * 32 + ni * 16 + (lane & 15);
                bfr[ni][kh] = *(const bf16x8*)(smem + 16 * 1024 + row * 128 +
                               ((kh * 64 + (lane >> 4) * 16) ^ ((row & 7) << 4)));
            }
#pragma unroll
        for (int mi = 0; mi < 4; ++mi)
#pragma unroll
            for (int ni = 0; ni < 2; ++ni) {
                acc[mi][ni] = __builtin_amdgcn_mfma_f32_16x16x32_bf16(a[mi][0], bfr[ni][0], acc[mi][ni], 0, 0, 0);
                acc[mi][ni] = __builtin_amdgcn_mfma_f32_16x16x32_bf16(a[mi][1], bfr[ni][1], acc[mi][ni], 0, 0, 0);
            }
        __syncthreads();
    }

#pragma unroll
    for (int mi = 0; mi < 4; ++mi)
#pragma unroll
        for (int ni = 0; ni < 2; ++ni) {
            const int col = n0 + wc * 32 + ni * 16 + (lane & 15);
            const int rowb = m0 + wr * 64 + mi * 16 + (lane >> 4) * 4;
            if (col < 320) {
#pragma unroll
                for (int r = 0; r < 4; ++r)
                    if (rowb + r < M) Y0[(size_t)(rowb + r) * 320 + col] = (bf16)acc[mi][ni][r];
            } else {
                bf16x4 tv;
#pragma unroll
                for (int r = 0; r < 4; ++r) tv[r] = (bf16)acc[mi][ni][r];
                *(bf16x4*)(Y2 + (size_t)(col - 320) * trs + rowb) = tv;
            }
        }
}

// ---------------- flash attention v5 (round-6 proven, verbatim) --------------
#define KVT 64
#define KBYTES 5120    // 64*80
#define VBYTES 6144    // 48*128
#define FBUF (KBYTES + VBYTES)

template <int DIRECT>
__global__ __launch_bounds__(256, 4)
void flash_attn5(const bf16* __restrict__ Qg, const bf16* __restrict__ Kg,
                 const bf16* __restrict__ VTg, bf16* __restrict__ O,
                 float* __restrict__ Opart, float* __restrict__ MLpart,
                 int nkv, int vstride, int tiles_per_split) {
    __shared__ char smem[2 * FBUF];   // 22528 B
    const int t = threadIdx.x, lane = t & 63, w = t >> 6;
    const int g = lane >> 4, q = lane & 15;
    const int h = blockIdx.y, split = blockIdx.z;
    const int qb = blockIdx.x * 64 + w * 16;

    const int ntiles = (nkv + KVT - 1) / KVT;
    const int tt0 = split * tiles_per_split;
    int tt1 = tt0 + tiles_per_split;
    if (tt1 > ntiles) tt1 = ntiles;

    // ones-row init: LDS V rows 40-47 of BOTH buffers (row 40 = 1.0 -> l in accO)
    if (t < 128) {
        bf16x8 v = bzero8();
        if (((t & 63) >> 3) == 0) {
#pragma unroll
            for (int e = 0; e < 8; ++e) v[e] = (bf16)1.0f;
        }
        *(bf16x8*)(smem + (t >> 6) * FBUF + KBYTES + 5120 + (t & 63) * 16) = v;
    }

    // staging slots: w0: K0 K1 K2 | w1: K3 K4 V0 | w2: V1 V2 V3 | w3: V4
    const int nslot = (w == 3) ? 1 : 3;
    const bf16* srcp[3];
    int dstoff[3], sstep[3];
#pragma unroll
    for (int s = 0; s < 3; ++s) {
        int id = w * 3 + s;
        if (id < 5) {
            int c16 = id * 64 + lane;
            int row = c16 / 5, seg = c16 - row * 5;
            srcp[s] = Kg + (size_t)(tt0 * KVT + row) * DIM + h * DHEAD + seg * 8;
            sstep[s] = KVT * DIM;
            dstoff[s] = id * 1024;
        } else {
            int vv = id - 5;
            int c16 = vv * 64 + lane;
            int row = c16 >> 3, seg = (c16 & 7) ^ (row & 7);   // pre-swizzled source
            srcp[s] = VTg + (size_t)(h * DHEAD + row) * vstride + tt0 * KVT + seg * 8;
            sstep[s] = KVT;
            dstoff[s] = KBYTES + vv * 1024;
        }
    }

#define STAGE(BUFOFF)                                                     \
    do {                                                                  \
        _Pragma("unroll")                                                 \
        for (int s = 0; s < 3; ++s) {                                     \
            if (s < nslot) {                                              \
                gld_lds16(srcp[s], smem + (BUFOFF) + dstoff[s]);          \
                srcp[s] += sstep[s];                                      \
            }                                                             \
        }                                                                 \
    } while (0)

    // Q fragments direct from global (d 40..63 pad = zero regs)
    bf16x8 qf0 = *(const bf16x8*)(Qg + (size_t)(qb + q) * DIM + h * DHEAD + g * 8);
    bf16x8 qf1 = bzero8();
    if (g == 0) qf1 = *(const bf16x8*)(Qg + (size_t)(qb + q) * DIM + h * DHEAD + 32);

    f32x4 accO[3];
#pragma unroll
    for (int dt = 0; dt < 3; ++dt)
#pragma unroll
        for (int r = 0; r < 4; ++r) accO[dt][r] = 0.f;
    float m_run = -1e30f;

#define TILE_BODY(KSC, J0)                                                        \
    do {                                                                          \
        const char* Ks_ = (KSC);                                                  \
        const char* Vs_ = Ks_ + KBYTES;                                           \
        f32x4 s4[4];                                                              \
        __builtin_amdgcn_s_setprio(1);                                            \
        _Pragma("unroll")                                                         \
        for (int jt = 0; jt < 4; ++jt) {                                          \
            const char* krow = Ks_ + (jt * 16 + q) * 80;                          \
            bf16x8 kb0 = *(const bf16x8*)(krow + g * 16);                         \
            bf16x8 kb1 = bzero8();                                                \
            if (g == 0) kb1 = *(const bf16x8*)(krow + 64);                        \
            f32x4 z;                                                              \
            _Pragma("unroll") for (int r = 0; r < 4; ++r) z[r] = 0.f;             \
            z = __builtin_amdgcn_mfma_f32_16x16x32_bf16(kb0, qf0, z, 0, 0, 0);    \
            z = __builtin_amdgcn_mfma_f32_16x16x32_bf16(kb1, qf1, z, 0, 0, 0);    \
            s4[jt] = z;                                                           \
        }                                                                         \
        __builtin_amdgcn_s_setprio(0);                                            \
        if ((J0) + KVT > nkv) {                                                   \
            _Pragma("unroll") for (int jt = 0; jt < 4; ++jt)                      \
            _Pragma("unroll") for (int r = 0; r < 4; ++r)                         \
                if ((J0) + jt * 16 + g * 4 + r >= nkv) s4[jt][r] = -1e30f;        \
        }                                                                         \
        f32x4 mvv = s4[0];                                                        \
        _Pragma("unroll") for (int jt = 1; jt < 4; ++jt)                          \
        _Pragma("unroll") for (int r = 0; r < 4; ++r)                             \
            mvv[r] = fmaxf(mvv[r], s4[jt][r]);                                    \
        float mt = fmaxf(fmaxf(mvv[0], mvv[1]), fmaxf(mvv[2], mvv[3]));           \
        mt = fmaxf(mt, __shfl_xor(mt, 16));                                       \
        mt = fmaxf(mt, __shfl_xor(mt, 32));                                       \
        if (!__all(mt <= m_run + 8.f)) {                                          \
            float mnew = fmaxf(m_run, mt);                                        \
            float f = exp2f(m_run - mnew);                                        \
            m_run = mnew;                                                         \
            _Pragma("unroll") for (int dt = 0; dt < 3; ++dt)                      \
            _Pragma("unroll") for (int r = 0; r < 4; ++r) accO[dt][r] *= f;       \
        }                                                                         \
        union PU { bf16x4 hv; shortx4 sv; } pk[4];                                \
        _Pragma("unroll") for (int jt = 0; jt < 4; ++jt) {                        \
            bf16x4 hv;                                                            \
            _Pragma("unroll") for (int r = 0; r < 4; ++r)                         \
                hv[r] = (bf16)exp2f(s4[jt][r] - m_run);                           \
            pk[jt].hv = hv;                                                       \
        }                                                                         \
        __builtin_amdgcn_s_setprio(1);                                            \
        _Pragma("unroll") for (int dt = 0; dt < 3; ++dt) {                        \
            const char* vrow = Vs_ + (dt * 16 + q) * 128;                         \
            _Pragma("unroll") for (int jt = 0; jt < 4; ++jt) {                    \
                shortx4 vb = *(const shortx4*)(vrow +                             \
                               ((jt * 32 + g * 8) ^ ((q & 7) << 4)));             \
                accO[dt] = __builtin_amdgcn_mfma_f32_16x16x16bf16_1k(             \
                               vb, pk[jt].sv, accO[dt], 0, 0, 0);                 \
            }                                                                     \
        }                                                                         \
        __builtin_amdgcn_s_setprio(0);                                            \
        __syncthreads();                                                          \
    } while (0)

    STAGE(0);
    __syncthreads();

    int tt = tt0;
    while (tt < tt1) {
        if (tt + 1 < tt1) STAGE(FBUF);
        TILE_BODY(smem, tt * KVT);
        ++tt;
        if (tt >= tt1) break;
        if (tt + 1 < tt1) STAGE(0);
        TILE_BODY(smem + FBUF, tt * KVT);
        ++tt;
    }
#undef TILE_BODY
#undef STAGE

    // l = O^T row 40 (ones row), held by lane 32+q at accO[2][0]
    float l = __shfl(accO[2][0], 32 + q);

    if (DIRECT) {
        float inv = 1.f / l;
#pragma unroll
        for (int dt = 0; dt < 3; ++dt) {
            if (dt < 2 || g < 2) {
                bf16x4 o;
#pragma unroll
                for (int r = 0; r < 4; ++r) o[r] = (bf16)(accO[dt][r] * inv);
                *(bf16x4*)(O + (size_t)(qb + q) * DIM + h * DHEAD + dt * 16 + g * 4) = o;
            }
        }
    } else {
        size_t rowi = (size_t)(split * HEADS + h) * NTOK + qb + q;
#pragma unroll
        for (int dt = 0; dt < 3; ++dt) {
            if (dt < 2 || g < 2)
                *(f32x4*)(Opart + rowi * 40 + dt * 16 + g * 4) = accO[dt];
        }
        if (g == 2) {
            f32x2 ml;
            ml[0] = m_run; ml[1] = accO[2][0];
            *(f32x2*)(MLpart + rowi * 2) = ml;
        }
    }
}

// ---------------- combine 2 KV-splits ----------------
__global__ __launch_bounds__(256)
void flash_combine2(const float* __restrict__ Opart, const float* __restrict__ MLpart,
                    bf16* __restrict__ O) {
    int idx = blockIdx.x * 256 + threadIdx.x;  // 4096*40
    int qi = idx / 40, c = idx - qi * 40;
    int h = c / 5, c8 = c - h * 5;
    size_t r0 = (size_t)h * NTOK + qi;
    size_t r1 = (size_t)(HEADS + h) * NTOK + qi;
    f32x2 ml0 = *(const f32x2*)(MLpart + r0 * 2);
    f32x2 ml1 = *(const f32x2*)(MLpart + r1 * 2);
    float M = fmaxf(ml0[0], ml1[0]);
    float w0 = exp2f(ml0[0] - M), w1 = exp2f(ml1[0] - M);
    float inv = 1.f / (w0 * ml0[1] + w1 * ml1[1]);
    const float* o0 = Opart + r0 * 40 + c8 * 8;
    const float* o1 = Opart + r1 * 40 + c8 * 8;
    bf16x8 ov;
#pragma unroll
    for (int e = 0; e < 8; ++e)
        ov[e] = (bf16)((o0[e] * w0 + o1[e] * w1) * inv);
    *(bf16x8*)(O + (size_t)qi * DIM + h * DHEAD + c8 * 8) = ov;
}

// ---------------- launch ----------------
extern "C" void kernel_launch(void* const* d_in, const int* in_sizes, int n_in,
                              void* d_out, int out_size, void* d_ws, size_t ws_size,
                              hipStream_t stream) {
    const float* x     = (const float*)d_in[0];
    const float* ctx   = (const float*)d_in[1];
    const float* n1_g  = (const float*)d_in[2];
    const float* n1_b  = (const float*)d_in[3];
    const float* a1_wq = (const float*)d_in[4];
    const float* a1_wk = (const float*)d_in[5];
    const float* a1_wv = (const float*)d_in[6];
    const float* a1_wo = (const float*)d_in[7];
    const float* a1_bo = (const float*)d_in[8];
    const float* n2_g  = (const float*)d_in[9];
    const float* n2_b  = (const float*)d_in[10];
    const float* a2_wq = (const float*)d_in[11];
    const float* a2_wk = (const float*)d_in[12];
    const float* a2_wv = (const float*)d_in[13];
    const float* a2_wo = (const float*)d_in[14];
    const float* a2_bo = (const float*)d_in[15];
    const float* n3_g  = (const float*)d_in[16];
    const float* n3_b  = (const float*)d_in[17];
    const float* ff_w1 = (const float*)d_in[18];
    const float* ff_b1 = (const float*)d_in[19];
    const float* ff_w2 = (const float*)d_in[20];
    const float* ff_b2 = (const float*)d_in[21];

    char* ws = (char*)d_ws;
    size_t off = 0;
    auto alloc = [&](size_t bytes) -> char* {
        char* p = ws + off;
        off += (bytes + 255) & ~(size_t)255;
        return p;
    };
    bf16* lnbuf  = (bf16*)alloc((size_t)NTOK * DIM * 2);
    bf16* qbuf   = (bf16*)alloc((size_t)NTOK * DIM * 2);
    bf16* kbuf   = (bf16*)alloc((size_t)NTOK * DIM * 2);
    bf16* vtbuf  = (bf16*)alloc((size_t)DIM * NTOK * 2);   // [320 d][4096 tok]
    bf16* abuf   = (bf16*)alloc((size_t)NTOK * DIM * 2);
    bf16* hbuf   = (bf16*)alloc((size_t)NTOK * 2 * IFF * 2);  // Opart alias only
    bf16* gbuf   = (bf16*)alloc((size_t)NTOK * IFF * 2);
    bf16* ctxb   = (bf16*)alloc((size_t)NCTX * CTXD * 2);
    bf16* k2buf  = (bf16*)alloc((size_t)128 * DIM * 2);
    bf16* vt2buf = (bf16*)alloc((size_t)DIM * 128 * 2);
    bf16* wqkvT  = (bf16*)alloc((size_t)960 * DIM * 2);
    bf16* woT    = (bf16*)alloc((size_t)DIM * DIM * 2);
    bf16* q2T    = (bf16*)alloc((size_t)DIM * DIM * 2);
    bf16* wkv2T  = (bf16*)alloc((size_t)640 * CTXD * 2);
    bf16* o2T    = (bf16*)alloc((size_t)DIM * DIM * 2);
    bf16* w1T    = (bf16*)alloc((size_t)2 * IFF * DIM * 2);
    bf16* w2T    = (bf16*)alloc((size_t)IFF * DIM * 2);
    float* out   = (float*)d_out;

    float* Opart  = (float*)hbuf;   // 2*8*4096*40 f32 = 10.5 MB
    float* MLpart = (float*)gbuf;   // consumed by combine before FF1 writes gbuf

    dim3 tb(32, 8);
    {
        TJobs<6> j6;
        j6.s[0] = a1_wq; j6.d[0] = wqkvT;
        j6.s[1] = a1_wk; j6.d[1] = wqkvT + (size_t)320 * 320;
        j6.s[2] = a1_wv; j6.d[2] = wqkvT + (size_t)640 * 320;
        j6.s[3] = a1_wo; j6.d[3] = woT;
        j6.s[4] = a2_wq; j6.d[4] = q2T;
        j6.s[5] = a2_wo; j6.d[5] = o2T;
        transpose_multi<6, 0><<<dim3(10, 10, 6), tb, 0, stream>>>(j6, 320, 320);
        TJobs<2> j2;
        j2.s[0] = a2_wk; j2.d[0] = wkv2T;
        j2.s[1] = a2_wv; j2.d[1] = wkv2T + (size_t)320 * 768;
        transpose_multi<2, 0><<<dim3(10, 24, 2), tb, 0, stream>>>(j2, 768, 320);
        TJobs<1> jw1; jw1.s[0] = ff_w1; jw1.d[0] = w1T;
        transpose_multi<1, 1><<<dim3(80, 10, 1), tb, 0, stream>>>(jw1, 320, 2560);
        TJobs<1> jw2; jw2.s[0] = ff_w2; jw2.d[0] = w2T;
        transpose_multi<1, 0><<<dim3(10, 40, 1), tb, 0, stream>>>(jw2, 1280, 320);
    }
    f32_to_bf16<<<231, 256, 0, stream>>>(ctx, ctxb, NCTX * CTXD);

    // ---- self-attention ----
    layernorm_kernel<<<1024, 256, 0, stream>>>(x, n1_g, n1_b, lnbuf);
    gemm_tb<5, 128><<<dim3(32, 15), 256, 0, stream>>>(lnbuf, wqkvT, NTOK, 960, DIM,
                                                      qbuf, kbuf, vtbuf, nullptr, nullptr, nullptr, NTOK);
    flash_attn5<0><<<dim3(64, 8, 2), 256, 0, stream>>>(qbuf, kbuf, vtbuf, nullptr,
                                                       Opart, MLpart, NTOK, NTOK, 32);
    flash_combine2<<<640, 256, 0, stream>>>(Opart, MLpart, abuf);
    gemm_tb<2, 64><<<dim3(64, 5), 256, 0, stream>>>(abuf, woT, NTOK, DIM, DIM,
                                                    nullptr, nullptr, nullptr, out, a1_bo, x, 0);

    // ---- cross-attention ----
    layernorm_kernel<<<1024, 256, 0, stream>>>(out, n2_g, n2_b, lnbuf);
    gemm_tb<4, 64><<<dim3(64, 5), 256, 0, stream>>>(lnbuf, q2T, NTOK, DIM, DIM,
                                                    qbuf, nullptr, nullptr, nullptr, nullptr, nullptr, 0);
    gemm_small6<<<dim3(1, 10), 256, 0, stream>>>(ctxb, wkv2T, NCTX, 640, CTXD,
                                                 k2buf, vt2buf, 128);
    flash_attn5<1><<<dim3(64, 8, 1), 256, 0, stream>>>(qbuf, k2buf, vt2buf, abuf,
                                                       nullptr, nullptr, NCTX, 128, 2);
    gemm_tb<2, 64><<<dim3(64, 5), 256, 0, stream>>>(abuf, o2T, NTOK, DIM, DIM,
                                                    nullptr, nullptr, nullptr, out, a2_bo, out, 0);

    // ---- GEGLU FF (geglu fused into FF1 epilogue) ----
    layernorm_kernel<<<1024, 256, 0, stream>>>(out, n3_g, n3_b, lnbuf);
    gemm_tb<7, 128><<<dim3(32, 40), 256, 0, stream>>>(lnbuf, w1T, NTOK, 2 * IFF, DIM,
                                                      gbuf, nullptr, nullptr, nullptr, ff_b1, nullptr, 0);
    gemm_tb<2, 64><<<dim3(64, 5), 256, 0, stream>>>(gbuf, w2T, NTOK, DIM, IFF,
                                                    nullptr, nullptr, nullptr, out, ff_b2, out, 0);
}

// Round 9
// 196.974 us; speedup vs baseline: 3.8609x; 1.0188x over previous
//
#include <hip/hip_runtime.h>
#include <hip/hip_bf16.h>
#include <math.h>

typedef __bf16 bf16;
typedef __attribute__((ext_vector_type(8))) __bf16 bf16x8;
typedef __attribute__((ext_vector_type(4))) __bf16 bf16x4;
typedef __attribute__((ext_vector_type(4))) float f32x4;
typedef __attribute__((ext_vector_type(2))) float f32x2;
typedef __attribute__((ext_vector_type(4))) short shortx4;

#define NTOK 4096
#define DIM  320
#define HEADS 8
#define DHEAD 40
#define NCTX 77
#define CTXD 768
#define IFF  1280

#define QSCALE (0.15811388300841897f * 1.4426950408889634f)  // 40^-0.5 * log2(e)

__device__ __forceinline__ bf16x8 bzero8() {
    bf16x8 v;
#pragma unroll
    for (int e = 0; e < 8; ++e) v[e] = (bf16)0.0f;
    return v;
}

__device__ __forceinline__ void gld_lds16(const void* g, void* l) {
    __builtin_amdgcn_global_load_lds(
        (const __attribute__((address_space(1))) void*)g,
        (__attribute__((address_space(3))) void*)l, 16, 0, 0);
}

// ---------------- transpose + convert fp32 W[K][N] -> bf16 Wt[N][K] ----------
template <int NJ>
struct TJobs { const float* s[NJ]; bf16* d[NJ]; };

template <int NJ, int PERM>
__global__ __launch_bounds__(256)
void transpose_multi(TJobs<NJ> jobs, int K, int N) {
    __shared__ float tile[32][33];
    const float* W = jobs.s[blockIdx.z];
    bf16* Wt = jobs.d[blockIdx.z];
    int n0 = blockIdx.x * 32, k0 = blockIdx.y * 32;
    int tx = threadIdx.x, ty = threadIdx.y;  // (32,8)
#pragma unroll
    for (int i = 0; i < 4; ++i)
        tile[ty + i * 8][tx] = W[(size_t)(k0 + ty + i * 8) * N + n0 + tx];
    __syncthreads();
#pragma unroll
    for (int i = 0; i < 4; ++i) {
        int n = n0 + ty + i * 8;
        int nd = PERM ? ((n < 1280) ? 2 * n : 2 * (n - 1280) + 1) : n;
        Wt[(size_t)nd * K + k0 + tx] = (bf16)tile[tx][ty + i * 8];
    }
}

// ---------------- fp32 -> bf16 elementwise ----------------
__global__ void f32_to_bf16(const float* __restrict__ X, bf16* __restrict__ Y, int n) {
    int i = blockIdx.x * 256 + threadIdx.x;
    if (i < n) Y[i] = (bf16)X[i];
}

// ---------------- LayerNorm: fp32 in -> bf16 out, N=320 ----------------
__global__ __launch_bounds__(256)
void layernorm_kernel(const float* __restrict__ X, const float* __restrict__ g,
                      const float* __restrict__ b, bf16* __restrict__ Y) {
    int w = threadIdx.x >> 6, lane = threadIdx.x & 63;
    int row = blockIdx.x * 4 + w;
    const float* xr = X + (size_t)row * DIM;
    float v[5];
    float sum = 0.f;
#pragma unroll
    for (int c = 0; c < 5; ++c) { v[c] = xr[c * 64 + lane]; sum += v[c]; }
#pragma unroll
    for (int off = 1; off < 64; off <<= 1) sum += __shfl_xor(sum, off);
    float mu = sum * (1.f / 320.f);
    float vs = 0.f;
#pragma unroll
    for (int c = 0; c < 5; ++c) { float d = v[c] - mu; vs += d * d; }
#pragma unroll
    for (int off = 1; off < 64; off <<= 1) vs += __shfl_xor(vs, off);
    float rs = rsqrtf(vs * (1.f / 320.f) + 1e-5f);
    bf16* yr = Y + (size_t)row * DIM;
#pragma unroll
    for (int c = 0; c < 5; ++c)
        yr[c * 64 + lane] = (bf16)((v[c] - mu) * rs * g[c * 64 + lane] + b[c * 64 + lane]);
}

// ---------------- single-barrier double-buffered bf16 MFMA GEMM --------------
// EPI 2: Yf = acc + bias + res (fp32)
// EPI 4: Y0 = bf16(acc * QSCALE)
// EPI 5 (fused qkv, N=960): col<320 -> Y0(q)*QSCALE; col<640 -> Y1(k); else transposed -> Y2
// EPI 7 (FF1+GEGLU, N=2560 permuted): even col=val, odd col=gate -> Y0[row][col>>1]
// Requires M % BM == 0, N % 64 == 0, K % 64 == 0.
template <int EPI, int BM>
__global__ __launch_bounds__(256)
void gemm_db(const bf16* __restrict__ A, const bf16* __restrict__ Bt,
             int M, int N, int K,
             bf16* __restrict__ Y0, bf16* __restrict__ Y1, bf16* __restrict__ Y2,
             float* Yf, const float* __restrict__ bias, const float* res, int trs) {
    constexpr int ABYTES = BM * 128;   // BM rows x 64 k x 2B
    constexpr int FB = ABYTES + 8192;  // + B tile [64][64]
    constexpr int WM = BM / 2;
    constexpr int MI = WM / 16;
    constexpr int ACH = BM / 32;
    __shared__ char smem[2 * FB];
    const int t = threadIdx.x, lane = t & 63, w = t >> 6;
    const int wr = w >> 1, wc = w & 1;
    const int m0 = blockIdx.x * BM;
    const int n0 = blockIdx.y * 64;

    // per-thread staging source bases (k0 added per call); source pre-swizzled
    const bf16* asrc[ACH];
    const bf16* bsrc[2];
#pragma unroll
    for (int i = 0; i < ACH; ++i) {
        int ch = i * 256 + t;
        int row = ch >> 3, seg = (ch & 7) ^ (row & 7);
        asrc[i] = A + (size_t)(m0 + row) * K + seg * 8;
    }
#pragma unroll
    for (int i = 0; i < 2; ++i) {
        int ch = i * 256 + t;
        int row = ch >> 3, seg = (ch & 7) ^ (row & 7);
        bsrc[i] = Bt + (size_t)(n0 + row) * K + seg * 8;
    }

    f32x4 acc[MI][2];
#pragma unroll
    for (int mi = 0; mi < MI; ++mi)
#pragma unroll
        for (int ni = 0; ni < 2; ++ni)
#pragma unroll
            for (int r = 0; r < 4; ++r) acc[mi][ni][r] = 0.f;

    auto STAGE = [&](char* base, int k0) {
#pragma unroll
        for (int i = 0; i < ACH; ++i)
            gld_lds16(asrc[i] + k0, base + (i * 256 + w * 64) * 16);
#pragma unroll
        for (int i = 0; i < 2; ++i)
            gld_lds16(bsrc[i] + k0, base + ABYTES + (i * 256 + w * 64) * 16);
    };

    char* cur = smem;
    char* nxt = smem + FB;
    STAGE(cur, 0);
    __syncthreads();

    for (int k0 = 0; k0 < K; k0 += 64) {
        if (k0 + 64 < K) STAGE(nxt, k0 + 64);   // async prefetch, drained at barrier
        bf16x8 a[MI][2], b[2][2];
#pragma unroll
        for (int mi = 0; mi < MI; ++mi)
#pragma unroll
            for (int kh = 0; kh < 2; ++kh) {
                int row = wr * WM + mi * 16 + (lane & 15);
                a[mi][kh] = *(const bf16x8*)(cur + row * 128 +
                             ((kh * 64 + (lane >> 4) * 16) ^ ((row & 7) << 4)));
            }
#pragma unroll
        for (int ni = 0; ni < 2; ++ni)
#pragma unroll
            for (int kh = 0; kh < 2; ++kh) {
                int row = wc * 32 + ni * 16 + (lane & 15);
                b[ni][kh] = *(const bf16x8*)(cur + ABYTES + row * 128 +
                             ((kh * 64 + (lane >> 4) * 16) ^ ((row & 7) << 4)));
            }
#pragma unroll
        for (int mi = 0; mi < MI; ++mi)
#pragma unroll
            for (int ni = 0; ni < 2; ++ni) {
                acc[mi][ni] = __builtin_amdgcn_mfma_f32_16x16x32_bf16(a[mi][0], b[ni][0], acc[mi][ni], 0, 0, 0);
                acc[mi][ni] = __builtin_amdgcn_mfma_f32_16x16x32_bf16(a[mi][1], b[ni][1], acc[mi][ni], 0, 0, 0);
            }
        __syncthreads();
        char* tmp = cur; cur = nxt; nxt = tmp;
    }

#pragma unroll
    for (int mi = 0; mi < MI; ++mi)
#pragma unroll
        for (int ni = 0; ni < 2; ++ni) {
            const int col = n0 + wc * 32 + ni * 16 + (lane & 15);
            const int rowb = m0 + wr * WM + mi * 16 + (lane >> 4) * 4;
            if (EPI == 5) {
                if (col < 320) {
#pragma unroll
                    for (int r = 0; r < 4; ++r)
                        Y0[(size_t)(rowb + r) * 320 + col] = (bf16)(acc[mi][ni][r] * QSCALE);
                } else if (col < 640) {
#pragma unroll
                    for (int r = 0; r < 4; ++r)
                        Y1[(size_t)(rowb + r) * 320 + (col - 320)] = (bf16)acc[mi][ni][r];
                } else {
                    bf16x4 tv;
#pragma unroll
                    for (int r = 0; r < 4; ++r) tv[r] = (bf16)acc[mi][ni][r];
                    *(bf16x4*)(Y2 + (size_t)(col - 640) * trs + rowb) = tv;
                }
            } else if (EPI == 7) {
                int bidx = (col & 1) ? (1280 + (col >> 1)) : (col >> 1);
                float bc = bias[bidx];
#pragma unroll
                for (int r = 0; r < 4; ++r) {
                    float v = acc[mi][ni][r] + bc;
                    float other = __shfl_xor(v, 1);
                    if (!(col & 1)) {
                        float gl = 0.5f * other * (1.f + erff(other * 0.70710678118654752f));
                        Y0[(size_t)(rowb + r) * 1280 + (col >> 1)] = (bf16)(v * gl);
                    }
                }
            } else {
#pragma unroll
                for (int r = 0; r < 4; ++r) {
                    int row = rowb + r;
                    if (row < M) {
                        float v = acc[mi][ni][r];
                        if (EPI == 4) Y0[(size_t)row * N + col] = (bf16)(v * QSCALE);
                        else Yf[(size_t)row * N + col] = v + bias[col] + res[(size_t)row * N + col];
                    }
                }
            }
        }
}

// ---------------- small GEMM (M=77 cross-KV), register-staged ----------------
__global__ __launch_bounds__(256)
void gemm_small6(const bf16* __restrict__ A, const bf16* __restrict__ Bt,
                 int M, int N, int K,
                 bf16* __restrict__ Y0, bf16* __restrict__ Y2, int trs) {
    __shared__ char smem[24 * 1024];
    const int t = threadIdx.x;
    const int lane = t & 63;
    const int w = t >> 6;
    const int wr = w >> 1, wc = w & 1;
    const int m0 = 0;
    const int n0 = blockIdx.y * 64;

    f32x4 acc[4][2];
#pragma unroll
    for (int mi = 0; mi < 4; ++mi)
#pragma unroll
        for (int ni = 0; ni < 2; ++ni)
#pragma unroll
            for (int r = 0; r < 4; ++r) acc[mi][ni][r] = 0.f;

    for (int k0 = 0; k0 < K; k0 += 64) {
#pragma unroll
        for (int i = 0; i < 4; ++i) {
            int c = t + i * 256;
            int row = c >> 3, seg = c & 7;
            int gr = m0 + row;
            bf16x8 v = bzero8();
            if (gr < M) v = *(const bf16x8*)(A + (size_t)gr * K + k0 + seg * 8);
            *(bf16x8*)(smem + row * 128 + ((seg * 16) ^ ((row & 7) << 4))) = v;
        }
#pragma unroll
        for (int i = 0; i < 2; ++i) {
            int c = t + i * 256;
            int row = c >> 3, seg = c & 7;
            bf16x8 v = *(const bf16x8*)(Bt + (size_t)(n0 + row) * K + k0 + seg * 8);
            *(bf16x8*)(smem + 16 * 1024 + row * 128 + ((seg * 16) ^ ((row & 7) << 4))) = v;
        }
        __syncthreads();

        bf16x8 a[4][2], bfr[2][2];
#pragma unroll
        for (int mi = 0; mi < 4; ++mi)
#pragma unroll
            for (int kh = 0; kh < 2; ++kh) {
                int row = wr * 64 + mi * 16 + (lane & 15);
                a[mi][kh] = *(const bf16x8*)(smem + row * 128 +
                             ((kh * 64 + (lane >> 4) * 16) ^ ((row & 7) << 4)));
            }
#pragma unroll
        for (int ni = 0; ni < 2; ++ni)
#pragma unroll
            for (int kh = 0; kh < 2; ++kh) {
                int row = wc * 32 + ni * 16 + (lane & 15);
                bfr[ni][kh] = *(const bf16x8*)(smem + 16 * 1024 + row * 128 +
                               ((kh * 64 + (lane >> 4) * 16) ^ ((row & 7) << 4)));
            }
#pragma unroll
        for (int mi = 0; mi < 4; ++mi)
#pragma unroll
            for (int ni = 0; ni < 2; ++ni) {
                acc[mi][ni] = __builtin_amdgcn_mfma_f32_16x16x32_bf16(a[mi][0], bfr[ni][0], acc[mi][ni], 0, 0, 0);
                acc[mi][ni] = __builtin_amdgcn_mfma_f32_16x16x32_bf16(a[mi][1], bfr[ni][1], acc[mi][ni], 0, 0, 0);
            }
        __syncthreads();
    }

#pragma unroll
    for (int mi = 0; mi < 4; ++mi)
#pragma unroll
        for (int ni = 0; ni < 2; ++ni) {
            const int col = n0 + wc * 32 + ni * 16 + (lane & 15);
            const int rowb = m0 + wr * 64 + mi * 16 + (lane >> 4) * 4;
            if (col < 320) {
#pragma unroll
                for (int r = 0; r < 4; ++r)
                    if (rowb + r < M) Y0[(size_t)(rowb + r) * 320 + col] = (bf16)acc[mi][ni][r];
            } else {
                bf16x4 tv;
#pragma unroll
                for (int r = 0; r < 4; ++r) tv[r] = (bf16)acc[mi][ni][r];
                *(bf16x4*)(Y2 + (size_t)(col - 320) * trs + rowb) = tv;
            }
        }
}

// ---------------- flash attention v5 (proven, verbatim) ----------------------
#define KVT 64
#define KBYTES 5120    // 64*80
#define VBYTES 6144    // 48*128
#define FBUF (KBYTES + VBYTES)

template <int DIRECT>
__global__ __launch_bounds__(256, 4)
void flash_attn5(const bf16* __restrict__ Qg, const bf16* __restrict__ Kg,
                 const bf16* __restrict__ VTg, bf16* __restrict__ O,
                 float* __restrict__ Opart, float* __restrict__ MLpart,
                 int nkv, int vstride, int tiles_per_split) {
    __shared__ char smem[2 * FBUF];   // 22528 B
    const int t = threadIdx.x, lane = t & 63, w = t >> 6;
    const int g = lane >> 4, q = lane & 15;
    const int h = blockIdx.y, split = blockIdx.z;
    const int qb = blockIdx.x * 64 + w * 16;

    const int ntiles = (nkv + KVT - 1) / KVT;
    const int tt0 = split * tiles_per_split;
    int tt1 = tt0 + tiles_per_split;
    if (tt1 > ntiles) tt1 = ntiles;

    // ones-row init: LDS V rows 40-47 of BOTH buffers (row 40 = 1.0 -> l in accO)
    if (t < 128) {
        bf16x8 v = bzero8();
        if (((t & 63) >> 3) == 0) {
#pragma unroll
            for (int e = 0; e < 8; ++e) v[e] = (bf16)1.0f;
        }
        *(bf16x8*)(smem + (t >> 6) * FBUF + KBYTES + 5120 + (t & 63) * 16) = v;
    }

    // staging slots: w0: K0 K1 K2 | w1: K3 K4 V0 | w2: V1 V2 V3 | w3: V4
    const int nslot = (w == 3) ? 1 : 3;
    const bf16* srcp[3];
    int dstoff[3], sstep[3];
#pragma unroll
    for (int s = 0; s < 3; ++s) {
        int id = w * 3 + s;
        if (id < 5) {
            int c16 = id * 64 + lane;
            int row = c16 / 5, seg = c16 - row * 5;
            srcp[s] = Kg + (size_t)(tt0 * KVT + row) * DIM + h * DHEAD + seg * 8;
            sstep[s] = KVT * DIM;
            dstoff[s] = id * 1024;
        } else {
            int vv = id - 5;
            int c16 = vv * 64 + lane;
            int row = c16 >> 3, seg = (c16 & 7) ^ (row & 7);   // pre-swizzled source
            srcp[s] = VTg + (size_t)(h * DHEAD + row) * vstride + tt0 * KVT + seg * 8;
            sstep[s] = KVT;
            dstoff[s] = KBYTES + vv * 1024;
        }
    }

#define STAGE(BUFOFF)                                                     \
    do {                                                                  \
        _Pragma("unroll")                                                 \
        for (int s = 0; s < 3; ++s) {                                     \
            if (s < nslot) {                                              \
                gld_lds16(srcp[s], smem + (BUFOFF) + dstoff[s]);          \
                srcp[s] += sstep[s];                                      \
            }                                                             \
        }                                                                 \
    } while (0)

    // Q fragments direct from global (d 40..63 pad = zero regs)
    bf16x8 qf0 = *(const bf16x8*)(Qg + (size_t)(qb + q) * DIM + h * DHEAD + g * 8);
    bf16x8 qf1 = bzero8();
    if (g == 0) qf1 = *(const bf16x8*)(Qg + (size_t)(qb + q) * DIM + h * DHEAD + 32);

    f32x4 accO[3];
#pragma unroll
    for (int dt = 0; dt < 3; ++dt)
#pragma unroll
        for (int r = 0; r < 4; ++r) accO[dt][r] = 0.f;
    float m_run = -1e30f;

#define TILE_BODY(KSC, J0)                                                        \
    do {                                                                          \
        const char* Ks_ = (KSC);                                                  \
        const char* Vs_ = Ks_ + KBYTES;                                           \
        f32x4 s4[4];                                                              \
        __builtin_amdgcn_s_setprio(1);                                            \
        _Pragma("unroll")                                                         \
        for (int jt = 0; jt < 4; ++jt) {                                          \
            const char* krow = Ks_ + (jt * 16 + q) * 80;                          \
            bf16x8 kb0 = *(const bf16x8*)(krow + g * 16);                         \
            bf16x8 kb1 = bzero8();                                                \
            if (g == 0) kb1 = *(const bf16x8*)(krow + 64);                        \
            f32x4 z;                                                              \
            _Pragma("unroll") for (int r = 0; r < 4; ++r) z[r] = 0.f;             \
            z = __builtin_amdgcn_mfma_f32_16x16x32_bf16(kb0, qf0, z, 0, 0, 0);    \
            z = __builtin_amdgcn_mfma_f32_16x16x32_bf16(kb1, qf1, z, 0, 0, 0);    \
            s4[jt] = z;                                                           \
        }                                                                         \
        __builtin_amdgcn_s_setprio(0);                                            \
        if ((J0) + KVT > nkv) {                                                   \
            _Pragma("unroll") for (int jt = 0; jt < 4; ++jt)                      \
            _Pragma("unroll") for (int r = 0; r < 4; ++r)                         \
                if ((J0) + jt * 16 + g * 4 + r >= nkv) s4[jt][r] = -1e30f;        \
        }                                                                         \
        f32x4 mvv = s4[0];                                                        \
        _Pragma("unroll") for (int jt = 1; jt < 4; ++jt)                          \
        _Pragma("unroll") for (int r = 0; r < 4; ++r)                             \
            mvv[r] = fmaxf(mvv[r], s4[jt][r]);                                    \
        float mt = fmaxf(fmaxf(mvv[0], mvv[1]), fmaxf(mvv[2], mvv[3]));           \
        mt = fmaxf(mt, __shfl_xor(mt, 16));                                       \
        mt = fmaxf(mt, __shfl_xor(mt, 32));                                       \
        if (!__all(mt <= m_run + 8.f)) {                                          \
            float mnew = fmaxf(m_run, mt);                                        \
            float f = exp2f(m_run - mnew);                                        \
            m_run = mnew;                                                         \
            _Pragma("unroll") for (int dt = 0; dt < 3; ++dt)                      \
            _Pragma("unroll") for (int r = 0; r < 4; ++r) accO[dt][r] *= f;       \
        }                                                                         \
        union PU { bf16x4 hv; shortx4 sv; } pk[4];                                \
        _Pragma("unroll") for (int jt = 0; jt < 4; ++jt) {                        \
            bf16x4 hv;                                                            \
            _Pragma("unroll") for (int r = 0; r < 4; ++r)                         \
                hv[r] = (bf16)exp2f(s4[jt][r] - m_run);                           \
            pk[jt].hv = hv;                                                       \
        }                                                                         \
        __builtin_amdgcn_s_setprio(1);                                            \
        _Pragma("unroll") for (int dt = 0; dt < 3; ++dt) {                        \
            const char* vrow = Vs_ + (dt * 16 + q) * 128;                         \
            _Pragma("unroll") for (int jt = 0; jt < 4; ++jt) {                    \
                shortx4 vb = *(const shortx4*)(vrow +                             \
                               ((jt * 32 + g * 8) ^ ((q & 7) << 4)));             \
                accO[dt] = __builtin_amdgcn_mfma_f32_16x16x16bf16_1k(             \
                               vb, pk[jt].sv, accO[dt], 0, 0, 0);                 \
            }                                                                     \
        }                                                                         \
        __builtin_amdgcn_s_setprio(0);                                            \
        __syncthreads();                                                          \
    } while (0)

    STAGE(0);
    __syncthreads();

    int tt = tt0;
    while (tt < tt1) {
        if (tt + 1 < tt1) STAGE(FBUF);
        TILE_BODY(smem, tt * KVT);
        ++tt;
        if (tt >= tt1) break;
        if (tt + 1 < tt1) STAGE(0);
        TILE_BODY(smem + FBUF, tt * KVT);
        ++tt;
    }
#undef TILE_BODY
#undef STAGE

    // l = O^T row 40 (ones row), held by lane 32+q at accO[2][0]
    float l = __shfl(accO[2][0], 32 + q);

    if (DIRECT) {
        float inv = 1.f / l;
#pragma unroll
        for (int dt = 0; dt < 3; ++dt) {
            if (dt < 2 || g < 2) {
                bf16x4 o;
#pragma unroll
                for (int r = 0; r < 4; ++r) o[r] = (bf16)(accO[dt][r] * inv);
                *(bf16x4*)(O + (size_t)(qb + q) * DIM + h * DHEAD + dt * 16 + g * 4) = o;
            }
        }
    } else {
        size_t rowi = (size_t)(split * HEADS + h) * NTOK + qb + q;
#pragma unroll
        for (int dt = 0; dt < 3; ++dt) {
            if (dt < 2 || g < 2)
                *(f32x4*)(Opart + rowi * 40 + dt * 16 + g * 4) = accO[dt];
        }
        if (g == 2) {
            f32x2 ml;
            ml[0] = m_run; ml[1] = accO[2][0];
            *(f32x2*)(MLpart + rowi * 2) = ml;
        }
    }
}

// ---------------- combine 4 KV-splits (round-6 proven) ----------------
__global__ __launch_bounds__(256)
void flash_combine(const float* __restrict__ Opart, const float* __restrict__ MLpart,
                   bf16* __restrict__ O) {
    int idx = blockIdx.x * 256 + threadIdx.x;  // 4096*40
    int qi = idx / 40, c = idx - qi * 40;
    int h = c / 5, c8 = c - h * 5;
    float mv[4], lv[4];
    float M = -1e30f;
#pragma unroll
    for (int s = 0; s < 4; ++s) {
        f32x2 ml = *(const f32x2*)(MLpart + ((size_t)(s * HEADS + h) * NTOK + qi) * 2);
        mv[s] = ml[0]; lv[s] = ml[1];
        M = fmaxf(M, ml[0]);
    }
    float wgt[4], denom = 0.f;
#pragma unroll
    for (int s = 0; s < 4; ++s) { wgt[s] = exp2f(mv[s] - M); denom += wgt[s] * lv[s]; }
    float inv = 1.f / denom;
    float o[8];
#pragma unroll
    for (int e = 0; e < 8; ++e) o[e] = 0.f;
#pragma unroll
    for (int s = 0; s < 4; ++s) {
        const float* op = Opart + ((size_t)(s * HEADS + h) * NTOK + qi) * 40 + c8 * 8;
#pragma unroll
        for (int e = 0; e < 8; ++e) o[e] += wgt[s] * op[e];
    }
    bf16x8 ov;
#pragma unroll
    for (int e = 0; e < 8; ++e) ov[e] = (bf16)(o[e] * inv);
    *(bf16x8*)(O + (size_t)qi * DIM + h * DHEAD + c8 * 8) = ov;
}

// ---------------- launch ----------------
extern "C" void kernel_launch(void* const* d_in, const int* in_sizes, int n_in,
                              void* d_out, int out_size, void* d_ws, size_t ws_size,
                              hipStream_t stream) {
    const float* x     = (const float*)d_in[0];
    const float* ctx   = (const float*)d_in[1];
    const float* n1_g  = (const float*)d_in[2];
    const float* n1_b  = (const float*)d_in[3];
    const float* a1_wq = (const float*)d_in[4];
    const float* a1_wk = (const float*)d_in[5];
    const float* a1_wv = (const float*)d_in[6];
    const float* a1_wo = (const float*)d_in[7];
    const float* a1_bo = (const float*)d_in[8];
    const float* n2_g  = (const float*)d_in[9];
    const float* n2_b  = (const float*)d_in[10];
    const float* a2_wq = (const float*)d_in[11];
    const float* a2_wk = (const float*)d_in[12];
    const float* a2_wv = (const float*)d_in[13];
    const float* a2_wo = (const float*)d_in[14];
    const float* a2_bo = (const float*)d_in[15];
    const float* n3_g  = (const float*)d_in[16];
    const float* n3_b  = (const float*)d_in[17];
    const float* ff_w1 = (const float*)d_in[18];
    const float* ff_b1 = (const float*)d_in[19];
    const float* ff_w2 = (const float*)d_in[20];
    const float* ff_b2 = (const float*)d_in[21];

    char* ws = (char*)d_ws;
    size_t off = 0;
    auto alloc = [&](size_t bytes) -> char* {
        char* p = ws + off;
        off += (bytes + 255) & ~(size_t)255;
        return p;
    };
    bf16* lnbuf  = (bf16*)alloc((size_t)NTOK * DIM * 2);
    bf16* qbuf   = (bf16*)alloc((size_t)NTOK * DIM * 2);
    bf16* kbuf   = (bf16*)alloc((size_t)NTOK * DIM * 2);
    bf16* vtbuf  = (bf16*)alloc((size_t)DIM * NTOK * 2);   // [320 d][4096 tok]
    bf16* abuf   = (bf16*)alloc((size_t)NTOK * DIM * 2);
    bf16* hbuf   = (bf16*)alloc((size_t)NTOK * 2 * IFF * 2);  // Opart alias only
    bf16* gbuf   = (bf16*)alloc((size_t)NTOK * IFF * 2);
    bf16* ctxb   = (bf16*)alloc((size_t)NCTX * CTXD * 2);
    bf16* k2buf  = (bf16*)alloc((size_t)128 * DIM * 2);
    bf16* vt2buf = (bf16*)alloc((size_t)DIM * 128 * 2);
    bf16* wqkvT  = (bf16*)alloc((size_t)960 * DIM * 2);
    bf16* woT    = (bf16*)alloc((size_t)DIM * DIM * 2);
    bf16* q2T    = (bf16*)alloc((size_t)DIM * DIM * 2);
    bf16* wkv2T  = (bf16*)alloc((size_t)640 * CTXD * 2);
    bf16* o2T    = (bf16*)alloc((size_t)DIM * DIM * 2);
    bf16* w1T    = (bf16*)alloc((size_t)2 * IFF * DIM * 2);
    bf16* w2T    = (bf16*)alloc((size_t)IFF * DIM * 2);
    float* out   = (float*)d_out;

    float* Opart  = (float*)hbuf;   // 4*8*4096*40 f32 = 20.97 MB
    float* MLpart = (float*)gbuf;   // consumed by combine before FF1 writes gbuf

    dim3 tb(32, 8);
    {
        TJobs<6> j6;
        j6.s[0] = a1_wq; j6.d[0] = wqkvT;
        j6.s[1] = a1_wk; j6.d[1] = wqkvT + (size_t)320 * 320;
        j6.s[2] = a1_wv; j6.d[2] = wqkvT + (size_t)640 * 320;
        j6.s[3] = a1_wo; j6.d[3] = woT;
        j6.s[4] = a2_wq; j6.d[4] = q2T;
        j6.s[5] = a2_wo; j6.d[5] = o2T;
        transpose_multi<6, 0><<<dim3(10, 10, 6), tb, 0, stream>>>(j6, 320, 320);
        TJobs<2> j2;
        j2.s[0] = a2_wk; j2.d[0] = wkv2T;
        j2.s[1] = a2_wv; j2.d[1] = wkv2T + (size_t)320 * 768;
        transpose_multi<2, 0><<<dim3(10, 24, 2), tb, 0, stream>>>(j2, 768, 320);
        TJobs<1> jw1; jw1.s[0] = ff_w1; jw1.d[0] = w1T;
        transpose_multi<1, 1><<<dim3(80, 10, 1), tb, 0, stream>>>(jw1, 320, 2560);
        TJobs<1> jw2; jw2.s[0] = ff_w2; jw2.d[0] = w2T;
        transpose_multi<1, 0><<<dim3(10, 40, 1), tb, 0, stream>>>(jw2, 1280, 320);
    }
    f32_to_bf16<<<231, 256, 0, stream>>>(ctx, ctxb, NCTX * CTXD);

    // ---- self-attention ----
    layernorm_kernel<<<1024, 256, 0, stream>>>(x, n1_g, n1_b, lnbuf);
    gemm_db<5, 128><<<dim3(32, 15), 256, 0, stream>>>(lnbuf, wqkvT, NTOK, 960, DIM,
                                                      qbuf, kbuf, vtbuf, nullptr, nullptr, nullptr, NTOK);
    flash_attn5<0><<<dim3(64, 8, 4), 256, 0, stream>>>(qbuf, kbuf, vtbuf, nullptr,
                                                       Opart, MLpart, NTOK, NTOK, 16);
    flash_combine<<<640, 256, 0, stream>>>(Opart, MLpart, abuf);
    gemm_db<2, 64><<<dim3(64, 5), 256, 0, stream>>>(abuf, woT, NTOK, DIM, DIM,
                                                    nullptr, nullptr, nullptr, out, a1_bo, x, 0);

    // ---- cross-attention ----
    layernorm_kernel<<<1024, 256, 0, stream>>>(out, n2_g, n2_b, lnbuf);
    gemm_db<4, 64><<<dim3(64, 5), 256, 0, stream>>>(lnbuf, q2T, NTOK, DIM, DIM,
                                                    qbuf, nullptr, nullptr, nullptr, nullptr, nullptr, 0);
    gemm_small6<<<dim3(1, 10), 256, 0, stream>>>(ctxb, wkv2T, NCTX, 640, CTXD,
                                                 k2buf, vt2buf, 128);
    flash_attn5<1><<<dim3(64, 8, 1), 256, 0, stream>>>(qbuf, k2buf, vt2buf, abuf,
                                                       nullptr, nullptr, NCTX, 128, 2);
    gemm_db<2, 64><<<dim3(64, 5), 256, 0, stream>>>(abuf, o2T, NTOK, DIM, DIM,
                                                    nullptr, nullptr, nullptr, out, a2_bo, out, 0);

    // ---- GEGLU FF (geglu fused into FF1 epilogue) ----
    layernorm_kernel<<<1024, 256, 0, stream>>>(out, n3_g, n3_b, lnbuf);
    gemm_db<7, 128><<<dim3(32, 40), 256, 0, stream>>>(lnbuf, w1T, NTOK, 2 * IFF, DIM,
                                                      gbuf, nullptr, nullptr, nullptr, ff_b1, nullptr, 0);
    gemm_db<2, 64><<<dim3(64, 5), 256, 0, stream>>>(gbuf, w2T, NTOK, DIM, IFF,
                                                    nullptr, nullptr, nullptr, out, ff_b2, out, 0);
}